// Round 1
// baseline (11954.535 us; speedup 1.0000x reference)
//
#include <hip/hip_runtime.h>

#define N_NODES 10000
#define N_EDGES 160000
#define NB 64
#define D 640
#define ND_IN 4
#define ED_IN 8
#define NLAYERS 6

#define SCORE_SCALE 0.039528470752104741f  // 1/sqrt(640)

// ---- ordered-uint mapping for float atomicMax ----
__device__ __forceinline__ unsigned f2ord(float f) {
  unsigned u = __float_as_uint(f);
  return (u & 0x80000000u) ? ~u : (u | 0x80000000u);
}
__device__ __forceinline__ float ord2f(unsigned u) {
  return __uint_as_float((u & 0x80000000u) ? (u & 0x7FFFFFFFu) : ~u);
}

// out[n,d] = bias[d] + sum_c X[n,c]*W[c,d]   (small Din: layer-0 projections)
__global__ void k_linear_small(const float* __restrict__ X, const float* __restrict__ W,
                               const float* __restrict__ bias, float* __restrict__ out,
                               int Din) {
  int t = blockIdx.x * blockDim.x + threadIdx.x;
  if (t >= N_NODES * D) return;
  int n = t / D, d = t % D;
  float acc = bias[d];
  for (int c = 0; c < Din; ++c) acc += X[n * Din + c] * W[c * D + d];
  out[t] = acc;
}

// fp32 tiled GEMM: out[M=N_NODES, D] = A[N_NODES, D] @ W[D, D] + bias
#define BM 64
#define BN 64
#define BK 16
__global__ __launch_bounds__(256) void k_gemm(const float* __restrict__ A,
                                              const float* __restrict__ W,
                                              const float* __restrict__ bias,
                                              float* __restrict__ out) {
  __shared__ float As[BK][BM + 1];
  __shared__ float Bs[BK][BN];
  const int bm = blockIdx.x * BM;
  const int bn = blockIdx.y * BN;
  const int tid = threadIdx.x;
  const int tx = tid & 15;
  const int ty = tid >> 4;
  float acc[4][4] = {};
  for (int k0 = 0; k0 < D; k0 += BK) {
#pragma unroll
    for (int i = 0; i < 4; ++i) {
      int r = (tid >> 4) + i * 16;
      int c = tid & 15;
      int gm = bm + r;
      As[c][r] = (gm < N_NODES) ? A[gm * D + k0 + c] : 0.0f;
    }
#pragma unroll
    for (int i = 0; i < 4; ++i) {
      int r = (tid >> 6) + i * 4;
      int c = tid & 63;
      Bs[r][c] = W[(k0 + r) * D + bn + c];
    }
    __syncthreads();
#pragma unroll
    for (int kk = 0; kk < BK; ++kk) {
      float a[4], b[4];
#pragma unroll
      for (int i = 0; i < 4; ++i) a[i] = As[kk][ty * 4 + i];
#pragma unroll
      for (int j = 0; j < 4; ++j) b[j] = Bs[kk][tx * 4 + j];
#pragma unroll
      for (int i = 0; i < 4; ++i)
#pragma unroll
        for (int j = 0; j < 4; ++j) acc[i][j] += a[i] * b[j];
    }
    __syncthreads();
  }
#pragma unroll
  for (int i = 0; i < 4; ++i) {
    int gm = bm + ty * 4 + i;
    if (gm >= N_NODES) continue;
#pragma unroll
    for (int j = 0; j < 4; ++j) {
      int gn = bn + tx * 4 + j;
      out[gm * D + gn] = acc[i][j] + bias[gn];
    }
  }
}

// wave per edge: score = q[dst] . (k[src] + ea@We) * scale ; atomicMax segment max
__global__ void k_edge_score(const float* __restrict__ q, const float* __restrict__ k,
                             const float* __restrict__ ea, const float* __restrict__ We,
                             const int* __restrict__ src, const int* __restrict__ dst,
                             float* __restrict__ p, unsigned* __restrict__ smax) {
  int gt = blockIdx.x * blockDim.x + threadIdx.x;
  int e = gt >> 6;
  int lane = gt & 63;
  if (e >= N_EDGES) return;
  int s = src[e], dn = dst[e];
  float eav[ED_IN];
#pragma unroll
  for (int c = 0; c < ED_IN; ++c) eav[c] = ea[e * ED_IN + c];
  const float* qrow = q + (size_t)dn * D;
  const float* krow = k + (size_t)s * D;
  float acc = 0.f;
#pragma unroll
  for (int d0 = 0; d0 < D / 64; ++d0) {
    int d = d0 * 64 + lane;
    float ev = 0.f;
#pragma unroll
    for (int c = 0; c < ED_IN; ++c) ev += eav[c] * We[c * D + d];
    acc += qrow[d] * (krow[d] + ev);
  }
#pragma unroll
  for (int off = 32; off > 0; off >>= 1) acc += __shfl_down(acc, off);
  if (lane == 0) {
    float sc = acc * SCORE_SCALE;
    p[e] = sc;
    atomicMax(smax + dn, f2ord(sc));
  }
}

// thread per edge: p = exp(score - smax[dst]) ; denom += p
__global__ void k_edge_p(float* __restrict__ p, const unsigned* __restrict__ smax,
                         const int* __restrict__ dst, float* __restrict__ denom) {
  int e = blockIdx.x * blockDim.x + threadIdx.x;
  if (e >= N_EDGES) return;
  int dn = dst[e];
  float m = ord2f(smax[dn]);
  float pe = expf(p[e] - m);
  p[e] = pe;
  atomicAdd(denom + dn, pe);
}

// wave per edge: agg[dst] += alpha * (v[src] + ea@We)   (agg pre-loaded with skip)
__global__ void k_edge_agg(const float* __restrict__ v, const float* __restrict__ ea,
                           const float* __restrict__ We, const int* __restrict__ src,
                           const int* __restrict__ dst, const float* __restrict__ p,
                           const float* __restrict__ denom, float* __restrict__ agg) {
  int gt = blockIdx.x * blockDim.x + threadIdx.x;
  int e = gt >> 6;
  int lane = gt & 63;
  if (e >= N_EDGES) return;
  int s = src[e], dn = dst[e];
  float alpha = p[e] / (denom[dn] + 1e-16f);
  float eav[ED_IN];
#pragma unroll
  for (int c = 0; c < ED_IN; ++c) eav[c] = ea[e * ED_IN + c];
  const float* vrow = v + (size_t)s * D;
  float* arow = agg + (size_t)dn * D;
#pragma unroll
  for (int d0 = 0; d0 < D / 64; ++d0) {
    int d = d0 * 64 + lane;
    float ev = 0.f;
#pragma unroll
    for (int c = 0; c < ED_IN; ++c) ev += eav[c] * We[c * D + d];
    atomicAdd(arow + d, alpha * (vrow[d] + ev));
  }
}

__global__ void k_relu(float* __restrict__ x, int n) {
  int t = blockIdx.x * blockDim.x + threadIdx.x;
  if (t < n) x[t] = fmaxf(x[t], 0.f);
}

// global add pool: pooled[batch[n], d] += h[n, d]
__global__ void k_pool(const float* __restrict__ h, const int* __restrict__ bat,
                       float* __restrict__ pooled) {
  int t = blockIdx.x * blockDim.x + threadIdx.x;
  if (t >= N_NODES * D) return;
  int n = t / D, d = t % D;
  atomicAdd(pooled + (size_t)bat[n] * D + d, h[t]);
}

// per graph row: LayerNorm -> @Wemb + bemb -> ReLU
__global__ __launch_bounds__(256) void k_head(const float* __restrict__ pooled,
                                              const float* __restrict__ gam,
                                              const float* __restrict__ bet,
                                              const float* __restrict__ Wemb,
                                              const float* __restrict__ bemb,
                                              float* __restrict__ z) {
  __shared__ float sh[D];
  __shared__ float red[4];
  int b = blockIdx.x, tid = threadIdx.x;
  float local = 0.f;
  for (int c = tid; c < D; c += 256) {
    float val = pooled[(size_t)b * D + c];
    sh[c] = val;
    local += val;
  }
#pragma unroll
  for (int off = 32; off > 0; off >>= 1) local += __shfl_down(local, off);
  if ((tid & 63) == 0) red[tid >> 6] = local;
  __syncthreads();
  float mu = (red[0] + red[1] + red[2] + red[3]) * (1.0f / D);
  __syncthreads();
  float lv = 0.f;
  for (int c = tid; c < D; c += 256) {
    float t2 = sh[c] - mu;
    lv += t2 * t2;
  }
#pragma unroll
  for (int off = 32; off > 0; off >>= 1) lv += __shfl_down(lv, off);
  if ((tid & 63) == 0) red[tid >> 6] = lv;
  __syncthreads();
  float var = (red[0] + red[1] + red[2] + red[3]) * (1.0f / D);
  float rstd = rsqrtf(var + 1e-5f);
  __syncthreads();
  for (int c = tid; c < D; c += 256) sh[c] = (sh[c] - mu) * rstd * gam[c] + bet[c];
  __syncthreads();
  for (int d = tid; d < D; d += 256) {
    float acc = bemb[d];
    for (int c = 0; c < D; ++c) acc += sh[c] * Wemb[c * D + d];
    z[(size_t)b * D + d] = fmaxf(acc, 0.f);
  }
}

// cosine similarity per graph (one wave each)
__global__ void k_cosine(const float* __restrict__ zi, const float* __restrict__ zj,
                         float* __restrict__ out) {
  int b = blockIdx.x, lane = threadIdx.x;
  float dot = 0.f, ni = 0.f, nj = 0.f;
  for (int d = lane; d < D; d += 64) {
    float a = zi[(size_t)b * D + d], c = zj[(size_t)b * D + d];
    dot += a * c;
    ni += a * a;
    nj += c * c;
  }
#pragma unroll
  for (int off = 32; off > 0; off >>= 1) {
    dot += __shfl_down(dot, off);
    ni += __shfl_down(ni, off);
    nj += __shfl_down(nj, off);
  }
  if (lane == 0)
    out[b] = dot / (fmaxf(sqrtf(ni), 1e-8f) * fmaxf(sqrtf(nj), 1e-8f));
}

extern "C" void kernel_launch(void* const* d_in, const int* in_sizes, int n_in,
                              void* d_out, int out_size, void* d_ws, size_t ws_size,
                              hipStream_t stream) {
  (void)in_sizes; (void)n_in; (void)out_size; (void)ws_size;
  const float* W0q = (const float*)d_in[8];
  const float* b0q = (const float*)d_in[9];
  const float* W0k = (const float*)d_in[10];
  const float* b0k = (const float*)d_in[11];
  const float* W0v = (const float*)d_in[12];
  const float* b0v = (const float*)d_in[13];
  const float* W0e = (const float*)d_in[14];
  const float* W0s = (const float*)d_in[15];
  const float* b0s = (const float*)d_in[16];
  const float* Wq = (const float*)d_in[17];
  const float* bq = (const float*)d_in[18];
  const float* Wk = (const float*)d_in[19];
  const float* bk = (const float*)d_in[20];
  const float* Wv = (const float*)d_in[21];
  const float* bv = (const float*)d_in[22];
  const float* We = (const float*)d_in[23];
  const float* Ws = (const float*)d_in[24];
  const float* bs = (const float*)d_in[25];
  const float* ln_g = (const float*)d_in[26];
  const float* ln_b = (const float*)d_in[27];
  const float* Wemb = (const float*)d_in[28];
  const float* bemb = (const float*)d_in[29];

  const size_t NDt = (size_t)N_NODES * D;
  float* bufA = (float*)d_ws;
  float* bufB = bufA + NDt;
  float* bufC = bufB + NDt;
  float* bufD = bufC + NDt;
  float* pbuf = bufD + NDt;                       // E
  unsigned* smax = (unsigned*)(pbuf + N_EDGES);   // N  (contiguous with denom)
  float* denom = (float*)(smax + N_NODES);        // N
  float* pooled = denom + N_NODES;                // B*D
  float* z0 = pooled + (size_t)NB * D;            // B*D
  float* z1 = z0 + (size_t)NB * D;                // B*D

  dim3 gLin((N_NODES * D + 255) / 256);
  dim3 gGemm((N_NODES + BM - 1) / BM, D / BN);
  dim3 gEdgeW(((size_t)N_EDGES * 64) / 256);
  dim3 gEdge((N_EDGES + 255) / 256);

  for (int g = 0; g < 2; ++g) {
    const float* x = (const float*)d_in[g ? 4 : 0];
    const int* ei = (const int*)d_in[g ? 5 : 1];
    const float* ea = (const float*)d_in[g ? 6 : 2];
    const int* bat = (const int*)d_in[g ? 7 : 3];
    const int* srcI = ei;
    const int* dstI = ei + N_EDGES;

    float* h = bufA;
    float* qb = bufB;
    float* kb = bufC;
    float* vb = bufD;

    // ---- layer 0 (Din = ND_IN = 4), input is x ----
    k_linear_small<<<gLin, 256, 0, stream>>>(x, W0q, b0q, qb, ND_IN);
    k_linear_small<<<gLin, 256, 0, stream>>>(x, W0k, b0k, kb, ND_IN);
    k_linear_small<<<gLin, 256, 0, stream>>>(x, W0v, b0v, vb, ND_IN);
    hipMemsetAsync(smax, 0, 2 * N_NODES * sizeof(float), stream);
    k_edge_score<<<gEdgeW, 256, 0, stream>>>(qb, kb, ea, W0e, srcI, dstI, pbuf, smax);
    k_edge_p<<<gEdge, 256, 0, stream>>>(pbuf, smax, dstI, denom);
    k_linear_small<<<gLin, 256, 0, stream>>>(x, W0s, b0s, qb, ND_IN);  // skip -> qb (q dead)
    k_edge_agg<<<gEdgeW, 256, 0, stream>>>(vb, ea, W0e, srcI, dstI, pbuf, denom, qb);
    k_relu<<<gLin, 256, 0, stream>>>(qb, N_NODES * D);
    { float* t = h; h = qb; qb = t; }

    // ---- layers 1..5 (Din = D) ----
    for (int l = 0; l < NLAYERS - 1; ++l) {
      const float* Wql = Wq + (size_t)l * D * D;
      const float* Wkl = Wk + (size_t)l * D * D;
      const float* Wvl = Wv + (size_t)l * D * D;
      const float* Wel = We + (size_t)l * ED_IN * D;
      const float* Wsl = Ws + (size_t)l * D * D;
      k_gemm<<<gGemm, 256, 0, stream>>>(h, Wql, bq + (size_t)l * D, qb);
      k_gemm<<<gGemm, 256, 0, stream>>>(h, Wkl, bk + (size_t)l * D, kb);
      k_gemm<<<gGemm, 256, 0, stream>>>(h, Wvl, bv + (size_t)l * D, vb);
      hipMemsetAsync(smax, 0, 2 * N_NODES * sizeof(float), stream);
      k_edge_score<<<gEdgeW, 256, 0, stream>>>(qb, kb, ea, Wel, srcI, dstI, pbuf, smax);
      k_edge_p<<<gEdge, 256, 0, stream>>>(pbuf, smax, dstI, denom);
      k_gemm<<<gGemm, 256, 0, stream>>>(h, Wsl, bs + (size_t)l * D, qb);  // skip -> qb
      k_edge_agg<<<gEdgeW, 256, 0, stream>>>(vb, ea, Wel, srcI, dstI, pbuf, denom, qb);
      if (l < NLAYERS - 2) k_relu<<<gLin, 256, 0, stream>>>(qb, N_NODES * D);
      { float* t = h; h = qb; qb = t; }
    }

    hipMemsetAsync(pooled, 0, (size_t)NB * D * sizeof(float), stream);
    k_pool<<<gLin, 256, 0, stream>>>(h, bat, pooled);
    k_head<<<NB, 256, 0, stream>>>(pooled, ln_g, ln_b, Wemb, bemb, g ? z1 : z0);
  }
  k_cosine<<<NB, 64, 0, stream>>>(z0, z1, (float*)d_out);
}

// Round 2
// 7301.710 us; speedup vs baseline: 1.6372x; 1.6372x over previous
//
#include <hip/hip_runtime.h>

#define N_NODES 10000
#define N_EDGES 160000
#define NB 64
#define D 640
#define ND_IN 4
#define ED_IN 8
#define NLAYERS 6

#define SCORE_SCALE 0.039528470752104741f  // 1/sqrt(640)

typedef __attribute__((ext_vector_type(8))) short short8;
typedef __attribute__((ext_vector_type(4))) float floatx4;

// ---- ordered-uint mapping for float atomicMax ----
__device__ __forceinline__ unsigned f2ord(float f) {
  unsigned u = __float_as_uint(f);
  return (u & 0x80000000u) ? ~u : (u | 0x80000000u);
}
__device__ __forceinline__ float ord2f(unsigned u) {
  return __uint_as_float((u & 0x80000000u) ? (u & 0x7FFFFFFFu) : ~u);
}
__device__ __forceinline__ unsigned short f2bf(float f) {
  unsigned u = __float_as_uint(f);
  u += 0x7fffu + ((u >> 16) & 1);  // round-to-nearest-even
  return (unsigned short)(u >> 16);
}

// out[n,d] = bias[d] + sum_c X[n,c]*W[c,d]   (small Din: layer-0 projections)
__global__ void k_linear_small(const float* __restrict__ X, const float* __restrict__ W,
                               const float* __restrict__ bias, float* __restrict__ out,
                               int Din) {
  int t = blockIdx.x * blockDim.x + threadIdx.x;
  if (t >= N_NODES * D) return;
  int n = t / D, d = t % D;
  float acc = bias[d];
  for (int c = 0; c < Din; ++c) acc += X[n * Din + c] * W[c * D + d];
  out[t] = acc;
}

// one-time: Wt[l][mat][n][k] = bf16(W[l][mat][k][n])  (transpose + convert, 20 mats)
__global__ __launch_bounds__(256) void k_wprep(const float* __restrict__ Wq,
                                               const float* __restrict__ Wk,
                                               const float* __restrict__ Wv,
                                               const float* __restrict__ Ws,
                                               unsigned short* __restrict__ Wt) {
  __shared__ float tile[32][33];
  int mt = blockIdx.z;  // layer*4 + mat
  int l = mt >> 2, mat = mt & 3;
  const float* W =
      (mat == 0 ? Wq : mat == 1 ? Wk : mat == 2 ? Wv : Ws) + (size_t)l * D * D;
  int tk = blockIdx.x * 32, tn = blockIdx.y * 32;
  int tx = threadIdx.x & 31, ty = threadIdx.x >> 5;  // ty in 0..7
#pragma unroll
  for (int i = 0; i < 32; i += 8)
    tile[ty + i][tx] = W[(size_t)(tk + ty + i) * D + tn + tx];
  __syncthreads();
  unsigned short* dst = Wt + (size_t)mt * D * D;
#pragma unroll
  for (int i = 0; i < 32; i += 8)
    dst[(size_t)(tn + ty + i) * D + tk + tx] = f2bf(tile[tx][ty + i]);
}

// h (fp32) -> bf16, 4 elems/thread
__global__ void k_h2bf16(const float* __restrict__ h, unsigned short* __restrict__ o) {
  int t = blockIdx.x * blockDim.x + threadIdx.x;  // NDt/4 threads
  float4 v = ((const float4*)h)[t];
  ushort4 r;
  r.x = f2bf(v.x); r.y = f2bf(v.y); r.z = f2bf(v.z); r.w = f2bf(v.w);
  ((ushort4*)o)[t] = r;
}

// bf16 MFMA GEMM: out[z][M,640] = A[M,640] @ Wt[z]^T + bias[z]
// A bf16 row-major [M][K]; Wt[z] is [N][K] (pre-transposed); out fp32.
#define BM 128
#define BN 128
#define BK 32
#define LDK 40  // padded K stride in bf16 units (80 B, breaks power-of-2)
__global__ __launch_bounds__(256) void k_gemm_bf16(
    const unsigned short* __restrict__ Abf, const unsigned short* __restrict__ Wt,
    const float* __restrict__ b0, const float* __restrict__ b1,
    const float* __restrict__ b2, float* __restrict__ o0, float* __restrict__ o1,
    float* __restrict__ o2) {
  __shared__ __attribute__((aligned(16))) unsigned short lA[BM * LDK];
  __shared__ __attribute__((aligned(16))) unsigned short lB[BN * LDK];
  const int z = blockIdx.z;
  const unsigned short* Wz = Wt + (size_t)z * D * D;
  const float* bias = (z == 0) ? b0 : (z == 1) ? b1 : b2;
  float* out = (z == 0) ? o0 : (z == 1) ? o1 : o2;
  const int bm = blockIdx.x * BM, bn = blockIdx.y * BN;
  const int t = threadIdx.x;
  const int lane = t & 63, wv = t >> 6;
  const int wm = (wv & 1) * 64, wn = (wv >> 1) * 64;
  const int l15 = lane & 15, l4 = lane >> 4;

  floatx4 acc[4][4] = {};

  for (int k0 = 0; k0 < D; k0 += BK) {
#pragma unroll
    for (int c = t; c < 512; c += 256) {
      int row = c >> 2, off = c & 3;
      int gm = bm + row;
      short8 va = {};
      if (gm < N_NODES)
        va = *(const short8*)(Abf + (size_t)gm * D + k0 + off * 8);
      *(short8*)(lA + row * LDK + off * 8) = va;
      short8 vb = *(const short8*)(Wz + (size_t)(bn + row) * D + k0 + off * 8);
      *(short8*)(lB + row * LDK + off * 8) = vb;
    }
    __syncthreads();
    short8 af[4], bfr[4];
#pragma unroll
    for (int i = 0; i < 4; ++i) {
      af[i] = *(const short8*)(lA + (wm + i * 16 + l15) * LDK + l4 * 8);
      bfr[i] = *(const short8*)(lB + (wn + i * 16 + l15) * LDK + l4 * 8);
    }
#pragma unroll
    for (int mi = 0; mi < 4; ++mi)
#pragma unroll
      for (int ni = 0; ni < 4; ++ni)
        acc[mi][ni] = __builtin_amdgcn_mfma_f32_16x16x32_bf16(af[mi], bfr[ni],
                                                              acc[mi][ni], 0, 0, 0);
    __syncthreads();
  }
#pragma unroll
  for (int mi = 0; mi < 4; ++mi)
#pragma unroll
    for (int ni = 0; ni < 4; ++ni)
#pragma unroll
      for (int r = 0; r < 4; ++r) {
        int row = bm + wm + mi * 16 + l4 * 4 + r;
        int col = bn + wn + ni * 16 + l15;
        if (row < N_NODES) out[(size_t)row * D + col] = acc[mi][ni][r] + bias[col];
      }
}

// wave per edge: score = q[dst] . (k[src] + ea@We) * scale ; atomicMax segment max
__global__ void k_edge_score(const float* __restrict__ q, const float* __restrict__ k,
                             const float* __restrict__ ea, const float* __restrict__ We,
                             const int* __restrict__ src, const int* __restrict__ dst,
                             float* __restrict__ p, unsigned* __restrict__ smax) {
  int gt = blockIdx.x * blockDim.x + threadIdx.x;
  int e = gt >> 6;
  int lane = gt & 63;
  if (e >= N_EDGES) return;
  int s = src[e], dn = dst[e];
  float eav[ED_IN];
#pragma unroll
  for (int c = 0; c < ED_IN; ++c) eav[c] = ea[e * ED_IN + c];
  const float* qrow = q + (size_t)dn * D;
  const float* krow = k + (size_t)s * D;
  float acc = 0.f;
#pragma unroll
  for (int d0 = 0; d0 < D / 64; ++d0) {
    int d = d0 * 64 + lane;
    float ev = 0.f;
#pragma unroll
    for (int c = 0; c < ED_IN; ++c) ev += eav[c] * We[c * D + d];
    acc += qrow[d] * (krow[d] + ev);
  }
#pragma unroll
  for (int off = 32; off > 0; off >>= 1) acc += __shfl_down(acc, off);
  if (lane == 0) {
    float sc = acc * SCORE_SCALE;
    p[e] = sc;
    atomicMax(smax + dn, f2ord(sc));
  }
}

// thread per edge: p = exp(score - smax[dst]) ; denom += p
__global__ void k_edge_p(float* __restrict__ p, const unsigned* __restrict__ smax,
                         const int* __restrict__ dst, float* __restrict__ denom) {
  int e = blockIdx.x * blockDim.x + threadIdx.x;
  if (e >= N_EDGES) return;
  int dn = dst[e];
  float m = ord2f(smax[dn]);
  float pe = expf(p[e] - m);
  p[e] = pe;
  atomicAdd(denom + dn, pe);
}

// wave per edge: agg[dst] += alpha * (v[src] + ea@We)   (agg pre-loaded with skip)
__global__ void k_edge_agg(const float* __restrict__ v, const float* __restrict__ ea,
                           const float* __restrict__ We, const int* __restrict__ src,
                           const int* __restrict__ dst, const float* __restrict__ p,
                           const float* __restrict__ denom, float* __restrict__ agg) {
  int gt = blockIdx.x * blockDim.x + threadIdx.x;
  int e = gt >> 6;
  int lane = gt & 63;
  if (e >= N_EDGES) return;
  int s = src[e], dn = dst[e];
  float alpha = p[e] / (denom[dn] + 1e-16f);
  float eav[ED_IN];
#pragma unroll
  for (int c = 0; c < ED_IN; ++c) eav[c] = ea[e * ED_IN + c];
  const float* vrow = v + (size_t)s * D;
  float* arow = agg + (size_t)dn * D;
#pragma unroll
  for (int d0 = 0; d0 < D / 64; ++d0) {
    int d = d0 * 64 + lane;
    float ev = 0.f;
#pragma unroll
    for (int c = 0; c < ED_IN; ++c) ev += eav[c] * We[c * D + d];
    atomicAdd(arow + d, alpha * (vrow[d] + ev));
  }
}

__global__ void k_relu(float* __restrict__ x, int n) {
  int t = blockIdx.x * blockDim.x + threadIdx.x;
  if (t < n) x[t] = fmaxf(x[t], 0.f);
}

// global add pool: pooled[batch[n], d] += h[n, d]
__global__ void k_pool(const float* __restrict__ h, const int* __restrict__ bat,
                       float* __restrict__ pooled) {
  int t = blockIdx.x * blockDim.x + threadIdx.x;
  if (t >= N_NODES * D) return;
  int n = t / D, d = t % D;
  atomicAdd(pooled + (size_t)bat[n] * D + d, h[t]);
}

// per graph row: LayerNorm -> @Wemb + bemb -> ReLU
__global__ __launch_bounds__(256) void k_head(const float* __restrict__ pooled,
                                              const float* __restrict__ gam,
                                              const float* __restrict__ bet,
                                              const float* __restrict__ Wemb,
                                              const float* __restrict__ bemb,
                                              float* __restrict__ z) {
  __shared__ float sh[D];
  __shared__ float red[4];
  int b = blockIdx.x, tid = threadIdx.x;
  float local = 0.f;
  for (int c = tid; c < D; c += 256) {
    float val = pooled[(size_t)b * D + c];
    sh[c] = val;
    local += val;
  }
#pragma unroll
  for (int off = 32; off > 0; off >>= 1) local += __shfl_down(local, off);
  if ((tid & 63) == 0) red[tid >> 6] = local;
  __syncthreads();
  float mu = (red[0] + red[1] + red[2] + red[3]) * (1.0f / D);
  __syncthreads();
  float lv = 0.f;
  for (int c = tid; c < D; c += 256) {
    float t2 = sh[c] - mu;
    lv += t2 * t2;
  }
#pragma unroll
  for (int off = 32; off > 0; off >>= 1) lv += __shfl_down(lv, off);
  if ((tid & 63) == 0) red[tid >> 6] = lv;
  __syncthreads();
  float var = (red[0] + red[1] + red[2] + red[3]) * (1.0f / D);
  float rstd = rsqrtf(var + 1e-5f);
  __syncthreads();
  for (int c = tid; c < D; c += 256) sh[c] = (sh[c] - mu) * rstd * gam[c] + bet[c];
  __syncthreads();
  for (int d = tid; d < D; d += 256) {
    float acc = bemb[d];
    for (int c = 0; c < D; ++c) acc += sh[c] * Wemb[c * D + d];
    z[(size_t)b * D + d] = fmaxf(acc, 0.f);
  }
}

// cosine similarity per graph (one wave each)
__global__ void k_cosine(const float* __restrict__ zi, const float* __restrict__ zj,
                         float* __restrict__ out) {
  int b = blockIdx.x, lane = threadIdx.x;
  float dot = 0.f, ni = 0.f, nj = 0.f;
  for (int d = lane; d < D; d += 64) {
    float a = zi[(size_t)b * D + d], c = zj[(size_t)b * D + d];
    dot += a * c;
    ni += a * a;
    nj += c * c;
  }
#pragma unroll
  for (int off = 32; off > 0; off >>= 1) {
    dot += __shfl_down(dot, off);
    ni += __shfl_down(ni, off);
    nj += __shfl_down(nj, off);
  }
  if (lane == 0)
    out[b] = dot / (fmaxf(sqrtf(ni), 1e-8f) * fmaxf(sqrtf(nj), 1e-8f));
}

extern "C" void kernel_launch(void* const* d_in, const int* in_sizes, int n_in,
                              void* d_out, int out_size, void* d_ws, size_t ws_size,
                              hipStream_t stream) {
  (void)in_sizes; (void)n_in; (void)out_size; (void)ws_size;
  const float* W0q = (const float*)d_in[8];
  const float* b0q = (const float*)d_in[9];
  const float* W0k = (const float*)d_in[10];
  const float* b0k = (const float*)d_in[11];
  const float* W0v = (const float*)d_in[12];
  const float* b0v = (const float*)d_in[13];
  const float* W0e = (const float*)d_in[14];
  const float* W0s = (const float*)d_in[15];
  const float* b0s = (const float*)d_in[16];
  const float* Wq = (const float*)d_in[17];
  const float* bq = (const float*)d_in[18];
  const float* Wk = (const float*)d_in[19];
  const float* bk = (const float*)d_in[20];
  const float* Wv = (const float*)d_in[21];
  const float* bv = (const float*)d_in[22];
  const float* We = (const float*)d_in[23];
  const float* Ws = (const float*)d_in[24];
  const float* bs = (const float*)d_in[25];
  const float* ln_g = (const float*)d_in[26];
  const float* ln_b = (const float*)d_in[27];
  const float* Wemb = (const float*)d_in[28];
  const float* bemb = (const float*)d_in[29];

  const size_t NDt = (size_t)N_NODES * D;
  float* buf0 = (float*)d_ws;  // h / skip+agg target
  float* qb = buf0 + NDt;
  float* kb = qb + NDt;
  float* vb = kb + NDt;
  float* pbuf = vb + NDt;                        // E
  unsigned* smax = (unsigned*)(pbuf + N_EDGES);  // N (contiguous with denom)
  float* denom = (float*)(smax + N_NODES);       // N
  float* pooled = denom + N_NODES;               // B*D
  float* z0 = pooled + (size_t)NB * D;           // B*D
  float* z1 = z0 + (size_t)NB * D;               // B*D
  unsigned short* hbf = (unsigned short*)(z1 + (size_t)NB * D);  // NDt bf16
  unsigned short* Wt = hbf + NDt;  // 5*4*D*D bf16 (transposed weights)

  dim3 gLin((N_NODES * D + 255) / 256);
  dim3 gGemm3((N_NODES + BM - 1) / BM, D / BN, 3);
  dim3 gGemm1((N_NODES + BM - 1) / BM, D / BN, 1);
  dim3 gEdgeW(((size_t)N_EDGES * 64) / 256);
  dim3 gEdge((N_EDGES + 255) / 256);
  dim3 gCvt((N_NODES * D / 4 + 255) / 256);

  // one-time weight transpose+convert (weights shared across both graphs)
  k_wprep<<<dim3(D / 32, D / 32, (NLAYERS - 1) * 4), 256, 0, stream>>>(Wq, Wk, Wv, Ws, Wt);

  for (int g = 0; g < 2; ++g) {
    const float* x = (const float*)d_in[g ? 4 : 0];
    const int* ei = (const int*)d_in[g ? 5 : 1];
    const float* ea = (const float*)d_in[g ? 6 : 2];
    const int* bat = (const int*)d_in[g ? 7 : 3];
    const int* srcI = ei;
    const int* dstI = ei + N_EDGES;

    float* h = buf0;

    // ---- layer 0 (Din = ND_IN = 4, fp32), input x ----
    k_linear_small<<<gLin, 256, 0, stream>>>(x, W0q, b0q, qb, ND_IN);
    k_linear_small<<<gLin, 256, 0, stream>>>(x, W0k, b0k, kb, ND_IN);
    k_linear_small<<<gLin, 256, 0, stream>>>(x, W0v, b0v, vb, ND_IN);
    k_linear_small<<<gLin, 256, 0, stream>>>(x, W0s, b0s, h, ND_IN);  // skip -> h
    hipMemsetAsync(smax, 0, 2 * N_NODES * sizeof(float), stream);
    k_edge_score<<<gEdgeW, 256, 0, stream>>>(qb, kb, ea, W0e, srcI, dstI, pbuf, smax);
    k_edge_p<<<gEdge, 256, 0, stream>>>(pbuf, smax, dstI, denom);
    k_edge_agg<<<gEdgeW, 256, 0, stream>>>(vb, ea, W0e, srcI, dstI, pbuf, denom, h);
    k_relu<<<gLin, 256, 0, stream>>>(h, N_NODES * D);

    // ---- layers 1..5 (bf16 MFMA GEMMs) ----
    for (int l = 0; l < NLAYERS - 1; ++l) {
      const unsigned short* WtL = Wt + (size_t)l * 4 * D * D;
      const float* Wel = We + (size_t)l * ED_IN * D;
      k_h2bf16<<<gCvt, 256, 0, stream>>>(h, hbf);  // h now dead (fp32 copy)
      k_gemm_bf16<<<gGemm3, 256, 0, stream>>>(hbf, WtL, bq + (size_t)l * D,
                                              bk + (size_t)l * D, bv + (size_t)l * D,
                                              qb, kb, vb);
      k_gemm_bf16<<<gGemm1, 256, 0, stream>>>(hbf, WtL + 3 * (size_t)D * D,
                                              bs + (size_t)l * D, bs, bs, h, h, h);
      hipMemsetAsync(smax, 0, 2 * N_NODES * sizeof(float), stream);
      k_edge_score<<<gEdgeW, 256, 0, stream>>>(qb, kb, ea, Wel, srcI, dstI, pbuf, smax);
      k_edge_p<<<gEdge, 256, 0, stream>>>(pbuf, smax, dstI, denom);
      k_edge_agg<<<gEdgeW, 256, 0, stream>>>(vb, ea, Wel, srcI, dstI, pbuf, denom, h);
      if (l < NLAYERS - 2) k_relu<<<gLin, 256, 0, stream>>>(h, N_NODES * D);
    }

    hipMemsetAsync(pooled, 0, (size_t)NB * D * sizeof(float), stream);
    k_pool<<<gLin, 256, 0, stream>>>(h, bat, pooled);
    k_head<<<NB, 256, 0, stream>>>(pooled, ln_g, ln_b, Wemb, bemb, g ? z1 : z0);
  }
  k_cosine<<<NB, 64, 0, stream>>>(z0, z1, (float*)d_out);
}

// Round 3
// 3216.410 us; speedup vs baseline: 3.7167x; 2.2701x over previous
//
#include <hip/hip_runtime.h>

#define N_NODES 10000
#define N_EDGES 160000
#define NB 64
#define D 640
#define ND_IN 4
#define ED_IN 8
#define NLAYERS 6

#define SCORE_SCALE 0.039528470752104741f  // 1/sqrt(640)

typedef __attribute__((ext_vector_type(8))) short short8;
typedef __attribute__((ext_vector_type(4))) float floatx4;

__device__ __forceinline__ unsigned short f2bf(float f) {
  unsigned u = __float_as_uint(f);
  u += 0x7fffu + ((u >> 16) & 1);  // RNE
  return (unsigned short)(u >> 16);
}

// ---- layer-0 projections: out[z][n,d] = bias + x@W, z in {q,k,v,s} ----
__global__ void k_lin4(const float* __restrict__ X, const float* __restrict__ Wq,
                       const float* __restrict__ bq, const float* __restrict__ Wk,
                       const float* __restrict__ bk, const float* __restrict__ Wv,
                       const float* __restrict__ bv, const float* __restrict__ Ws,
                       const float* __restrict__ bs, float* __restrict__ oq,
                       float* __restrict__ ok, float* __restrict__ ov,
                       float* __restrict__ os) {
  int t = blockIdx.x * blockDim.x + threadIdx.x;
  if (t >= N_NODES * D) return;
  int z = blockIdx.z;
  const float* W = (z == 0) ? Wq : (z == 1) ? Wk : (z == 2) ? Wv : Ws;
  const float* b = (z == 0) ? bq : (z == 1) ? bk : (z == 2) ? bv : bs;
  float* o = (z == 0) ? oq : (z == 1) ? ok : (z == 2) ? ov : os;
  int n = t / D, d = t % D;
  float acc = b[d];
#pragma unroll
  for (int c = 0; c < ND_IN; ++c) acc += X[n * ND_IN + c] * W[c * D + d];
  o[t] = acc;
}

// one-time: Wt[l][mat][n][k] = bf16(W[l][mat][k][n])
__global__ __launch_bounds__(256) void k_wprep(const float* __restrict__ Wq,
                                               const float* __restrict__ Wk,
                                               const float* __restrict__ Wv,
                                               const float* __restrict__ Ws,
                                               unsigned short* __restrict__ Wt) {
  __shared__ float tile[32][33];
  int mt = blockIdx.z;
  int l = mt >> 2, mat = mt & 3;
  const float* W =
      (mat == 0 ? Wq : mat == 1 ? Wk : mat == 2 ? Wv : Ws) + (size_t)l * D * D;
  int tk = blockIdx.x * 32, tn = blockIdx.y * 32;
  int tx = threadIdx.x & 31, ty = threadIdx.x >> 5;
#pragma unroll
  for (int i = 0; i < 32; i += 8)
    tile[ty + i][tx] = W[(size_t)(tk + ty + i) * D + tn + tx];
  __syncthreads();
  unsigned short* dst = Wt + (size_t)mt * D * D;
#pragma unroll
  for (int i = 0; i < 32; i += 8)
    dst[(size_t)(tn + ty + i) * D + tk + tx] = f2bf(tile[tx][ty + i]);
}

// bf16 MFMA GEMM, z in {q,k,v,s}: out[z] = A @ Wt[z]^T + bias[z] (fp32 out)
#define BM 128
#define BN 128
#define BK 32
#define LDK 40
__global__ __launch_bounds__(256) void k_gemm_bf16(
    const unsigned short* __restrict__ Abf, const unsigned short* __restrict__ Wt,
    const float* __restrict__ b0, const float* __restrict__ b1,
    const float* __restrict__ b2, const float* __restrict__ b3,
    float* __restrict__ o0, float* __restrict__ o1, float* __restrict__ o2,
    float* __restrict__ o3) {
  __shared__ __attribute__((aligned(16))) unsigned short lA[BM * LDK];
  __shared__ __attribute__((aligned(16))) unsigned short lB[BN * LDK];
  const int z = blockIdx.z;
  const unsigned short* Wz = Wt + (size_t)z * D * D;
  const float* bias = (z == 0) ? b0 : (z == 1) ? b1 : (z == 2) ? b2 : b3;
  float* out = (z == 0) ? o0 : (z == 1) ? o1 : (z == 2) ? o2 : o3;
  const int bm = blockIdx.x * BM, bn = blockIdx.y * BN;
  const int t = threadIdx.x;
  const int lane = t & 63, wv = t >> 6;
  const int wm = (wv & 1) * 64, wn = (wv >> 1) * 64;
  const int l15 = lane & 15, l4 = lane >> 4;

  floatx4 acc[4][4] = {};

  for (int k0 = 0; k0 < D; k0 += BK) {
#pragma unroll
    for (int c = t; c < 512; c += 256) {
      int row = c >> 2, off = c & 3;
      int gm = bm + row;
      short8 va = {};
      if (gm < N_NODES)
        va = *(const short8*)(Abf + (size_t)gm * D + k0 + off * 8);
      *(short8*)(lA + row * LDK + off * 8) = va;
      short8 vb = *(const short8*)(Wz + (size_t)(bn + row) * D + k0 + off * 8);
      *(short8*)(lB + row * LDK + off * 8) = vb;
    }
    __syncthreads();
    short8 af[4], bfr[4];
#pragma unroll
    for (int i = 0; i < 4; ++i) {
      af[i] = *(const short8*)(lA + (wm + i * 16 + l15) * LDK + l4 * 8);
      bfr[i] = *(const short8*)(lB + (wn + i * 16 + l15) * LDK + l4 * 8);
    }
#pragma unroll
    for (int mi = 0; mi < 4; ++mi)
#pragma unroll
      for (int ni = 0; ni < 4; ++ni)
        acc[mi][ni] = __builtin_amdgcn_mfma_f32_16x16x32_bf16(af[mi], bfr[ni],
                                                              acc[mi][ni], 0, 0, 0);
    __syncthreads();
  }
#pragma unroll
  for (int mi = 0; mi < 4; ++mi)
#pragma unroll
    for (int ni = 0; ni < 4; ++ni)
#pragma unroll
      for (int r = 0; r < 4; ++r) {
        int row = bm + wm + mi * 16 + l4 * 4 + r;
        int col = bn + wn + ni * 16 + l15;
        if (row < N_NODES) out[(size_t)row * D + col] = acc[mi][ni][r] + bias[col];
      }
}

// ---- CSR build: histogram, scan, scatter ----
__global__ void k_hist(const int* __restrict__ dst, int* __restrict__ cnt) {
  int e = blockIdx.x * blockDim.x + threadIdx.x;
  if (e < N_EDGES) atomicAdd(&cnt[dst[e]], 1);
}

__global__ __launch_bounds__(1024) void k_scan(const int* __restrict__ cnt,
                                               int* __restrict__ start,
                                               int* __restrict__ cursor) {
  __shared__ int sh[1024];
  __shared__ int carry_sh;
  int tid = threadIdx.x;
  if (tid == 0) {
    carry_sh = 0;
    start[0] = 0;
  }
  __syncthreads();
  for (int base = 0; base < N_NODES; base += 1024) {
    int idx = base + tid;
    int v = (idx < N_NODES) ? cnt[idx] : 0;
    sh[tid] = v;
    __syncthreads();
    for (int off = 1; off < 1024; off <<= 1) {
      int t = (tid >= off) ? sh[tid - off] : 0;
      __syncthreads();
      sh[tid] += t;
      __syncthreads();
    }
    int incl = sh[tid] + carry_sh;
    if (idx < N_NODES) {
      start[idx + 1] = incl;
      cursor[idx] = incl - v;
    }
    __syncthreads();
    if (tid == 1023) carry_sh = incl;
    __syncthreads();
  }
}

__global__ void k_scatter(const int* __restrict__ src, const int* __restrict__ dst,
                          int* __restrict__ cursor, int* __restrict__ srcS,
                          int* __restrict__ permS) {
  int e = blockIdx.x * blockDim.x + threadIdx.x;
  if (e >= N_EDGES) return;
  int pos = atomicAdd(&cursor[dst[e]], 1);
  srcS[pos] = src[e];
  permS[pos] = e;
}

// ---- fused edge phase, wave per dst node ----
// score_e = (q[n].k[src_e] + sum_c ea[e,c]*(q[n].We[c,:])) * SCALE
// h[n] = skip[n] + (sum_e p_e*v[src_e] + (sum_e p_e*ea[e,:])@We) / (sum_e p_e + 1e-16)
__global__ __launch_bounds__(256) void k_edge_fused(
    float* __restrict__ h, unsigned short* __restrict__ hbf,
    const float* __restrict__ q, const float* __restrict__ k,
    const float* __restrict__ v, const float* __restrict__ ea,
    const float* __restrict__ We, const int* __restrict__ srcS,
    const int* __restrict__ permS, const int* __restrict__ start,
    float* __restrict__ sbuf, int do_relu) {
  int w = (blockIdx.x * blockDim.x + threadIdx.x) >> 6;
  int lane = threadIdx.x & 63;
  if (w >= N_NODES) return;
  const int s0 = start[w], s1 = start[w + 1];

  float qr[10];
#pragma unroll
  for (int i = 0; i < 10; ++i) qr[i] = q[(size_t)w * D + i * 64 + lane];

  // Gc on lane c (c<8): q[n] . We[c,:]
  float Gc = 0.f;
#pragma unroll
  for (int c = 0; c < ED_IN; ++c) {
    const float* wr = We + c * D;
    float p = 0.f;
#pragma unroll
    for (int i = 0; i < 10; ++i) p += qr[i] * wr[i * 64 + lane];
#pragma unroll
    for (int m = 1; m < 64; m <<= 1) p += __shfl_xor(p, m);
    if (lane == c) Gc = p;
  }

  // sweep 1: scores -> sbuf, running max
  float mx = -3.4e38f;
  for (int pos = s0; pos < s1; ++pos) {
    int sj = srcS[pos];
    int pe = permS[pos];
    const float* krow = k + (size_t)sj * D;
    float part = 0.f;
#pragma unroll
    for (int i = 0; i < 10; ++i) part += qr[i] * krow[i * 64 + lane];
    if (lane < ED_IN) part += ea[(size_t)pe * ED_IN + lane] * Gc;
#pragma unroll
    for (int m = 1; m < 64; m <<= 1) part += __shfl_xor(part, m);
    float sc = part * SCORE_SCALE;
    mx = fmaxf(mx, sc);
    if (lane == 0) sbuf[pos] = sc;
  }

  // sweep 2: Sp, Sp*v, Sp*ea
  float Sp = 0.f, Sea = 0.f;
  float acc[10];
#pragma unroll
  for (int i = 0; i < 10; ++i) acc[i] = 0.f;
  for (int pos = s0; pos < s1; ++pos) {
    int sj = srcS[pos];
    int pe = permS[pos];
    float p = __expf(sbuf[pos] - mx);
    Sp += p;
    const float* vrow = v + (size_t)sj * D;
#pragma unroll
    for (int i = 0; i < 10; ++i) acc[i] += p * vrow[i * 64 + lane];
    if (lane < ED_IN) Sea += p * ea[(size_t)pe * ED_IN + lane];
  }
  float inv = 1.0f / (Sp + 1e-16f);

  // epilogue: + (Sea @ We), skip, normalize, relu, dual write
  float seac[ED_IN];
#pragma unroll
  for (int c = 0; c < ED_IN; ++c) seac[c] = __shfl(Sea, c);
#pragma unroll
  for (int i = 0; i < 10; ++i) {
    int d = i * 64 + lane;
    float term = acc[i];
#pragma unroll
    for (int c = 0; c < ED_IN; ++c) term += seac[c] * We[c * D + d];
    float val = h[(size_t)w * D + d] + term * inv;
    if (do_relu) val = fmaxf(val, 0.f);
    h[(size_t)w * D + d] = val;
    hbf[(size_t)w * D + d] = f2bf(val);
  }
}

// global add pool: pooled[batch[n], d] += h[n, d]
__global__ void k_pool(const float* __restrict__ h, const int* __restrict__ bat,
                       float* __restrict__ pooled) {
  int t = blockIdx.x * blockDim.x + threadIdx.x;
  if (t >= N_NODES * D) return;
  int n = t / D, d = t % D;
  atomicAdd(pooled + (size_t)bat[n] * D + d, h[t]);
}

// per graph row: LayerNorm -> @Wemb + bemb -> ReLU
__global__ __launch_bounds__(256) void k_head(const float* __restrict__ pooled,
                                              const float* __restrict__ gam,
                                              const float* __restrict__ bet,
                                              const float* __restrict__ Wemb,
                                              const float* __restrict__ bemb,
                                              float* __restrict__ z) {
  __shared__ float sh[D];
  __shared__ float red[4];
  int b = blockIdx.x, tid = threadIdx.x;
  float local = 0.f;
  for (int c = tid; c < D; c += 256) {
    float val = pooled[(size_t)b * D + c];
    sh[c] = val;
    local += val;
  }
#pragma unroll
  for (int off = 32; off > 0; off >>= 1) local += __shfl_down(local, off);
  if ((tid & 63) == 0) red[tid >> 6] = local;
  __syncthreads();
  float mu = (red[0] + red[1] + red[2] + red[3]) * (1.0f / D);
  __syncthreads();
  float lv = 0.f;
  for (int c = tid; c < D; c += 256) {
    float t2 = sh[c] - mu;
    lv += t2 * t2;
  }
#pragma unroll
  for (int off = 32; off > 0; off >>= 1) lv += __shfl_down(lv, off);
  if ((tid & 63) == 0) red[tid >> 6] = lv;
  __syncthreads();
  float var = (red[0] + red[1] + red[2] + red[3]) * (1.0f / D);
  float rstd = rsqrtf(var + 1e-5f);
  __syncthreads();
  for (int c = tid; c < D; c += 256) sh[c] = (sh[c] - mu) * rstd * gam[c] + bet[c];
  __syncthreads();
  for (int d = tid; d < D; d += 256) {
    float acc = bemb[d];
    for (int c = 0; c < D; ++c) acc += sh[c] * Wemb[c * D + d];
    z[(size_t)b * D + d] = fmaxf(acc, 0.f);
  }
}

__global__ void k_cosine(const float* __restrict__ zi, const float* __restrict__ zj,
                         float* __restrict__ out) {
  int b = blockIdx.x, lane = threadIdx.x;
  float dot = 0.f, ni = 0.f, nj = 0.f;
  for (int d = lane; d < D; d += 64) {
    float a = zi[(size_t)b * D + d], c = zj[(size_t)b * D + d];
    dot += a * c;
    ni += a * a;
    nj += c * c;
  }
#pragma unroll
  for (int off = 32; off > 0; off >>= 1) {
    dot += __shfl_down(dot, off);
    ni += __shfl_down(ni, off);
    nj += __shfl_down(nj, off);
  }
  if (lane == 0)
    out[b] = dot / (fmaxf(sqrtf(ni), 1e-8f) * fmaxf(sqrtf(nj), 1e-8f));
}

extern "C" void kernel_launch(void* const* d_in, const int* in_sizes, int n_in,
                              void* d_out, int out_size, void* d_ws, size_t ws_size,
                              hipStream_t stream) {
  (void)in_sizes; (void)n_in; (void)out_size; (void)ws_size;
  const float* W0q = (const float*)d_in[8];
  const float* b0q = (const float*)d_in[9];
  const float* W0k = (const float*)d_in[10];
  const float* b0k = (const float*)d_in[11];
  const float* W0v = (const float*)d_in[12];
  const float* b0v = (const float*)d_in[13];
  const float* W0e = (const float*)d_in[14];
  const float* W0s = (const float*)d_in[15];
  const float* b0s = (const float*)d_in[16];
  const float* Wq = (const float*)d_in[17];
  const float* bq = (const float*)d_in[18];
  const float* Wk = (const float*)d_in[19];
  const float* bk = (const float*)d_in[20];
  const float* Wv = (const float*)d_in[21];
  const float* bv = (const float*)d_in[22];
  const float* We = (const float*)d_in[23];
  const float* Ws = (const float*)d_in[24];
  const float* bs = (const float*)d_in[25];
  const float* ln_g = (const float*)d_in[26];
  const float* ln_b = (const float*)d_in[27];
  const float* Wemb = (const float*)d_in[28];
  const float* bemb = (const float*)d_in[29];

  const size_t NDt = (size_t)N_NODES * D;
  float* h = (float*)d_ws;  // skip + agg target / layer output
  float* qb = h + NDt;
  float* kb = qb + NDt;
  float* vb = kb + NDt;
  float* sbuf = vb + NDt;                // E scores
  float* pooled = sbuf + N_EDGES;        // B*D
  float* z0 = pooled + (size_t)NB * D;   // B*D
  float* z1 = z0 + (size_t)NB * D;       // B*D
  unsigned short* hbf = (unsigned short*)(z1 + (size_t)NB * D);  // NDt bf16
  unsigned short* Wt = hbf + NDt;        // 20*D*D bf16
  int* cnt = (int*)(Wt + (size_t)(NLAYERS - 1) * 4 * D * D);  // N
  int* start = cnt + N_NODES;            // N+1
  int* cursor = start + N_NODES + 1;     // N
  int* srcS = cursor + N_NODES;          // E
  int* permS = srcS + N_EDGES;           // E

  dim3 gLin4((N_NODES * D + 255) / 256, 1, 4);
  dim3 gGemm((N_NODES + BM - 1) / BM, D / BN, 4);
  dim3 gEdge((N_NODES + 3) / 4);  // 4 waves/block, wave per node
  dim3 gE((N_EDGES + 255) / 256);
  dim3 gPool((N_NODES * D + 255) / 256);

  k_wprep<<<dim3(D / 32, D / 32, (NLAYERS - 1) * 4), 256, 0, stream>>>(Wq, Wk, Wv, Ws, Wt);

  for (int g = 0; g < 2; ++g) {
    const float* x = (const float*)d_in[g ? 4 : 0];
    const int* ei = (const int*)d_in[g ? 5 : 1];
    const float* ea = (const float*)d_in[g ? 6 : 2];
    const int* bat = (const int*)d_in[g ? 7 : 3];
    const int* srcI = ei;
    const int* dstI = ei + N_EDGES;

    // CSR by dst
    hipMemsetAsync(cnt, 0, N_NODES * sizeof(int), stream);
    k_hist<<<gE, 256, 0, stream>>>(dstI, cnt);
    k_scan<<<1, 1024, 0, stream>>>(cnt, start, cursor);
    k_scatter<<<gE, 256, 0, stream>>>(srcI, dstI, cursor, srcS, permS);

    // layer 0 (fp32 small projections from x)
    k_lin4<<<gLin4, 256, 0, stream>>>(x, W0q, b0q, W0k, b0k, W0v, b0v, W0s, b0s,
                                      qb, kb, vb, h);
    k_edge_fused<<<gEdge, 256, 0, stream>>>(h, hbf, qb, kb, vb, ea, W0e, srcS,
                                            permS, start, sbuf, 1);

    // layers 1..5
    for (int l = 0; l < NLAYERS - 1; ++l) {
      const unsigned short* WtL = Wt + (size_t)l * 4 * D * D;
      const float* Wel = We + (size_t)l * ED_IN * D;
      k_gemm_bf16<<<gGemm, 256, 0, stream>>>(
          hbf, WtL, bq + (size_t)l * D, bk + (size_t)l * D, bv + (size_t)l * D,
          bs + (size_t)l * D, qb, kb, vb, h);
      k_edge_fused<<<gEdge, 256, 0, stream>>>(h, hbf, qb, kb, vb, ea, Wel, srcS,
                                              permS, start, sbuf,
                                              (l < NLAYERS - 2) ? 1 : 0);
    }

    hipMemsetAsync(pooled, 0, (size_t)NB * D * sizeof(float), stream);
    k_pool<<<gPool, 256, 0, stream>>>(h, bat, pooled);
    k_head<<<NB, 256, 0, stream>>>(pooled, ln_g, ln_b, Wemb, bemb, g ? z1 : z0);
  }
  k_cosine<<<NB, 64, 0, stream>>>(z0, z1, (float*)d_out);
}

// Round 4
// 2656.158 us; speedup vs baseline: 4.5007x; 1.2109x over previous
//
#include <hip/hip_runtime.h>

#define N_NODES 10000
#define N_EDGES 160000
#define NB 64
#define D 640
#define ND_IN 4
#define ED_IN 8
#define NLAYERS 6

#define SCORE_SCALE 0.039528470752104741f  // 1/sqrt(640)

typedef __attribute__((ext_vector_type(8))) short short8;
typedef __attribute__((ext_vector_type(4))) float floatx4;

__device__ __forceinline__ unsigned short f2bf(float f) {
  unsigned u = __float_as_uint(f);
  u += 0x7fffu + ((u >> 16) & 1);  // RNE
  return (unsigned short)(u >> 16);
}
__device__ __forceinline__ float bf2f(unsigned short s) {
  return __uint_as_float((unsigned)s << 16);
}

// ---- layer-0 projections: q,skip fp32; k,v bf16 ----
__global__ void k_lin4(const float* __restrict__ X, const float* __restrict__ Wq,
                       const float* __restrict__ bq, const float* __restrict__ Wk,
                       const float* __restrict__ bk, const float* __restrict__ Wv,
                       const float* __restrict__ bv, const float* __restrict__ Ws,
                       const float* __restrict__ bs, float* __restrict__ oq,
                       unsigned short* __restrict__ okb, unsigned short* __restrict__ ovb,
                       float* __restrict__ oh) {
  int t = blockIdx.x * blockDim.x + threadIdx.x;
  if (t >= N_NODES * D) return;
  int z = blockIdx.z;
  const float* W = (z == 0) ? Wq : (z == 1) ? Wk : (z == 2) ? Wv : Ws;
  const float* b = (z == 0) ? bq : (z == 1) ? bk : (z == 2) ? bv : bs;
  int n = t / D, d = t % D;
  float acc = b[d];
#pragma unroll
  for (int c = 0; c < ND_IN; ++c) acc += X[n * ND_IN + c] * W[c * D + d];
  if (z == 0) oq[t] = acc;
  else if (z == 1) okb[t] = f2bf(acc);
  else if (z == 2) ovb[t] = f2bf(acc);
  else oh[t] = acc;
}

// one-time: Wt[l][mat][n][k] = bf16(W[l][mat][k][n])
__global__ __launch_bounds__(256) void k_wprep(const float* __restrict__ Wq,
                                               const float* __restrict__ Wk,
                                               const float* __restrict__ Wv,
                                               const float* __restrict__ Ws,
                                               unsigned short* __restrict__ Wt) {
  __shared__ float tile[32][33];
  int mt = blockIdx.z;
  int l = mt >> 2, mat = mt & 3;
  const float* W =
      (mat == 0 ? Wq : mat == 1 ? Wk : mat == 2 ? Wv : Ws) + (size_t)l * D * D;
  int tk = blockIdx.x * 32, tn = blockIdx.y * 32;
  int tx = threadIdx.x & 31, ty = threadIdx.x >> 5;
#pragma unroll
  for (int i = 0; i < 32; i += 8)
    tile[ty + i][tx] = W[(size_t)(tk + ty + i) * D + tn + tx];
  __syncthreads();
  unsigned short* dst = Wt + (size_t)mt * D * D;
#pragma unroll
  for (int i = 0; i < 32; i += 8)
    dst[(size_t)(tn + ty + i) * D + tk + tx] = f2bf(tile[tx][ty + i]);
}

// bf16 MFMA GEMM, z in {q,k,v,s}: q,s -> fp32; k,v -> bf16
#define BM 128
#define BN 128
#define BK 32
#define LDK 40
__global__ __launch_bounds__(256) void k_gemm_bf16(
    const unsigned short* __restrict__ Abf, const unsigned short* __restrict__ Wt,
    const float* __restrict__ b0, const float* __restrict__ b1,
    const float* __restrict__ b2, const float* __restrict__ b3,
    float* __restrict__ oq, unsigned short* __restrict__ okb,
    unsigned short* __restrict__ ovb, float* __restrict__ oh) {
  __shared__ __attribute__((aligned(16))) unsigned short lA[BM * LDK];
  __shared__ __attribute__((aligned(16))) unsigned short lB[BN * LDK];
  const int z = blockIdx.z;
  const unsigned short* Wz = Wt + (size_t)z * D * D;
  const float* bias = (z == 0) ? b0 : (z == 1) ? b1 : (z == 2) ? b2 : b3;
  const int bm = blockIdx.x * BM, bn = blockIdx.y * BN;
  const int t = threadIdx.x;
  const int lane = t & 63, wv = t >> 6;
  const int wm = (wv & 1) * 64, wn = (wv >> 1) * 64;
  const int l15 = lane & 15, l4 = lane >> 4;

  floatx4 acc[4][4] = {};

  for (int k0 = 0; k0 < D; k0 += BK) {
#pragma unroll
    for (int c = t; c < 512; c += 256) {
      int row = c >> 2, off = c & 3;
      int gm = bm + row;
      short8 va = {};
      if (gm < N_NODES)
        va = *(const short8*)(Abf + (size_t)gm * D + k0 + off * 8);
      *(short8*)(lA + row * LDK + off * 8) = va;
      short8 vb = *(const short8*)(Wz + (size_t)(bn + row) * D + k0 + off * 8);
      *(short8*)(lB + row * LDK + off * 8) = vb;
    }
    __syncthreads();
    short8 af[4], bfr[4];
#pragma unroll
    for (int i = 0; i < 4; ++i) {
      af[i] = *(const short8*)(lA + (wm + i * 16 + l15) * LDK + l4 * 8);
      bfr[i] = *(const short8*)(lB + (wn + i * 16 + l15) * LDK + l4 * 8);
    }
#pragma unroll
    for (int mi = 0; mi < 4; ++mi)
#pragma unroll
      for (int ni = 0; ni < 4; ++ni)
        acc[mi][ni] = __builtin_amdgcn_mfma_f32_16x16x32_bf16(af[mi], bfr[ni],
                                                              acc[mi][ni], 0, 0, 0);
    __syncthreads();
  }
  const bool isbf = (z == 1 || z == 2);
  unsigned short* ob = (z == 1) ? okb : ovb;
  float* of = (z == 0) ? oq : oh;
#pragma unroll
  for (int mi = 0; mi < 4; ++mi)
#pragma unroll
    for (int ni = 0; ni < 4; ++ni)
#pragma unroll
      for (int r = 0; r < 4; ++r) {
        int row = bm + wm + mi * 16 + l4 * 4 + r;
        int col = bn + wn + ni * 16 + l15;
        if (row < N_NODES) {
          float val = acc[mi][ni][r] + bias[col];
          if (isbf) ob[(size_t)row * D + col] = f2bf(val);
          else of[(size_t)row * D + col] = val;
        }
      }
}

// ---- CSR build: histogram, scan, scatter ----
__global__ void k_hist(const int* __restrict__ dst, int* __restrict__ cnt) {
  int e = blockIdx.x * blockDim.x + threadIdx.x;
  if (e < N_EDGES) atomicAdd(&cnt[dst[e]], 1);
}

__global__ __launch_bounds__(1024) void k_scan(const int* __restrict__ cnt,
                                               int* __restrict__ start,
                                               int* __restrict__ cursor) {
  __shared__ int sh[1024];
  __shared__ int carry_sh;
  int tid = threadIdx.x;
  if (tid == 0) {
    carry_sh = 0;
    start[0] = 0;
  }
  __syncthreads();
  for (int base = 0; base < N_NODES; base += 1024) {
    int idx = base + tid;
    int v = (idx < N_NODES) ? cnt[idx] : 0;
    sh[tid] = v;
    __syncthreads();
    for (int off = 1; off < 1024; off <<= 1) {
      int t = (tid >= off) ? sh[tid - off] : 0;
      __syncthreads();
      sh[tid] += t;
      __syncthreads();
    }
    int incl = sh[tid] + carry_sh;
    if (idx < N_NODES) {
      start[idx + 1] = incl;
      cursor[idx] = incl - v;
    }
    __syncthreads();
    if (tid == 1023) carry_sh = incl;
    __syncthreads();
  }
}

__global__ void k_scatter(const int* __restrict__ src, const int* __restrict__ dst,
                          int* __restrict__ cursor, int* __restrict__ srcS,
                          int* __restrict__ permS) {
  int e = blockIdx.x * blockDim.x + threadIdx.x;
  if (e >= N_EDGES) return;
  int pos = atomicAdd(&cursor[dst[e]], 1);
  srcS[pos] = src[e];
  permS[pos] = e;
}

// ---- fused edge phase: wave per dst node, single sweep, online softmax ----
// bf16 k/v gathers; lane layout d = i*128 + 2*lane + {0,1}
__global__ __launch_bounds__(256) void k_edge_fused(
    float* __restrict__ h, unsigned short* __restrict__ hbf,
    const float* __restrict__ q, const unsigned short* __restrict__ kb16,
    const unsigned short* __restrict__ vb16, const float* __restrict__ ea,
    const float* __restrict__ We, const int* __restrict__ srcS,
    const int* __restrict__ permS, const int* __restrict__ start, int do_relu) {
  int w = (blockIdx.x * blockDim.x + threadIdx.x) >> 6;
  int lane = threadIdx.x & 63;
  if (w >= N_NODES) return;
  const int s0 = start[w], s1 = start[w + 1];

  float2 qr[5];
#pragma unroll
  for (int i = 0; i < 5; ++i)
    qr[i] = *(const float2*)(q + (size_t)w * D + i * 128 + 2 * lane);

  // Gc on lane c (c<8): q[n] . We[c,:]
  float Gc = 0.f;
#pragma unroll
  for (int c = 0; c < ED_IN; ++c) {
    const float* wr = We + c * D;
    float p = 0.f;
#pragma unroll
    for (int i = 0; i < 5; ++i) {
      float2 wv = *(const float2*)(wr + i * 128 + 2 * lane);
      p += qr[i].x * wv.x + qr[i].y * wv.y;
    }
#pragma unroll
    for (int m = 1; m < 64; m <<= 1) p += __shfl_xor(p, m);
    if (lane == c) Gc = p;
  }

  float mx = -3.4e38f, Sp = 0.f, Sea = 0.f;
  float2 acc[5];
#pragma unroll
  for (int i = 0; i < 5; ++i) acc[i] = make_float2(0.f, 0.f);

  for (int pos = s0; pos < s1; ++pos) {
    int sj = srcS[pos];
    int pe = permS[pos];
    const unsigned short* krow = kb16 + (size_t)sj * D;
    const unsigned short* vrow = vb16 + (size_t)sj * D;
    float part = 0.f;
    float2 vv[5];
#pragma unroll
    for (int i = 0; i < 5; ++i) {
      ushort2 kc = *(const ushort2*)(krow + i * 128 + 2 * lane);
      ushort2 vc = *(const ushort2*)(vrow + i * 128 + 2 * lane);
      vv[i].x = bf2f(vc.x);
      vv[i].y = bf2f(vc.y);
      part += qr[i].x * bf2f(kc.x) + qr[i].y * bf2f(kc.y);
    }
    float eaL = (lane < ED_IN) ? ea[(size_t)pe * ED_IN + lane] : 0.f;
    part += eaL * Gc;
#pragma unroll
    for (int m = 1; m < 64; m <<= 1) part += __shfl_xor(part, m);
    float sc = part * SCORE_SCALE;
    float mn = fmaxf(mx, sc);
    float cs = __expf(mx - mn);
    float p = __expf(sc - mn);
    mx = mn;
    Sp = Sp * cs + p;
#pragma unroll
    for (int i = 0; i < 5; ++i) {
      acc[i].x = acc[i].x * cs + p * vv[i].x;
      acc[i].y = acc[i].y * cs + p * vv[i].y;
    }
    Sea = Sea * cs + p * eaL;
  }
  float inv = 1.0f / (Sp + 1e-16f);

  float seac[ED_IN];
#pragma unroll
  for (int c = 0; c < ED_IN; ++c) seac[c] = __shfl(Sea, c);
#pragma unroll
  for (int i = 0; i < 5; ++i) {
    int d = i * 128 + 2 * lane;
    float2 term = acc[i];
#pragma unroll
    for (int c = 0; c < ED_IN; ++c) {
      term.x += seac[c] * We[c * D + d];
      term.y += seac[c] * We[c * D + d + 1];
    }
    float2 hv = *(const float2*)(h + (size_t)w * D + d);
    float vx = hv.x + term.x * inv;
    float vy = hv.y + term.y * inv;
    if (do_relu) {
      vx = fmaxf(vx, 0.f);
      vy = fmaxf(vy, 0.f);
    }
    *(float2*)(h + (size_t)w * D + d) = make_float2(vx, vy);
    ushort2 hb;
    hb.x = f2bf(vx);
    hb.y = f2bf(vy);
    *(ushort2*)(hbf + (size_t)w * D + d) = hb;
  }
}

// global add pool: pooled[batch[n], d] += h[n, d]
__global__ void k_pool(const float* __restrict__ h, const int* __restrict__ bat,
                       float* __restrict__ pooled) {
  int t = blockIdx.x * blockDim.x + threadIdx.x;
  if (t >= N_NODES * D) return;
  int n = t / D, d = t % D;
  atomicAdd(pooled + (size_t)bat[n] * D + d, h[t]);
}

// per graph row: LayerNorm -> @Wemb + bemb -> ReLU
__global__ __launch_bounds__(256) void k_head(const float* __restrict__ pooled,
                                              const float* __restrict__ gam,
                                              const float* __restrict__ bet,
                                              const float* __restrict__ Wemb,
                                              const float* __restrict__ bemb,
                                              float* __restrict__ z) {
  __shared__ float sh[D];
  __shared__ float red[4];
  int b = blockIdx.x, tid = threadIdx.x;
  float local = 0.f;
  for (int c = tid; c < D; c += 256) {
    float val = pooled[(size_t)b * D + c];
    sh[c] = val;
    local += val;
  }
#pragma unroll
  for (int off = 32; off > 0; off >>= 1) local += __shfl_down(local, off);
  if ((tid & 63) == 0) red[tid >> 6] = local;
  __syncthreads();
  float mu = (red[0] + red[1] + red[2] + red[3]) * (1.0f / D);
  __syncthreads();
  float lv = 0.f;
  for (int c = tid; c < D; c += 256) {
    float t2 = sh[c] - mu;
    lv += t2 * t2;
  }
#pragma unroll
  for (int off = 32; off > 0; off >>= 1) lv += __shfl_down(lv, off);
  if ((tid & 63) == 0) red[tid >> 6] = lv;
  __syncthreads();
  float var = (red[0] + red[1] + red[2] + red[3]) * (1.0f / D);
  float rstd = rsqrtf(var + 1e-5f);
  __syncthreads();
  for (int c = tid; c < D; c += 256) sh[c] = (sh[c] - mu) * rstd * gam[c] + bet[c];
  __syncthreads();
  for (int d = tid; d < D; d += 256) {
    float acc = bemb[d];
    for (int c = 0; c < D; ++c) acc += sh[c] * Wemb[c * D + d];
    z[(size_t)b * D + d] = fmaxf(acc, 0.f);
  }
}

__global__ void k_cosine(const float* __restrict__ zi, const float* __restrict__ zj,
                         float* __restrict__ out) {
  int b = blockIdx.x, lane = threadIdx.x;
  float dot = 0.f, ni = 0.f, nj = 0.f;
  for (int d = lane; d < D; d += 64) {
    float a = zi[(size_t)b * D + d], c = zj[(size_t)b * D + d];
    dot += a * c;
    ni += a * a;
    nj += c * c;
  }
#pragma unroll
  for (int off = 32; off > 0; off >>= 1) {
    dot += __shfl_down(dot, off);
    ni += __shfl_down(ni, off);
    nj += __shfl_down(nj, off);
  }
  if (lane == 0)
    out[b] = dot / (fmaxf(sqrtf(ni), 1e-8f) * fmaxf(sqrtf(nj), 1e-8f));
}

extern "C" void kernel_launch(void* const* d_in, const int* in_sizes, int n_in,
                              void* d_out, int out_size, void* d_ws, size_t ws_size,
                              hipStream_t stream) {
  (void)in_sizes; (void)n_in; (void)out_size; (void)ws_size;
  const float* W0q = (const float*)d_in[8];
  const float* b0q = (const float*)d_in[9];
  const float* W0k = (const float*)d_in[10];
  const float* b0k = (const float*)d_in[11];
  const float* W0v = (const float*)d_in[12];
  const float* b0v = (const float*)d_in[13];
  const float* W0e = (const float*)d_in[14];
  const float* W0s = (const float*)d_in[15];
  const float* b0s = (const float*)d_in[16];
  const float* Wq = (const float*)d_in[17];
  const float* bq = (const float*)d_in[18];
  const float* Wk = (const float*)d_in[19];
  const float* bk = (const float*)d_in[20];
  const float* Wv = (const float*)d_in[21];
  const float* bv = (const float*)d_in[22];
  const float* We = (const float*)d_in[23];
  const float* Ws = (const float*)d_in[24];
  const float* bs = (const float*)d_in[25];
  const float* ln_g = (const float*)d_in[26];
  const float* ln_b = (const float*)d_in[27];
  const float* Wemb = (const float*)d_in[28];
  const float* bemb = (const float*)d_in[29];

  const size_t NDt = (size_t)N_NODES * D;
  float* h = (float*)d_ws;
  float* qb = h + NDt;
  float* pooled = qb + NDt;              // B*D
  float* z0 = pooled + (size_t)NB * D;   // B*D
  float* z1 = z0 + (size_t)NB * D;       // B*D
  unsigned short* kbf = (unsigned short*)(z1 + (size_t)NB * D);  // NDt
  unsigned short* vbf = kbf + NDt;       // NDt
  unsigned short* hbf = vbf + NDt;       // NDt
  unsigned short* Wt = hbf + NDt;        // 20*D*D
  int* cnt = (int*)(Wt + (size_t)(NLAYERS - 1) * 4 * D * D);  // N
  int* start = cnt + N_NODES;            // N+1
  int* cursor = start + N_NODES + 1;     // N
  int* srcS = cursor + N_NODES;          // E
  int* permS = srcS + N_EDGES;           // E

  dim3 gLin4((N_NODES * D + 255) / 256, 1, 4);
  dim3 gGemm((N_NODES + BM - 1) / BM, D / BN, 4);
  dim3 gEdge((N_NODES + 3) / 4);
  dim3 gE((N_EDGES + 255) / 256);
  dim3 gPool((N_NODES * D + 255) / 256);

  k_wprep<<<dim3(D / 32, D / 32, (NLAYERS - 1) * 4), 256, 0, stream>>>(Wq, Wk, Wv, Ws, Wt);

  for (int g = 0; g < 2; ++g) {
    const float* x = (const float*)d_in[g ? 4 : 0];
    const int* ei = (const int*)d_in[g ? 5 : 1];
    const float* ea = (const float*)d_in[g ? 6 : 2];
    const int* bat = (const int*)d_in[g ? 7 : 3];
    const int* srcI = ei;
    const int* dstI = ei + N_EDGES;

    hipMemsetAsync(cnt, 0, N_NODES * sizeof(int), stream);
    k_hist<<<gE, 256, 0, stream>>>(dstI, cnt);
    k_scan<<<1, 1024, 0, stream>>>(cnt, start, cursor);
    k_scatter<<<gE, 256, 0, stream>>>(srcI, dstI, cursor, srcS, permS);

    k_lin4<<<gLin4, 256, 0, stream>>>(x, W0q, b0q, W0k, b0k, W0v, b0v, W0s, b0s,
                                      qb, kbf, vbf, h);
    k_edge_fused<<<gEdge, 256, 0, stream>>>(h, hbf, qb, kbf, vbf, ea, W0e, srcS,
                                            permS, start, 1);

    for (int l = 0; l < NLAYERS - 1; ++l) {
      const unsigned short* WtL = Wt + (size_t)l * 4 * D * D;
      const float* Wel = We + (size_t)l * ED_IN * D;
      k_gemm_bf16<<<gGemm, 256, 0, stream>>>(
          hbf, WtL, bq + (size_t)l * D, bk + (size_t)l * D, bv + (size_t)l * D,
          bs + (size_t)l * D, qb, kbf, vbf, h);
      k_edge_fused<<<gEdge, 256, 0, stream>>>(h, hbf, qb, kbf, vbf, ea, Wel, srcS,
                                              permS, start, (l < NLAYERS - 2) ? 1 : 0);
    }

    hipMemsetAsync(pooled, 0, (size_t)NB * D * sizeof(float), stream);
    k_pool<<<gPool, 256, 0, stream>>>(h, bat, pooled);
    k_head<<<NB, 256, 0, stream>>>(pooled, ln_g, ln_b, Wemb, bemb, g ? z1 : z0);
  }
  k_cosine<<<NB, 64, 0, stream>>>(z0, z1, (float*)d_out);
}

// Round 5
// 2070.674 us; speedup vs baseline: 5.7733x; 1.2828x over previous
//
#include <hip/hip_runtime.h>

#define N_NODES 10000
#define N_EDGES 160000
#define NB 64
#define D 640
#define ND_IN 4
#define ED_IN 8
#define NLAYERS 6
#define M_ROWS (2 * N_NODES)  // both graphs batched

#define SCORE_SCALE 0.039528470752104741f  // 1/sqrt(640)

typedef __attribute__((ext_vector_type(8))) short short8;
typedef __attribute__((ext_vector_type(4))) float floatx4;

__device__ __forceinline__ unsigned short f2bf(float f) {
  unsigned u = __float_as_uint(f);
  u += 0x7fffu + ((u >> 16) & 1);  // RNE
  return (unsigned short)(u >> 16);
}
__device__ __forceinline__ float bf2f(unsigned short s) {
  return __uint_as_float((unsigned)s << 16);
}
__device__ __forceinline__ void gload_lds16(const void* g, void* l) {
  __builtin_amdgcn_global_load_lds(
      (const __attribute__((address_space(1))) void*)g,
      (__attribute__((address_space(3))) void*)l, 16, 0, 0);
}

// ---- layer-0 projections over both graphs: q,k,v bf16; skip fp32 ----
__global__ void k_lin4(const float* __restrict__ xI, const float* __restrict__ xJ,
                       const float* __restrict__ Wq, const float* __restrict__ bq,
                       const float* __restrict__ Wk, const float* __restrict__ bk,
                       const float* __restrict__ Wv, const float* __restrict__ bv,
                       const float* __restrict__ Ws, const float* __restrict__ bs,
                       unsigned short* __restrict__ oqb, unsigned short* __restrict__ okb,
                       unsigned short* __restrict__ ovb, float* __restrict__ oh) {
  int t = blockIdx.x * blockDim.x + threadIdx.x;
  if (t >= M_ROWS * D) return;
  int z = blockIdx.z;
  const float* W = (z == 0) ? Wq : (z == 1) ? Wk : (z == 2) ? Wv : Ws;
  const float* b = (z == 0) ? bq : (z == 1) ? bk : (z == 2) ? bv : bs;
  int n = t / D, d = t % D;
  const float* xr = (n < N_NODES) ? xI + (size_t)n * ND_IN
                                  : xJ + (size_t)(n - N_NODES) * ND_IN;
  float acc = b[d];
#pragma unroll
  for (int c = 0; c < ND_IN; ++c) acc += xr[c] * W[c * D + d];
  if (z == 0) oqb[t] = f2bf(acc);
  else if (z == 1) okb[t] = f2bf(acc);
  else if (z == 2) ovb[t] = f2bf(acc);
  else oh[t] = acc;
}

// one-time: Wt[l][mat][n][k] = bf16(W[l][mat][k][n])
__global__ __launch_bounds__(256) void k_wprep(const float* __restrict__ Wq,
                                               const float* __restrict__ Wk,
                                               const float* __restrict__ Wv,
                                               const float* __restrict__ Ws,
                                               unsigned short* __restrict__ Wt) {
  __shared__ float tile[32][33];
  int mt = blockIdx.z;
  int l = mt >> 2, mat = mt & 3;
  const float* W =
      (mat == 0 ? Wq : mat == 1 ? Wk : mat == 2 ? Wv : Ws) + (size_t)l * D * D;
  int tk = blockIdx.x * 32, tn = blockIdx.y * 32;
  int tx = threadIdx.x & 31, ty = threadIdx.x >> 5;
#pragma unroll
  for (int i = 0; i < 32; i += 8)
    tile[ty + i][tx] = W[(size_t)(tk + ty + i) * D + tn + tx];
  __syncthreads();
  unsigned short* dst = Wt + (size_t)mt * D * D;
#pragma unroll
  for (int i = 0; i < 32; i += 8)
    dst[(size_t)(tn + ty + i) * D + tk + tx] = f2bf(tile[tx][ty + i]);
}

// bf16 MFMA GEMM over 2N rows, m97-style global_load_lds staging.
// LDS tile [row][BK] unpadded; colblk XOR-swizzle c^((row>>1)&3) -> 2-way
// bank aliasing on ds_read_b128 (free per m136).
#define BM 128
#define BN 128
#define BK 32
__global__ __launch_bounds__(256) void k_gemm_bf16(
    const unsigned short* __restrict__ Abf, const unsigned short* __restrict__ Wt,
    const float* __restrict__ b0, const float* __restrict__ b1,
    const float* __restrict__ b2, const float* __restrict__ b3,
    unsigned short* __restrict__ oqb, unsigned short* __restrict__ okb,
    unsigned short* __restrict__ ovb, float* __restrict__ oh) {
  __shared__ __attribute__((aligned(16))) unsigned short lA[BM * BK];
  __shared__ __attribute__((aligned(16))) unsigned short lB[BN * BK];
  const int z = blockIdx.z;
  const unsigned short* Wz = Wt + (size_t)z * D * D;
  const float* bias = (z == 0) ? b0 : (z == 1) ? b1 : (z == 2) ? b2 : b3;
  const int bm = blockIdx.x * BM, bn = blockIdx.y * BN;
  const int t = threadIdx.x;
  const int lane = t & 63, wv = t >> 6;
  const int wm = (wv & 1) * 64, wn = (wv >> 1) * 64;
  const int l15 = lane & 15, l4 = lane >> 4;
  const int r16 = lane >> 2;  // staging: row within 16-row chunk
  const int cb = lane & 3;    // staging: physical colblk

  floatx4 acc[4][4] = {};

  for (int k0 = 0; k0 < D; k0 += BK) {
#pragma unroll
    for (int i = 0; i < 2; ++i) {
      int row = wv * 32 + i * 16 + r16;
      int lcb = cb ^ ((row >> 1) & 3);  // logical colblk stored at physical cb
      gload_lds16(Abf + (size_t)(bm + row) * D + k0 + lcb * 8,
                  lA + (size_t)(wv * 32 + i * 16) * BK);
      gload_lds16(Wz + (size_t)(bn + row) * D + k0 + lcb * 8,
                  lB + (size_t)(wv * 32 + i * 16) * BK);
    }
    __syncthreads();
    short8 af[4], bfr[4];
#pragma unroll
    for (int i = 0; i < 4; ++i) {
      int rowA = wm + i * 16 + l15;
      af[i] = *(const short8*)(lA + rowA * BK + (l4 ^ ((rowA >> 1) & 3)) * 8);
      int rowB = wn + i * 16 + l15;
      bfr[i] = *(const short8*)(lB + rowB * BK + (l4 ^ ((rowB >> 1) & 3)) * 8);
    }
#pragma unroll
    for (int mi = 0; mi < 4; ++mi)
#pragma unroll
      for (int ni = 0; ni < 4; ++ni)
        acc[mi][ni] = __builtin_amdgcn_mfma_f32_16x16x32_bf16(af[mi], bfr[ni],
                                                              acc[mi][ni], 0, 0, 0);
    __syncthreads();
  }
  unsigned short* ob = (z == 0) ? oqb : (z == 1) ? okb : ovb;
#pragma unroll
  for (int mi = 0; mi < 4; ++mi)
#pragma unroll
    for (int ni = 0; ni < 4; ++ni)
#pragma unroll
      for (int r = 0; r < 4; ++r) {
        int row = bm + wm + mi * 16 + l4 * 4 + r;
        int col = bn + wn + ni * 16 + l15;
        if (row < M_ROWS) {
          float val = acc[mi][ni][r] + bias[col];
          if (z == 3) oh[(size_t)row * D + col] = val;
          else ob[(size_t)row * D + col] = f2bf(val);
        }
      }
}

// ---- combined-graph CSR build ----
__global__ void k_hist(const int* __restrict__ dstI, const int* __restrict__ dstJ,
                       int* __restrict__ cnt) {
  int e = blockIdx.x * blockDim.x + threadIdx.x;
  if (e >= 2 * N_EDGES) return;
  int d = (e < N_EDGES) ? dstI[e] : (dstJ[e - N_EDGES] + N_NODES);
  atomicAdd(&cnt[d], 1);
}

__global__ __launch_bounds__(1024) void k_scan(const int* __restrict__ cnt,
                                               int* __restrict__ start,
                                               int* __restrict__ cursor) {
  __shared__ int sh[1024];
  __shared__ int carry_sh;
  int tid = threadIdx.x;
  if (tid == 0) {
    carry_sh = 0;
    start[0] = 0;
  }
  __syncthreads();
  for (int base = 0; base < M_ROWS; base += 1024) {
    int idx = base + tid;
    int v = (idx < M_ROWS) ? cnt[idx] : 0;
    sh[tid] = v;
    __syncthreads();
    for (int off = 1; off < 1024; off <<= 1) {
      int t = (tid >= off) ? sh[tid - off] : 0;
      __syncthreads();
      sh[tid] += t;
      __syncthreads();
    }
    int incl = sh[tid] + carry_sh;
    if (idx < M_ROWS) {
      start[idx + 1] = incl;
      cursor[idx] = incl - v;
    }
    __syncthreads();
    if (tid == 1023) carry_sh = incl;
    __syncthreads();
  }
}

__global__ void k_scatter(const int* __restrict__ srcI, const int* __restrict__ dstI,
                          const int* __restrict__ srcJ, const int* __restrict__ dstJ,
                          int* __restrict__ cursor, int* __restrict__ srcS,
                          int* __restrict__ permS) {
  int e = blockIdx.x * blockDim.x + threadIdx.x;
  if (e >= 2 * N_EDGES) return;
  int s, d;
  if (e < N_EDGES) {
    s = srcI[e];
    d = dstI[e];
  } else {
    s = srcJ[e - N_EDGES] + N_NODES;
    d = dstJ[e - N_EDGES] + N_NODES;
  }
  int pos = atomicAdd(&cursor[d], 1);
  srcS[pos] = s;
  permS[pos] = e;  // >= N_EDGES means graph j
}

// ---- fused edge phase: 32-lane group per dst node (2 nodes/wave), ----
// single sweep, online softmax, bf16 q/k/v gathers. d = i*128 + 4*lane32.
__global__ __launch_bounds__(256) void k_edge_fused(
    float* __restrict__ h, unsigned short* __restrict__ hbf,
    const unsigned short* __restrict__ qb16, const unsigned short* __restrict__ kb16,
    const unsigned short* __restrict__ vb16, const float* __restrict__ eaI,
    const float* __restrict__ eaJ, const float* __restrict__ We,
    const int* __restrict__ srcS, const int* __restrict__ permS,
    const int* __restrict__ start, int do_relu) {
  int w = blockIdx.x * 8 + (threadIdx.x >> 5);
  int lane = threadIdx.x & 31;
  if (w >= M_ROWS) return;
  const int s0 = start[w], s1 = start[w + 1];

  float4 qr[5];
#pragma unroll
  for (int i = 0; i < 5; ++i) {
    ushort4 qc = *(const ushort4*)(qb16 + (size_t)w * D + i * 128 + 4 * lane);
    qr[i] = make_float4(bf2f(qc.x), bf2f(qc.y), bf2f(qc.z), bf2f(qc.w));
  }

  // Gc on lane c (c<8): q[w] . We[c,:]
  float Gc = 0.f;
#pragma unroll
  for (int c = 0; c < ED_IN; ++c) {
    const float* wr = We + c * D;
    float p = 0.f;
#pragma unroll
    for (int i = 0; i < 5; ++i) {
      float4 wv = *(const float4*)(wr + i * 128 + 4 * lane);
      p += qr[i].x * wv.x + qr[i].y * wv.y + qr[i].z * wv.z + qr[i].w * wv.w;
    }
#pragma unroll
    for (int m = 1; m < 32; m <<= 1) p += __shfl_xor(p, m, 32);
    if (lane == c) Gc = p;
  }

  float mx = -3.4e38f, Sp = 0.f, Sea = 0.f;
  float4 acc[5];
#pragma unroll
  for (int i = 0; i < 5; ++i) acc[i] = make_float4(0.f, 0.f, 0.f, 0.f);

  for (int pos = s0; pos < s1; ++pos) {
    int sj = srcS[pos];
    int pe = permS[pos];
    const unsigned short* krow = kb16 + (size_t)sj * D;
    const unsigned short* vrow = vb16 + (size_t)sj * D;
    float part = 0.f;
    float4 vv[5];
#pragma unroll
    for (int i = 0; i < 5; ++i) {
      ushort4 kc = *(const ushort4*)(krow + i * 128 + 4 * lane);
      ushort4 vc = *(const ushort4*)(vrow + i * 128 + 4 * lane);
      vv[i] = make_float4(bf2f(vc.x), bf2f(vc.y), bf2f(vc.z), bf2f(vc.w));
      part += qr[i].x * bf2f(kc.x) + qr[i].y * bf2f(kc.y) + qr[i].z * bf2f(kc.z) +
              qr[i].w * bf2f(kc.w);
    }
    const float* eap = (pe < N_EDGES) ? eaI + (size_t)pe * ED_IN
                                      : eaJ + (size_t)(pe - N_EDGES) * ED_IN;
    float eaL = (lane < ED_IN) ? eap[lane] : 0.f;
    part += eaL * Gc;
#pragma unroll
    for (int m = 1; m < 32; m <<= 1) part += __shfl_xor(part, m, 32);
    float sc = part * SCORE_SCALE;
    float mn = fmaxf(mx, sc);
    float cs = __expf(mx - mn);
    float p = __expf(sc - mn);
    mx = mn;
    Sp = Sp * cs + p;
#pragma unroll
    for (int i = 0; i < 5; ++i) {
      acc[i].x = acc[i].x * cs + p * vv[i].x;
      acc[i].y = acc[i].y * cs + p * vv[i].y;
      acc[i].z = acc[i].z * cs + p * vv[i].z;
      acc[i].w = acc[i].w * cs + p * vv[i].w;
    }
    Sea = Sea * cs + p * eaL;
  }
  float inv = 1.0f / (Sp + 1e-16f);

  float seac[ED_IN];
#pragma unroll
  for (int c = 0; c < ED_IN; ++c) seac[c] = __shfl(Sea, c, 32);
#pragma unroll
  for (int i = 0; i < 5; ++i) {
    int d = i * 128 + 4 * lane;
    float4 term = acc[i];
#pragma unroll
    for (int c = 0; c < ED_IN; ++c) {
      float4 wv = *(const float4*)(We + c * D + d);
      term.x += seac[c] * wv.x;
      term.y += seac[c] * wv.y;
      term.z += seac[c] * wv.z;
      term.w += seac[c] * wv.w;
    }
    float4 hv = *(const float4*)(h + (size_t)w * D + d);
    float vx = hv.x + term.x * inv;
    float vy = hv.y + term.y * inv;
    float vz = hv.z + term.z * inv;
    float vw = hv.w + term.w * inv;
    if (do_relu) {
      vx = fmaxf(vx, 0.f);
      vy = fmaxf(vy, 0.f);
      vz = fmaxf(vz, 0.f);
      vw = fmaxf(vw, 0.f);
    }
    *(float4*)(h + (size_t)w * D + d) = make_float4(vx, vy, vz, vw);
    ushort4 hb;
    hb.x = f2bf(vx);
    hb.y = f2bf(vy);
    hb.z = f2bf(vz);
    hb.w = f2bf(vw);
    *(ushort4*)(hbf + (size_t)w * D + d) = hb;
  }
}

// global add pool over both graphs
__global__ void k_pool(const float* __restrict__ h, const int* __restrict__ batI,
                       const int* __restrict__ batJ, float* __restrict__ pooled) {
  int t = blockIdx.x * blockDim.x + threadIdx.x;
  if (t >= M_ROWS * D) return;
  int n = t / D, d = t % D;
  int b = (n < N_NODES) ? batI[n] : (batJ[n - N_NODES] + NB);
  atomicAdd(pooled + (size_t)b * D + d, h[t]);
}

// per graph row: LayerNorm -> @Wemb + bemb -> ReLU  (grid 2*NB)
__global__ __launch_bounds__(256) void k_head(const float* __restrict__ pooled,
                                              const float* __restrict__ gam,
                                              const float* __restrict__ bet,
                                              const float* __restrict__ Wemb,
                                              const float* __restrict__ bemb,
                                              float* __restrict__ z) {
  __shared__ float sh[D];
  __shared__ float red[4];
  int b = blockIdx.x, tid = threadIdx.x;
  float local = 0.f;
  for (int c = tid; c < D; c += 256) {
    float val = pooled[(size_t)b * D + c];
    sh[c] = val;
    local += val;
  }
#pragma unroll
  for (int off = 32; off > 0; off >>= 1) local += __shfl_down(local, off);
  if ((tid & 63) == 0) red[tid >> 6] = local;
  __syncthreads();
  float mu = (red[0] + red[1] + red[2] + red[3]) * (1.0f / D);
  __syncthreads();
  float lv = 0.f;
  for (int c = tid; c < D; c += 256) {
    float t2 = sh[c] - mu;
    lv += t2 * t2;
  }
#pragma unroll
  for (int off = 32; off > 0; off >>= 1) lv += __shfl_down(lv, off);
  if ((tid & 63) == 0) red[tid >> 6] = lv;
  __syncthreads();
  float var = (red[0] + red[1] + red[2] + red[3]) * (1.0f / D);
  float rstd = rsqrtf(var + 1e-5f);
  __syncthreads();
  for (int c = tid; c < D; c += 256) sh[c] = (sh[c] - mu) * rstd * gam[c] + bet[c];
  __syncthreads();
  for (int d = tid; d < D; d += 256) {
    float acc = bemb[d];
    for (int c = 0; c < D; ++c) acc += sh[c] * Wemb[c * D + d];
    z[(size_t)b * D + d] = fmaxf(acc, 0.f);
  }
}

__global__ void k_cosine(const float* __restrict__ zi, const float* __restrict__ zj,
                         float* __restrict__ out) {
  int b = blockIdx.x, lane = threadIdx.x;
  float dot = 0.f, ni = 0.f, nj = 0.f;
  for (int d = lane; d < D; d += 64) {
    float a = zi[(size_t)b * D + d], c = zj[(size_t)b * D + d];
    dot += a * c;
    ni += a * a;
    nj += c * c;
  }
#pragma unroll
  for (int off = 32; off > 0; off >>= 1) {
    dot += __shfl_down(dot, off);
    ni += __shfl_down(ni, off);
    nj += __shfl_down(nj, off);
  }
  if (lane == 0)
    out[b] = dot / (fmaxf(sqrtf(ni), 1e-8f) * fmaxf(sqrtf(nj), 1e-8f));
}

extern "C" void kernel_launch(void* const* d_in, const int* in_sizes, int n_in,
                              void* d_out, int out_size, void* d_ws, size_t ws_size,
                              hipStream_t stream) {
  (void)in_sizes; (void)n_in; (void)out_size; (void)ws_size;
  const float* xI = (const float*)d_in[0];
  const int* eiI = (const int*)d_in[1];
  const float* eaI = (const float*)d_in[2];
  const int* batI = (const int*)d_in[3];
  const float* xJ = (const float*)d_in[4];
  const int* eiJ = (const int*)d_in[5];
  const float* eaJ = (const float*)d_in[6];
  const int* batJ = (const int*)d_in[7];
  const float* W0q = (const float*)d_in[8];
  const float* b0q = (const float*)d_in[9];
  const float* W0k = (const float*)d_in[10];
  const float* b0k = (const float*)d_in[11];
  const float* W0v = (const float*)d_in[12];
  const float* b0v = (const float*)d_in[13];
  const float* W0e = (const float*)d_in[14];
  const float* W0s = (const float*)d_in[15];
  const float* b0s = (const float*)d_in[16];
  const float* Wq = (const float*)d_in[17];
  const float* bq = (const float*)d_in[18];
  const float* Wk = (const float*)d_in[19];
  const float* bk = (const float*)d_in[20];
  const float* Wv = (const float*)d_in[21];
  const float* bv = (const float*)d_in[22];
  const float* We = (const float*)d_in[23];
  const float* Ws = (const float*)d_in[24];
  const float* bs = (const float*)d_in[25];
  const float* ln_g = (const float*)d_in[26];
  const float* ln_b = (const float*)d_in[27];
  const float* Wemb = (const float*)d_in[28];
  const float* bemb = (const float*)d_in[29];

  const size_t ND2 = (size_t)M_ROWS * D;
  float* h = (float*)d_ws;                       // 2N*D f32
  float* pooled = h + ND2;                       // 2NB*D
  float* z = pooled + (size_t)2 * NB * D;        // 2NB*D
  unsigned short* qbf = (unsigned short*)(z + (size_t)2 * NB * D);  // 2N*D
  unsigned short* kbf = qbf + ND2;
  unsigned short* vbf = kbf + ND2;
  unsigned short* hbf = vbf + ND2;
  unsigned short* Wt = hbf + ND2;                // 20*D*D (also OOB-read pad)
  int* cnt = (int*)(Wt + (size_t)(NLAYERS - 1) * 4 * D * D);  // 2N
  int* start = cnt + M_ROWS;                     // 2N+1
  int* cursor = start + M_ROWS + 1;              // 2N
  int* srcS = cursor + M_ROWS;                   // 2E
  int* permS = srcS + 2 * N_EDGES;               // 2E

  const int* srcI = eiI;
  const int* dstI = eiI + N_EDGES;
  const int* srcJ = eiJ;
  const int* dstJ = eiJ + N_EDGES;

  dim3 gLin4((M_ROWS * D + 255) / 256, 1, 4);
  dim3 gGemm((M_ROWS + BM - 1) / BM, D / BN, 4);
  dim3 gEdge((M_ROWS + 7) / 8);
  dim3 gE((2 * N_EDGES + 255) / 256);
  dim3 gPool((M_ROWS * D + 255) / 256);

  k_wprep<<<dim3(D / 32, D / 32, (NLAYERS - 1) * 4), 256, 0, stream>>>(Wq, Wk, Wv, Ws, Wt);

  // combined CSR
  hipMemsetAsync(cnt, 0, M_ROWS * sizeof(int), stream);
  k_hist<<<gE, 256, 0, stream>>>(dstI, dstJ, cnt);
  k_scan<<<1, 1024, 0, stream>>>(cnt, start, cursor);
  k_scatter<<<gE, 256, 0, stream>>>(srcI, dstI, srcJ, dstJ, cursor, srcS, permS);

  // layer 0
  k_lin4<<<gLin4, 256, 0, stream>>>(xI, xJ, W0q, b0q, W0k, b0k, W0v, b0v, W0s, b0s,
                                    qbf, kbf, vbf, h);
  k_edge_fused<<<gEdge, 256, 0, stream>>>(h, hbf, qbf, kbf, vbf, eaI, eaJ, W0e,
                                          srcS, permS, start, 1);

  // layers 1..5
  for (int l = 0; l < NLAYERS - 1; ++l) {
    const unsigned short* WtL = Wt + (size_t)l * 4 * D * D;
    const float* Wel = We + (size_t)l * ED_IN * D;
    k_gemm_bf16<<<gGemm, 256, 0, stream>>>(
        hbf, WtL, bq + (size_t)l * D, bk + (size_t)l * D, bv + (size_t)l * D,
        bs + (size_t)l * D, qbf, kbf, vbf, h);
    k_edge_fused<<<gEdge, 256, 0, stream>>>(h, hbf, qbf, kbf, vbf, eaI, eaJ, Wel,
                                            srcS, permS, start,
                                            (l < NLAYERS - 2) ? 1 : 0);
  }

  hipMemsetAsync(pooled, 0, (size_t)2 * NB * D * sizeof(float), stream);
  k_pool<<<gPool, 256, 0, stream>>>(h, batI, batJ, pooled);
  k_head<<<2 * NB, 256, 0, stream>>>(pooled, ln_g, ln_b, Wemb, bemb, z);
  k_cosine<<<NB, 64, 0, stream>>>(z, z + (size_t)NB * D, (float*)d_out);
}

// Round 6
// 2001.053 us; speedup vs baseline: 5.9741x; 1.0348x over previous
//
#include <hip/hip_runtime.h>

#define N_NODES 10000
#define N_EDGES 160000
#define NB 64
#define D 640
#define ND_IN 4
#define ED_IN 8
#define NLAYERS 6
#define M_ROWS (2 * N_NODES)  // both graphs batched

#define SCORE_SCALE 0.039528470752104741f  // 1/sqrt(640)

typedef __attribute__((ext_vector_type(8))) short short8;
typedef __attribute__((ext_vector_type(4))) float floatx4;

__device__ __forceinline__ unsigned short f2bf(float f) {
  unsigned u = __float_as_uint(f);
  u += 0x7fffu + ((u >> 16) & 1);  // RNE
  return (unsigned short)(u >> 16);
}
__device__ __forceinline__ float bf2f(unsigned short s) {
  return __uint_as_float((unsigned)s << 16);
}
__device__ __forceinline__ void gload_lds16(const void* g, void* l) {
  __builtin_amdgcn_global_load_lds(
      (const __attribute__((address_space(1))) void*)g,
      (__attribute__((address_space(3))) void*)l, 16, 0, 0);
}

// ---- layer-0 projections over both graphs: q,k,v,skip all bf16 ----
__global__ void k_lin4(const float* __restrict__ xI, const float* __restrict__ xJ,
                       const float* __restrict__ Wq, const float* __restrict__ bq,
                       const float* __restrict__ Wk, const float* __restrict__ bk,
                       const float* __restrict__ Wv, const float* __restrict__ bv,
                       const float* __restrict__ Ws, const float* __restrict__ bs,
                       unsigned short* __restrict__ oqb, unsigned short* __restrict__ okb,
                       unsigned short* __restrict__ ovb, unsigned short* __restrict__ osb) {
  int t = blockIdx.x * blockDim.x + threadIdx.x;
  if (t >= M_ROWS * D) return;
  int z = blockIdx.z;
  const float* W = (z == 0) ? Wq : (z == 1) ? Wk : (z == 2) ? Wv : Ws;
  const float* b = (z == 0) ? bq : (z == 1) ? bk : (z == 2) ? bv : bs;
  unsigned short* o = (z == 0) ? oqb : (z == 1) ? okb : (z == 2) ? ovb : osb;
  int n = t / D, d = t % D;
  const float* xr = (n < N_NODES) ? xI + (size_t)n * ND_IN
                                  : xJ + (size_t)(n - N_NODES) * ND_IN;
  float acc = b[d];
#pragma unroll
  for (int c = 0; c < ND_IN; ++c) acc += xr[c] * W[c * D + d];
  o[t] = f2bf(acc);
}

// one-time: Wt[l][mat][n][k] = bf16(W[l][mat][k][n])
__global__ __launch_bounds__(256) void k_wprep(const float* __restrict__ Wq,
                                               const float* __restrict__ Wk,
                                               const float* __restrict__ Wv,
                                               const float* __restrict__ Ws,
                                               unsigned short* __restrict__ Wt) {
  __shared__ float tile[32][33];
  int mt = blockIdx.z;
  int l = mt >> 2, mat = mt & 3;
  const float* W =
      (mat == 0 ? Wq : mat == 1 ? Wk : mat == 2 ? Wv : Ws) + (size_t)l * D * D;
  int tk = blockIdx.x * 32, tn = blockIdx.y * 32;
  int tx = threadIdx.x & 31, ty = threadIdx.x >> 5;
#pragma unroll
  for (int i = 0; i < 32; i += 8)
    tile[ty + i][tx] = W[(size_t)(tk + ty + i) * D + tn + tx];
  __syncthreads();
  unsigned short* dst = Wt + (size_t)mt * D * D;
#pragma unroll
  for (int i = 0; i < 32; i += 8)
    dst[(size_t)(tn + ty + i) * D + tk + tx] = f2bf(tile[tx][ty + i]);
}

// bf16 MFMA GEMM over 2N rows. Flat grid with XCD-aware swizzle: all 20
// blocks (5 by x 4 z) sharing one A row-band map to the same XCD (f%8
// round-robin) in consecutive slots -> A band fetched once per XCD L2.
#define BM 128
#define BN 128
#define BK 32
#define RBANDS ((M_ROWS + BM - 1) / BM)  // 157
__global__ __launch_bounds__(256) void k_gemm_bf16(
    const unsigned short* __restrict__ Abf, const unsigned short* __restrict__ Wt,
    const float* __restrict__ b0, const float* __restrict__ b1,
    const float* __restrict__ b2, const float* __restrict__ b3,
    unsigned short* __restrict__ oqb, unsigned short* __restrict__ okb,
    unsigned short* __restrict__ ovb, unsigned short* __restrict__ osb) {
  __shared__ __attribute__((aligned(16))) unsigned short lA[BM * BK];
  __shared__ __attribute__((aligned(16))) unsigned short lB[BN * BK];
  const int f = blockIdx.x;
  const int xcd = f & 7;
  const int slot = f >> 3;
  const int grp = slot / 20;
  const int tt = slot - grp * 20;  // 0..19
  const int r = xcd + (grp << 3);
  if (r >= RBANDS) return;
  const int z = tt / 5;
  const int by = tt - z * 5;
  const unsigned short* Wz = Wt + (size_t)z * D * D;
  const float* bias = (z == 0) ? b0 : (z == 1) ? b1 : (z == 2) ? b2 : b3;
  unsigned short* out = (z == 0) ? oqb : (z == 1) ? okb : (z == 2) ? ovb : osb;
  const int bm = r * BM, bn = by * BN;
  const int t = threadIdx.x;
  const int lane = t & 63, wv = t >> 6;
  const int wm = (wv & 1) * 64, wn = (wv >> 1) * 64;
  const int l15 = lane & 15, l4 = lane >> 4;
  const int r16 = lane >> 2;
  const int cb = lane & 3;

  floatx4 acc[4][4] = {};

  for (int k0 = 0; k0 < D; k0 += BK) {
#pragma unroll
    for (int i = 0; i < 2; ++i) {
      int row = wv * 32 + i * 16 + r16;
      int lcb = cb ^ ((row >> 1) & 3);
      gload_lds16(Abf + (size_t)(bm + row) * D + k0 + lcb * 8,
                  lA + (size_t)(wv * 32 + i * 16) * BK);
      gload_lds16(Wz + (size_t)(bn + row) * D + k0 + lcb * 8,
                  lB + (size_t)(wv * 32 + i * 16) * BK);
    }
    __syncthreads();
    short8 af[4], bfr[4];
#pragma unroll
    for (int i = 0; i < 4; ++i) {
      int rowA = wm + i * 16 + l15;
      af[i] = *(const short8*)(lA + rowA * BK + (l4 ^ ((rowA >> 1) & 3)) * 8);
      int rowB = wn + i * 16 + l15;
      bfr[i] = *(const short8*)(lB + rowB * BK + (l4 ^ ((rowB >> 1) & 3)) * 8);
    }
#pragma unroll
    for (int mi = 0; mi < 4; ++mi)
#pragma unroll
      for (int ni = 0; ni < 4; ++ni)
        acc[mi][ni] = __builtin_amdgcn_mfma_f32_16x16x32_bf16(af[mi], bfr[ni],
                                                              acc[mi][ni], 0, 0, 0);
    __syncthreads();
  }
#pragma unroll
  for (int mi = 0; mi < 4; ++mi)
#pragma unroll
    for (int ni = 0; ni < 4; ++ni)
#pragma unroll
      for (int rr = 0; rr < 4; ++rr) {
        int row = bm + wm + mi * 16 + l4 * 4 + rr;
        int col = bn + wn + ni * 16 + l15;
        if (row < M_ROWS)
          out[(size_t)row * D + col] = f2bf(acc[mi][ni][rr] + bias[col]);
      }
}

// G[n,c] = q[n,:] . We[c,:]  (hoisted edge-score prologue), 32-lane group/node
__global__ __launch_bounds__(256) void k_qg(const unsigned short* __restrict__ qb16,
                                            const float* __restrict__ We,
                                            float* __restrict__ G) {
  int w = blockIdx.x * 8 + (threadIdx.x >> 5);
  int lane = threadIdx.x & 31;
  if (w >= M_ROWS) return;
  float4 qr[5];
#pragma unroll
  for (int i = 0; i < 5; ++i) {
    ushort4 qc = *(const ushort4*)(qb16 + (size_t)w * D + i * 128 + 4 * lane);
    qr[i] = make_float4(bf2f(qc.x), bf2f(qc.y), bf2f(qc.z), bf2f(qc.w));
  }
  float Gc = 0.f;
#pragma unroll
  for (int c = 0; c < ED_IN; ++c) {
    const float* wr = We + c * D;
    float p = 0.f;
#pragma unroll
    for (int i = 0; i < 5; ++i) {
      float4 wv = *(const float4*)(wr + i * 128 + 4 * lane);
      p += qr[i].x * wv.x + qr[i].y * wv.y + qr[i].z * wv.z + qr[i].w * wv.w;
    }
#pragma unroll
    for (int m = 1; m < 32; m <<= 1) p += __shfl_xor(p, m, 32);
    if (lane == c) Gc = p;
  }
  if (lane < ED_IN) G[(size_t)w * ED_IN + lane] = Gc;
}

// ---- combined-graph CSR build ----
__global__ void k_hist(const int* __restrict__ dstI, const int* __restrict__ dstJ,
                       int* __restrict__ cnt) {
  int e = blockIdx.x * blockDim.x + threadIdx.x;
  if (e >= 2 * N_EDGES) return;
  int d = (e < N_EDGES) ? dstI[e] : (dstJ[e - N_EDGES] + N_NODES);
  atomicAdd(&cnt[d], 1);
}

__global__ __launch_bounds__(1024) void k_scan(const int* __restrict__ cnt,
                                               int* __restrict__ start,
                                               int* __restrict__ cursor) {
  __shared__ int sh[1024];
  __shared__ int carry_sh;
  int tid = threadIdx.x;
  if (tid == 0) {
    carry_sh = 0;
    start[0] = 0;
  }
  __syncthreads();
  for (int base = 0; base < M_ROWS; base += 1024) {
    int idx = base + tid;
    int v = (idx < M_ROWS) ? cnt[idx] : 0;
    sh[tid] = v;
    __syncthreads();
    for (int off = 1; off < 1024; off <<= 1) {
      int t = (tid >= off) ? sh[tid - off] : 0;
      __syncthreads();
      sh[tid] += t;
      __syncthreads();
    }
    int incl = sh[tid] + carry_sh;
    if (idx < M_ROWS) {
      start[idx + 1] = incl;
      cursor[idx] = incl - v;
    }
    __syncthreads();
    if (tid == 1023) carry_sh = incl;
    __syncthreads();
  }
}

__global__ void k_scatter(const int* __restrict__ srcI, const int* __restrict__ dstI,
                          const int* __restrict__ srcJ, const int* __restrict__ dstJ,
                          int* __restrict__ cursor, int* __restrict__ srcS,
                          int* __restrict__ permS) {
  int e = blockIdx.x * blockDim.x + threadIdx.x;
  if (e >= 2 * N_EDGES) return;
  int s, d;
  if (e < N_EDGES) {
    s = srcI[e];
    d = dstI[e];
  } else {
    s = srcJ[e - N_EDGES] + N_NODES;
    d = dstJ[e - N_EDGES] + N_NODES;
  }
  int pos = atomicAdd(&cursor[d], 1);
  srcS[pos] = s;
  permS[pos] = e;  // >= N_EDGES means graph j
}

// ---- fused edge phase: 32-lane group per dst node, online softmax with ----
// group-uniform fast path; bf16 q/k/v/skip; G precomputed.
__global__ __launch_bounds__(256) void k_edge_fused(
    float* __restrict__ h, unsigned short* __restrict__ hbf,
    const unsigned short* __restrict__ sbf, const unsigned short* __restrict__ qb16,
    const unsigned short* __restrict__ kb16, const unsigned short* __restrict__ vb16,
    const float* __restrict__ G, const float* __restrict__ eaI,
    const float* __restrict__ eaJ, const float* __restrict__ We,
    const int* __restrict__ srcS, const int* __restrict__ permS,
    const int* __restrict__ start, int do_relu, int write_h) {
  int w = blockIdx.x * 8 + (threadIdx.x >> 5);
  int lane = threadIdx.x & 31;
  if (w >= M_ROWS) return;
  const int s0 = start[w], s1 = start[w + 1];

  float4 qr[5];
#pragma unroll
  for (int i = 0; i < 5; ++i) {
    ushort4 qc = *(const ushort4*)(qb16 + (size_t)w * D + i * 128 + 4 * lane);
    qr[i] = make_float4(bf2f(qc.x), bf2f(qc.y), bf2f(qc.z), bf2f(qc.w));
  }
  float Gc = (lane < ED_IN) ? G[(size_t)w * ED_IN + lane] : 0.f;

  float mx = -3.4e38f, Sp = 0.f, Sea = 0.f;
  float4 acc[5];
#pragma unroll
  for (int i = 0; i < 5; ++i) acc[i] = make_float4(0.f, 0.f, 0.f, 0.f);

  for (int pos = s0; pos < s1; ++pos) {
    int sj = srcS[pos];
    int pe = permS[pos];
    const unsigned short* krow = kb16 + (size_t)sj * D;
    const unsigned short* vrow = vb16 + (size_t)sj * D;
    float part = 0.f;
    float4 vv[5];
#pragma unroll
    for (int i = 0; i < 5; ++i) {
      ushort4 kc = *(const ushort4*)(krow + i * 128 + 4 * lane);
      ushort4 vc = *(const ushort4*)(vrow + i * 128 + 4 * lane);
      vv[i] = make_float4(bf2f(vc.x), bf2f(vc.y), bf2f(vc.z), bf2f(vc.w));
      part += qr[i].x * bf2f(kc.x) + qr[i].y * bf2f(kc.y) + qr[i].z * bf2f(kc.z) +
              qr[i].w * bf2f(kc.w);
    }
    const float* eap = (pe < N_EDGES) ? eaI + (size_t)pe * ED_IN
                                      : eaJ + (size_t)(pe - N_EDGES) * ED_IN;
    float eaL = (lane < ED_IN) ? eap[lane] : 0.f;
    part += eaL * Gc;
#pragma unroll
    for (int m = 1; m < 32; m <<= 1) part += __shfl_xor(part, m, 32);
    float sc = part * SCORE_SCALE;
    if (sc > mx) {  // group-uniform branch: p == 1
      float cs = __expf(mx - sc);
      mx = sc;
      Sp = Sp * cs + 1.f;
      Sea = Sea * cs + eaL;
#pragma unroll
      for (int i = 0; i < 5; ++i) {
        acc[i].x = acc[i].x * cs + vv[i].x;
        acc[i].y = acc[i].y * cs + vv[i].y;
        acc[i].z = acc[i].z * cs + vv[i].z;
        acc[i].w = acc[i].w * cs + vv[i].w;
      }
    } else {  // cs == 1
      float p = __expf(sc - mx);
      Sp += p;
      Sea += p * eaL;
#pragma unroll
      for (int i = 0; i < 5; ++i) {
        acc[i].x += p * vv[i].x;
        acc[i].y += p * vv[i].y;
        acc[i].z += p * vv[i].z;
        acc[i].w += p * vv[i].w;
      }
    }
  }
  float inv = 1.0f / (Sp + 1e-16f);

  float seac[ED_IN];
#pragma unroll
  for (int c = 0; c < ED_IN; ++c) seac[c] = __shfl(Sea, c, 32);
#pragma unroll
  for (int i = 0; i < 5; ++i) {
    int d = i * 128 + 4 * lane;
    float4 term = acc[i];
#pragma unroll
    for (int c = 0; c < ED_IN; ++c) {
      float4 wv = *(const float4*)(We + c * D + d);
      term.x += seac[c] * wv.x;
      term.y += seac[c] * wv.y;
      term.z += seac[c] * wv.z;
      term.w += seac[c] * wv.w;
    }
    ushort4 sv = *(const ushort4*)(sbf + (size_t)w * D + d);
    float vx = bf2f(sv.x) + term.x * inv;
    float vy = bf2f(sv.y) + term.y * inv;
    float vz = bf2f(sv.z) + term.z * inv;
    float vw = bf2f(sv.w) + term.w * inv;
    if (do_relu) {
      vx = fmaxf(vx, 0.f);
      vy = fmaxf(vy, 0.f);
      vz = fmaxf(vz, 0.f);
      vw = fmaxf(vw, 0.f);
    }
    if (write_h) {
      *(float4*)(h + (size_t)w * D + d) = make_float4(vx, vy, vz, vw);
    } else {
      ushort4 hb;
      hb.x = f2bf(vx);
      hb.y = f2bf(vy);
      hb.z = f2bf(vz);
      hb.w = f2bf(vw);
      *(ushort4*)(hbf + (size_t)w * D + d) = hb;
    }
  }
}

// global add pool over both graphs (h fp32 from final layer)
__global__ void k_pool(const float* __restrict__ h, const int* __restrict__ batI,
                       const int* __restrict__ batJ, float* __restrict__ pooled) {
  int t = blockIdx.x * blockDim.x + threadIdx.x;
  if (t >= M_ROWS * D) return;
  int n = t / D, d = t % D;
  int b = (n < N_NODES) ? batI[n] : (batJ[n - N_NODES] + NB);
  atomicAdd(pooled + (size_t)b * D + d, h[t]);
}

// per graph row: LayerNorm -> @Wemb + bemb -> ReLU  (grid 2*NB)
__global__ __launch_bounds__(256) void k_head(const float* __restrict__ pooled,
                                              const float* __restrict__ gam,
                                              const float* __restrict__ bet,
                                              const float* __restrict__ Wemb,
                                              const float* __restrict__ bemb,
                                              float* __restrict__ z) {
  __shared__ float sh[D];
  __shared__ float red[4];
  int b = blockIdx.x, tid = threadIdx.x;
  float local = 0.f;
  for (int c = tid; c < D; c += 256) {
    float val = pooled[(size_t)b * D + c];
    sh[c] = val;
    local += val;
  }
#pragma unroll
  for (int off = 32; off > 0; off >>= 1) local += __shfl_down(local, off);
  if ((tid & 63) == 0) red[tid >> 6] = local;
  __syncthreads();
  float mu = (red[0] + red[1] + red[2] + red[3]) * (1.0f / D);
  __syncthreads();
  float lv = 0.f;
  for (int c = tid; c < D; c += 256) {
    float t2 = sh[c] - mu;
    lv += t2 * t2;
  }
#pragma unroll
  for (int off = 32; off > 0; off >>= 1) lv += __shfl_down(lv, off);
  if ((tid & 63) == 0) red[tid >> 6] = lv;
  __syncthreads();
  float var = (red[0] + red[1] + red[2] + red[3]) * (1.0f / D);
  float rstd = rsqrtf(var + 1e-5f);
  __syncthreads();
  for (int c = tid; c < D; c += 256) sh[c] = (sh[c] - mu) * rstd * gam[c] + bet[c];
  __syncthreads();
  for (int d = tid; d < D; d += 256) {
    float acc = bemb[d];
    for (int c = 0; c < D; ++c) acc += sh[c] * Wemb[c * D + d];
    z[(size_t)b * D + d] = fmaxf(acc, 0.f);
  }
}

__global__ void k_cosine(const float* __restrict__ zi, const float* __restrict__ zj,
                         float* __restrict__ out) {
  int b = blockIdx.x, lane = threadIdx.x;
  float dot = 0.f, ni = 0.f, nj = 0.f;
  for (int d = lane; d < D; d += 64) {
    float a = zi[(size_t)b * D + d], c = zj[(size_t)b * D + d];
    dot += a * c;
    ni += a * a;
    nj += c * c;
  }
#pragma unroll
  for (int off = 32; off > 0; off >>= 1) {
    dot += __shfl_down(dot, off);
    ni += __shfl_down(ni, off);
    nj += __shfl_down(nj, off);
  }
  if (lane == 0)
    out[b] = dot / (fmaxf(sqrtf(ni), 1e-8f) * fmaxf(sqrtf(nj), 1e-8f));
}

extern "C" void kernel_launch(void* const* d_in, const int* in_sizes, int n_in,
                              void* d_out, int out_size, void* d_ws, size_t ws_size,
                              hipStream_t stream) {
  (void)in_sizes; (void)n_in; (void)out_size; (void)ws_size;
  const float* xI = (const float*)d_in[0];
  const int* eiI = (const int*)d_in[1];
  const float* eaI = (const float*)d_in[2];
  const int* batI = (const int*)d_in[3];
  const float* xJ = (const float*)d_in[4];
  const int* eiJ = (const int*)d_in[5];
  const float* eaJ = (const float*)d_in[6];
  const int* batJ = (const int*)d_in[7];
  const float* W0q = (const float*)d_in[8];
  const float* b0q = (const float*)d_in[9];
  const float* W0k = (const float*)d_in[10];
  const float* b0k = (const float*)d_in[11];
  const float* W0v = (const float*)d_in[12];
  const float* b0v = (const float*)d_in[13];
  const float* W0e = (const float*)d_in[14];
  const float* W0s = (const float*)d_in[15];
  const float* b0s = (const float*)d_in[16];
  const float* Wq = (const float*)d_in[17];
  const float* bq = (const float*)d_in[18];
  const float* Wk = (const float*)d_in[19];
  const float* bk = (const float*)d_in[20];
  const float* Wv = (const float*)d_in[21];
  const float* bv = (const float*)d_in[22];
  const float* We = (const float*)d_in[23];
  const float* Ws = (const float*)d_in[24];
  const float* bs = (const float*)d_in[25];
  const float* ln_g = (const float*)d_in[26];
  const float* ln_b = (const float*)d_in[27];
  const float* Wemb = (const float*)d_in[28];
  const float* bemb = (const float*)d_in[29];

  const size_t ND2 = (size_t)M_ROWS * D;
  float* h = (float*)d_ws;                       // 2N*D f32 (final layer only)
  float* pooled = h + ND2;                       // 2NB*D
  float* z = pooled + (size_t)2 * NB * D;        // 2NB*D
  float* G = z + (size_t)2 * NB * D;             // 2N*8
  unsigned short* qbf = (unsigned short*)(G + (size_t)M_ROWS * ED_IN);
  unsigned short* kbf = qbf + ND2;
  unsigned short* vbf = kbf + ND2;
  unsigned short* hbf = vbf + ND2;
  unsigned short* sbf = hbf + ND2;               // bf16 skip (also A-OOB pad)
  unsigned short* Wt = sbf + ND2;                // 20*D*D
  int* cnt = (int*)(Wt + (size_t)(NLAYERS - 1) * 4 * D * D);  // 2N
  int* start = cnt + M_ROWS;                     // 2N+1
  int* cursor = start + M_ROWS + 1;              // 2N
  int* srcS = cursor + M_ROWS;                   // 2E
  int* permS = srcS + 2 * N_EDGES;               // 2E

  const int* srcI = eiI;
  const int* dstI = eiI + N_EDGES;
  const int* srcJ = eiJ;
  const int* dstJ = eiJ + N_EDGES;

  dim3 gLin4((M_ROWS * D + 255) / 256, 1, 4);
  dim3 gGemm(8 * 20 * 20);  // flat XCD-swizzled: 8 xcd x 20 grp x 20 (by,z)
  dim3 gEdge((M_ROWS + 7) / 8);
  dim3 gE((2 * N_EDGES + 255) / 256);
  dim3 gPool((M_ROWS * D + 255) / 256);
  dim3 gQg((M_ROWS + 7) / 8);

  k_wprep<<<dim3(D / 32, D / 32, (NLAYERS - 1) * 4), 256, 0, stream>>>(Wq, Wk, Wv, Ws, Wt);

  // combined CSR
  hipMemsetAsync(cnt, 0, M_ROWS * sizeof(int), stream);
  k_hist<<<gE, 256, 0, stream>>>(dstI, dstJ, cnt);
  k_scan<<<1, 1024, 0, stream>>>(cnt, start, cursor);
  k_scatter<<<gE, 256, 0, stream>>>(srcI, dstI, srcJ, dstJ, cursor, srcS, permS);

  // layer 0
  k_lin4<<<gLin4, 256, 0, stream>>>(xI, xJ, W0q, b0q, W0k, b0k, W0v, b0v, W0s, b0s,
                                    qbf, kbf, vbf, sbf);
  k_qg<<<gQg, 256, 0, stream>>>(qbf, W0e, G);
  k_edge_fused<<<gEdge, 256, 0, stream>>>(h, hbf, sbf, qbf, kbf, vbf, G, eaI, eaJ,
                                          W0e, srcS, permS, start, 1, 0);

  // layers 1..5
  for (int l = 0; l < NLAYERS - 1; ++l) {
    const unsigned short* WtL = Wt + (size_t)l * 4 * D * D;
    const float* Wel = We + (size_t)l * ED_IN * D;
    int last = (l == NLAYERS - 2);
    k_gemm_bf16<<<gGemm, 256, 0, stream>>>(
        hbf, WtL, bq + (size_t)l * D, bk + (size_t)l * D, bv + (size_t)l * D,
        bs + (size_t)l * D, qbf, kbf, vbf, sbf);
    k_qg<<<gQg, 256, 0, stream>>>(qbf, Wel, G);
    k_edge_fused<<<gEdge, 256, 0, stream>>>(h, hbf, sbf, qbf, kbf, vbf, G, eaI, eaJ,
                                            Wel, srcS, permS, start,
                                            last ? 0 : 1, last ? 1 : 0);
  }

  hipMemsetAsync(pooled, 0, (size_t)2 * NB * D * sizeof(float), stream);
  k_pool<<<gPool, 256, 0, stream>>>(h, batI, batJ, pooled);
  k_head<<<2 * NB, 256, 0, stream>>>(pooled, ln_g, ln_b, Wemb, bemb, z);
  k_cosine<<<NB, 64, 0, stream>>>(z, z + (size_t)NB * D, (float*)d_out);
}

// Round 7
// 1933.145 us; speedup vs baseline: 6.1840x; 1.0351x over previous
//
#include <hip/hip_runtime.h>

#define N_NODES 10000
#define N_EDGES 160000
#define NB 64
#define D 640
#define ND_IN 4
#define ED_IN 8
#define NLAYERS 6
#define M_ROWS (2 * N_NODES)  // both graphs batched

#define SCORE_SCALE 0.039528470752104741f  // 1/sqrt(640)
#define NEGBIG -3.4e38f

typedef __attribute__((ext_vector_type(8))) short short8;
typedef __attribute__((ext_vector_type(4))) float floatx4;

__device__ __forceinline__ unsigned short f2bf(float f) {
  unsigned u = __float_as_uint(f);
  u += 0x7fffu + ((u >> 16) & 1);  // RNE
  return (unsigned short)(u >> 16);
}
__device__ __forceinline__ float bf2f(unsigned short s) {
  return __uint_as_float((unsigned)s << 16);
}
__device__ __forceinline__ void gload_lds16(const void* g, void* l) {
  __builtin_amdgcn_global_load_lds(
      (const __attribute__((address_space(1))) void*)g,
      (__attribute__((address_space(3))) void*)l, 16, 0, 0);
}
__device__ __forceinline__ float4 cvt4(ushort4 s) {
  return make_float4(bf2f(s.x), bf2f(s.y), bf2f(s.z), bf2f(s.w));
}

// ---- layer-0 projections: q,skip separate; k,v interleaved in kv ----
__global__ void k_lin4(const float* __restrict__ xI, const float* __restrict__ xJ,
                       const float* __restrict__ Wq, const float* __restrict__ bq,
                       const float* __restrict__ Wk, const float* __restrict__ bk,
                       const float* __restrict__ Wv, const float* __restrict__ bv,
                       const float* __restrict__ Ws, const float* __restrict__ bs,
                       unsigned short* __restrict__ oqb, unsigned short* __restrict__ okv,
                       unsigned short* __restrict__ osb) {
  int t = blockIdx.x * blockDim.x + threadIdx.x;
  if (t >= M_ROWS * D) return;
  int z = blockIdx.z;
  const float* W = (z == 0) ? Wq : (z == 1) ? Wk : (z == 2) ? Wv : Ws;
  const float* b = (z == 0) ? bq : (z == 1) ? bk : (z == 2) ? bv : bs;
  int n = t / D, d = t % D;
  const float* xr = (n < N_NODES) ? xI + (size_t)n * ND_IN
                                  : xJ + (size_t)(n - N_NODES) * ND_IN;
  float acc = b[d];
#pragma unroll
  for (int c = 0; c < ND_IN; ++c) acc += xr[c] * W[c * D + d];
  unsigned short r = f2bf(acc);
  if (z == 0) oqb[t] = r;
  else if (z == 1) okv[(size_t)(2 * n) * D + d] = r;
  else if (z == 2) okv[(size_t)(2 * n + 1) * D + d] = r;
  else osb[t] = r;
}

// one-time: Wt[l][mat][n][k] = bf16(W[l][mat][k][n])
__global__ __launch_bounds__(256) void k_wprep(const float* __restrict__ Wq,
                                               const float* __restrict__ Wk,
                                               const float* __restrict__ Wv,
                                               const float* __restrict__ Ws,
                                               unsigned short* __restrict__ Wt) {
  __shared__ float tile[32][33];
  int mt = blockIdx.z;
  int l = mt >> 2, mat = mt & 3;
  const float* W =
      (mat == 0 ? Wq : mat == 1 ? Wk : mat == 2 ? Wv : Ws) + (size_t)l * D * D;
  int tk = blockIdx.x * 32, tn = blockIdx.y * 32;
  int tx = threadIdx.x & 31, ty = threadIdx.x >> 5;
#pragma unroll
  for (int i = 0; i < 32; i += 8)
    tile[ty + i][tx] = W[(size_t)(tk + ty + i) * D + tn + tx];
  __syncthreads();
  unsigned short* dst = Wt + (size_t)mt * D * D;
#pragma unroll
  for (int i = 0; i < 32; i += 8)
    dst[(size_t)(tn + ty + i) * D + tk + tx] = f2bf(tile[tx][ty + i]);
}

// bf16 MFMA GEMM over 2N rows, XCD-swizzled flat grid (A band -> one XCD).
#define BM 128
#define BN 128
#define BK 32
#define RBANDS ((M_ROWS + BM - 1) / BM)  // 157
__global__ __launch_bounds__(256) void k_gemm_bf16(
    const unsigned short* __restrict__ Abf, const unsigned short* __restrict__ Wt,
    const float* __restrict__ b0, const float* __restrict__ b1,
    const float* __restrict__ b2, const float* __restrict__ b3,
    unsigned short* __restrict__ oqb, unsigned short* __restrict__ okv,
    unsigned short* __restrict__ osb) {
  __shared__ __attribute__((aligned(16))) unsigned short lA[BM * BK];
  __shared__ __attribute__((aligned(16))) unsigned short lB[BN * BK];
  const int f = blockIdx.x;
  const int xcd = f & 7;
  const int slot = f >> 3;
  const int grp = slot / 20;
  const int tt = slot - grp * 20;  // 0..19
  const int r = xcd + (grp << 3);
  if (r >= RBANDS) return;
  const int z = tt / 5;
  const int by = tt - z * 5;
  const unsigned short* Wz = Wt + (size_t)z * D * D;
  const float* bias = (z == 0) ? b0 : (z == 1) ? b1 : (z == 2) ? b2 : b3;
  const int bm = r * BM, bn = by * BN;
  const int t = threadIdx.x;
  const int lane = t & 63, wv = t >> 6;
  const int wm = (wv & 1) * 64, wn = (wv >> 1) * 64;
  const int l15 = lane & 15, l4 = lane >> 4;
  const int r16 = lane >> 2;
  const int cb = lane & 3;

  floatx4 acc[4][4] = {};

  for (int k0 = 0; k0 < D; k0 += BK) {
#pragma unroll
    for (int i = 0; i < 2; ++i) {
      int row = wv * 32 + i * 16 + r16;
      int lcb = cb ^ ((row >> 1) & 3);
      gload_lds16(Abf + (size_t)(bm + row) * D + k0 + lcb * 8,
                  lA + (size_t)(wv * 32 + i * 16) * BK);
      gload_lds16(Wz + (size_t)(bn + row) * D + k0 + lcb * 8,
                  lB + (size_t)(wv * 32 + i * 16) * BK);
    }
    __syncthreads();
    short8 af[4], bfr[4];
#pragma unroll
    for (int i = 0; i < 4; ++i) {
      int rowA = wm + i * 16 + l15;
      af[i] = *(const short8*)(lA + rowA * BK + (l4 ^ ((rowA >> 1) & 3)) * 8);
      int rowB = wn + i * 16 + l15;
      bfr[i] = *(const short8*)(lB + rowB * BK + (l4 ^ ((rowB >> 1) & 3)) * 8);
    }
#pragma unroll
    for (int mi = 0; mi < 4; ++mi)
#pragma unroll
      for (int ni = 0; ni < 4; ++ni)
        acc[mi][ni] = __builtin_amdgcn_mfma_f32_16x16x32_bf16(af[mi], bfr[ni],
                                                              acc[mi][ni], 0, 0, 0);
    __syncthreads();
  }
#pragma unroll
  for (int mi = 0; mi < 4; ++mi)
#pragma unroll
    for (int ni = 0; ni < 4; ++ni)
#pragma unroll
      for (int rr = 0; rr < 4; ++rr) {
        int row = bm + wm + mi * 16 + l4 * 4 + rr;
        int col = bn + wn + ni * 16 + l15;
        if (row < M_ROWS) {
          unsigned short v = f2bf(acc[mi][ni][rr] + bias[col]);
          if (z == 0) oqb[(size_t)row * D + col] = v;
          else if (z == 1) okv[(size_t)(2 * row) * D + col] = v;
          else if (z == 2) okv[(size_t)(2 * row + 1) * D + col] = v;
          else osb[(size_t)row * D + col] = v;
        }
      }
}

// ---- combined-graph CSR build ----
__global__ void k_hist(const int* __restrict__ dstI, const int* __restrict__ dstJ,
                       int* __restrict__ cnt) {
  int e = blockIdx.x * blockDim.x + threadIdx.x;
  if (e >= 2 * N_EDGES) return;
  int d = (e < N_EDGES) ? dstI[e] : (dstJ[e - N_EDGES] + N_NODES);
  atomicAdd(&cnt[d], 1);
}

__global__ __launch_bounds__(1024) void k_scan(const int* __restrict__ cnt,
                                               int* __restrict__ start,
                                               int* __restrict__ cursor) {
  __shared__ int sh[1024];
  __shared__ int carry_sh;
  int tid = threadIdx.x;
  if (tid == 0) {
    carry_sh = 0;
    start[0] = 0;
  }
  __syncthreads();
  for (int base = 0; base < M_ROWS; base += 1024) {
    int idx = base + tid;
    int v = (idx < M_ROWS) ? cnt[idx] : 0;
    sh[tid] = v;
    __syncthreads();
    for (int off = 1; off < 1024; off <<= 1) {
      int t = (tid >= off) ? sh[tid - off] : 0;
      __syncthreads();
      sh[tid] += t;
      __syncthreads();
    }
    int incl = sh[tid] + carry_sh;
    if (idx < M_ROWS) {
      start[idx + 1] = incl;
      cursor[idx] = incl - v;
    }
    __syncthreads();
    if (tid == 1023) carry_sh = incl;
    __syncthreads();
  }
}

// scatter + gather edge attrs into CSR order (eaS)
__global__ void k_scatter(const int* __restrict__ srcI, const int* __restrict__ dstI,
                          const int* __restrict__ srcJ, const int* __restrict__ dstJ,
                          const float* __restrict__ eaI, const float* __restrict__ eaJ,
                          int* __restrict__ cursor, int* __restrict__ srcS,
                          float* __restrict__ eaS) {
  int e = blockIdx.x * blockDim.x + threadIdx.x;
  if (e >= 2 * N_EDGES) return;
  int s, d;
  const float* eap;
  if (e < N_EDGES) {
    s = srcI[e];
    d = dstI[e];
    eap = eaI + (size_t)e * ED_IN;
  } else {
    s = srcJ[e - N_EDGES] + N_NODES;
    d = dstJ[e - N_EDGES] + N_NODES;
    eap = eaJ + (size_t)(e - N_EDGES) * ED_IN;
  }
  int pos = atomicAdd(&cursor[d], 1);
  srcS[pos] = s;
  float4 a0 = *(const float4*)eap;
  float4 a1 = *(const float4*)(eap + 4);
  *(float4*)(eaS + (size_t)pos * ED_IN) = a0;
  *(float4*)(eaS + (size_t)pos * ED_IN + 4) = a1;
}

// ---- fused edge phase: one wave per node; the two 32-lane groups split the
// edge list (stride 2), each unrolled by 2; online softmax; width-64 merge.
__global__ __launch_bounds__(256) void k_edge_fused(
    unsigned short* __restrict__ hbf, const unsigned short* __restrict__ sbf,
    const unsigned short* __restrict__ qb16, const unsigned short* __restrict__ kv16,
    const float* __restrict__ eaS, const float* __restrict__ We,
    const int* __restrict__ srcS, const int* __restrict__ start, int do_relu) {
  int w = blockIdx.x * 4 + (threadIdx.x >> 6);
  if (w >= M_ROWS) return;
  int l64 = threadIdx.x & 63;
  int g = l64 >> 5, lane = l64 & 31;
  const int s0 = start[w], s1 = start[w + 1];
  const int deg = s1 - s0;

  float4 qr[5];
#pragma unroll
  for (int i = 0; i < 5; ++i)
    qr[i] = cvt4(*(const ushort4*)(qb16 + (size_t)w * D + i * 128 + 4 * lane));

  // Gc on lane c (c<8): q[w] . We[c,:]  (computed by both groups, identical)
  float Gc = 0.f;
#pragma unroll
  for (int c = 0; c < ED_IN; ++c) {
    const float* wr = We + c * D;
    float p = 0.f;
#pragma unroll
    for (int i = 0; i < 5; ++i) {
      float4 wv = *(const float4*)(wr + i * 128 + 4 * lane);
      p += qr[i].x * wv.x + qr[i].y * wv.y + qr[i].z * wv.z + qr[i].w * wv.w;
    }
#pragma unroll
    for (int m = 1; m < 32; m <<= 1) p += __shfl_xor(p, m, 32);
    if (lane == c) Gc = p;
  }

  float mx = NEGBIG, Sp = 0.f, Sea = 0.f;
  float4 acc[5];
#pragma unroll
  for (int i = 0; i < 5; ++i) acc[i] = make_float4(0.f, 0.f, 0.f, 0.f);

  const int U = (deg + 3) >> 2;
  for (int u = 0; u < U; ++u) {
    int p0 = s0 + g + 4 * u;
    int p1 = p0 + 2;
    bool ok0 = p0 < s1, ok1 = p1 < s1;
    int c0 = min(p0, 2 * N_EDGES - 1);
    int c1 = min(p1, 2 * N_EDGES - 1);
    int sj0 = srcS[c0], sj1 = srcS[c1];
    const unsigned short* r0 = kv16 + (size_t)sj0 * 2 * D;
    const unsigned short* r1 = kv16 + (size_t)sj1 * 2 * D;
    float part0 = 0.f, part1 = 0.f;
    float4 vv0[5], vv1[5];
#pragma unroll
    for (int i = 0; i < 5; ++i) {
      int off = i * 128 + 4 * lane;
      float4 k0 = cvt4(*(const ushort4*)(r0 + off));
      float4 k1 = cvt4(*(const ushort4*)(r1 + off));
      vv0[i] = cvt4(*(const ushort4*)(r0 + D + off));
      vv1[i] = cvt4(*(const ushort4*)(r1 + D + off));
      part0 += qr[i].x * k0.x + qr[i].y * k0.y + qr[i].z * k0.z + qr[i].w * k0.w;
      part1 += qr[i].x * k1.x + qr[i].y * k1.y + qr[i].z * k1.z + qr[i].w * k1.w;
    }
    float ea0 = (lane < ED_IN) ? eaS[(size_t)c0 * ED_IN + lane] : 0.f;
    float ea1 = (lane < ED_IN) ? eaS[(size_t)c1 * ED_IN + lane] : 0.f;
    part0 += ea0 * Gc;
    part1 += ea1 * Gc;
#pragma unroll
    for (int m = 1; m < 32; m <<= 1) {
      part0 += __shfl_xor(part0, m, 32);
      part1 += __shfl_xor(part1, m, 32);
    }
    float sc0 = ok0 ? part0 * SCORE_SCALE : NEGBIG;
    float sc1 = ok1 ? part1 * SCORE_SCALE : NEGBIG;
    float m2 = fmaxf(sc0, sc1);
    if (m2 > mx) {
      float cs = __expf(mx - m2);
      float pA = __expf(sc0 - m2);
      float pB = __expf(sc1 - m2);
      mx = m2;
      Sp = Sp * cs + pA + pB;
      Sea = Sea * cs + pA * ea0 + pB * ea1;
#pragma unroll
      for (int i = 0; i < 5; ++i) {
        acc[i].x = acc[i].x * cs + pA * vv0[i].x + pB * vv1[i].x;
        acc[i].y = acc[i].y * cs + pA * vv0[i].y + pB * vv1[i].y;
        acc[i].z = acc[i].z * cs + pA * vv0[i].z + pB * vv1[i].z;
        acc[i].w = acc[i].w * cs + pA * vv0[i].w + pB * vv1[i].w;
      }
    } else {
      float pA = __expf(sc0 - mx);
      float pB = __expf(sc1 - mx);
      Sp += pA + pB;
      Sea += pA * ea0 + pB * ea1;
#pragma unroll
      for (int i = 0; i < 5; ++i) {
        acc[i].x += pA * vv0[i].x + pB * vv1[i].x;
        acc[i].y += pA * vv0[i].y + pB * vv1[i].y;
        acc[i].z += pA * vv0[i].z + pB * vv1[i].z;
        acc[i].w += pA * vv0[i].w + pB * vv1[i].w;
      }
    }
  }

  // merge the two groups' online-softmax states (width-64 xor shuffles).
  // A group with no valid edges keeps mx=NEGBIG -> its factor exp(mx-mn)=0.
  float mo = __shfl_xor(mx, 32);
  float mn = fmaxf(mx, mo);
  float a = __expf(mx - mn);
  float b = __expf(mo - mn);
  float Spo = __shfl_xor(Sp, 32);
  Sp = Sp * a + Spo * b;
  float Seao = __shfl_xor(Sea, 32);
  Sea = Sea * a + Seao * b;
#pragma unroll
  for (int i = 0; i < 5; ++i) {
    float ox = __shfl_xor(acc[i].x, 32);
    float oy = __shfl_xor(acc[i].y, 32);
    float oz = __shfl_xor(acc[i].z, 32);
    float ow = __shfl_xor(acc[i].w, 32);
    acc[i].x = acc[i].x * a + ox * b;
    acc[i].y = acc[i].y * a + oy * b;
    acc[i].z = acc[i].z * a + oz * b;
    acc[i].w = acc[i].w * a + ow * b;
  }
  float inv = 1.0f / (Sp + 1e-16f);
  float seac[ED_IN];
#pragma unroll
  for (int c = 0; c < ED_IN; ++c) seac[c] = __shfl(Sea, c, 32);

  // split epilogue chunks between the two groups (identical merged state)
  for (int i = g; i < 5; i += 2) {
    int d = i * 128 + 4 * lane;
    float4 term = acc[i];
#pragma unroll
    for (int c = 0; c < ED_IN; ++c) {
      float4 wv = *(const float4*)(We + c * D + d);
      term.x += seac[c] * wv.x;
      term.y += seac[c] * wv.y;
      term.z += seac[c] * wv.z;
      term.w += seac[c] * wv.w;
    }
    ushort4 sv = *(const ushort4*)(sbf + (size_t)w * D + d);
    float vx = bf2f(sv.x) + term.x * inv;
    float vy = bf2f(sv.y) + term.y * inv;
    float vz = bf2f(sv.z) + term.z * inv;
    float vw = bf2f(sv.w) + term.w * inv;
    if (do_relu) {
      vx = fmaxf(vx, 0.f);
      vy = fmaxf(vy, 0.f);
      vz = fmaxf(vz, 0.f);
      vw = fmaxf(vw, 0.f);
    }
    ushort4 hb;
    hb.x = f2bf(vx);
    hb.y = f2bf(vy);
    hb.z = f2bf(vz);
    hb.w = f2bf(vw);
    *(ushort4*)(hbf + (size_t)w * D + d) = hb;
  }
}

// global add pool over both graphs (reads final-layer hbf)
__global__ void k_pool(const unsigned short* __restrict__ hbf,
                       const int* __restrict__ batI, const int* __restrict__ batJ,
                       float* __restrict__ pooled) {
  int t = blockIdx.x * blockDim.x + threadIdx.x;
  if (t >= M_ROWS * D) return;
  int n = t / D, d = t % D;
  int b = (n < N_NODES) ? batI[n] : (batJ[n - N_NODES] + NB);
  atomicAdd(pooled + (size_t)b * D + d, bf2f(hbf[t]));
}

// per graph row: LayerNorm -> @Wemb + bemb -> ReLU  (grid 2*NB)
__global__ __launch_bounds__(256) void k_head(const float* __restrict__ pooled,
                                              const float* __restrict__ gam,
                                              const float* __restrict__ bet,
                                              const float* __restrict__ Wemb,
                                              const float* __restrict__ bemb,
                                              float* __restrict__ z) {
  __shared__ float sh[D];
  __shared__ float red[4];
  int b = blockIdx.x, tid = threadIdx.x;
  float local = 0.f;
  for (int c = tid; c < D; c += 256) {
    float val = pooled[(size_t)b * D + c];
    sh[c] = val;
    local += val;
  }
#pragma unroll
  for (int off = 32; off > 0; off >>= 1) local += __shfl_down(local, off);
  if ((tid & 63) == 0) red[tid >> 6] = local;
  __syncthreads();
  float mu = (red[0] + red[1] + red[2] + red[3]) * (1.0f / D);
  __syncthreads();
  float lv = 0.f;
  for (int c = tid; c < D; c += 256) {
    float t2 = sh[c] - mu;
    lv += t2 * t2;
  }
#pragma unroll
  for (int off = 32; off > 0; off >>= 1) lv += __shfl_down(lv, off);
  if ((tid & 63) == 0) red[tid >> 6] = lv;
  __syncthreads();
  float var = (red[0] + red[1] + red[2] + red[3]) * (1.0f / D);
  float rstd = rsqrtf(var + 1e-5f);
  __syncthreads();
  for (int c = tid; c < D; c += 256) sh[c] = (sh[c] - mu) * rstd * gam[c] + bet[c];
  __syncthreads();
  for (int d = tid; d < D; d += 256) {
    float acc = bemb[d];
    for (int c = 0; c < D; ++c) acc += sh[c] * Wemb[c * D + d];
    z[(size_t)b * D + d] = fmaxf(acc, 0.f);
  }
}

__global__ void k_cosine(const float* __restrict__ zi, const float* __restrict__ zj,
                         float* __restrict__ out) {
  int b = blockIdx.x, lane = threadIdx.x;
  float dot = 0.f, ni = 0.f, nj = 0.f;
  for (int d = lane; d < D; d += 64) {
    float a = zi[(size_t)b * D + d], c = zj[(size_t)b * D + d];
    dot += a * c;
    ni += a * a;
    nj += c * c;
  }
#pragma unroll
  for (int off = 32; off > 0; off >>= 1) {
    dot += __shfl_down(dot, off);
    ni += __shfl_down(ni, off);
    nj += __shfl_down(nj, off);
  }
  if (lane == 0)
    out[b] = dot / (fmaxf(sqrtf(ni), 1e-8f) * fmaxf(sqrtf(nj), 1e-8f));
}

extern "C" void kernel_launch(void* const* d_in, const int* in_sizes, int n_in,
                              void* d_out, int out_size, void* d_ws, size_t ws_size,
                              hipStream_t stream) {
  (void)in_sizes; (void)n_in; (void)out_size; (void)ws_size;
  const float* xI = (const float*)d_in[0];
  const int* eiI = (const int*)d_in[1];
  const float* eaI = (const float*)d_in[2];
  const int* batI = (const int*)d_in[3];
  const float* xJ = (const float*)d_in[4];
  const int* eiJ = (const int*)d_in[5];
  const float* eaJ = (const float*)d_in[6];
  const int* batJ = (const int*)d_in[7];
  const float* W0q = (const float*)d_in[8];
  const float* b0q = (const float*)d_in[9];
  const float* W0k = (const float*)d_in[10];
  const float* b0k = (const float*)d_in[11];
  const float* W0v = (const float*)d_in[12];
  const float* b0v = (const float*)d_in[13];
  const float* W0e = (const float*)d_in[14];
  const float* W0s = (const float*)d_in[15];
  const float* b0s = (const float*)d_in[16];
  const float* Wq = (const float*)d_in[17];
  const float* bq = (const float*)d_in[18];
  const float* Wk = (const float*)d_in[19];
  const float* bk = (const float*)d_in[20];
  const float* Wv = (const float*)d_in[21];
  const float* bv = (const float*)d_in[22];
  const float* We = (const float*)d_in[23];
  const float* Ws = (const float*)d_in[24];
  const float* bs = (const float*)d_in[25];
  const float* ln_g = (const float*)d_in[26];
  const float* ln_b = (const float*)d_in[27];
  const float* Wemb = (const float*)d_in[28];
  const float* bemb = (const float*)d_in[29];

  const size_t ND2 = (size_t)M_ROWS * D;
  float* pooled = (float*)d_ws;                  // 2NB*D
  float* z = pooled + (size_t)2 * NB * D;        // 2NB*D
  float* eaS = z + (size_t)2 * NB * D;           // 2E*8
  unsigned short* qbf = (unsigned short*)(eaS + (size_t)2 * N_EDGES * ED_IN);
  unsigned short* kvbf = qbf + ND2;              // 2*ND2 (k/v interleaved)
  unsigned short* hbf = kvbf + 2 * ND2;          // ND2
  unsigned short* sbf = hbf + ND2;               // ND2 (also A-OOB pad)
  unsigned short* Wt = sbf + ND2;                // 20*D*D
  int* cnt = (int*)(Wt + (size_t)(NLAYERS - 1) * 4 * D * D);  // 2N
  int* start = cnt + M_ROWS;                     // 2N+1
  int* cursor = start + M_ROWS + 1;              // 2N
  int* srcS = cursor + M_ROWS;                   // 2E

  const int* srcI = eiI;
  const int* dstI = eiI + N_EDGES;
  const int* srcJ = eiJ;
  const int* dstJ = eiJ + N_EDGES;

  dim3 gLin4((M_ROWS * D + 255) / 256, 1, 4);
  dim3 gGemm(8 * 20 * 20);
  dim3 gEdge((M_ROWS + 3) / 4);
  dim3 gE((2 * N_EDGES + 255) / 256);
  dim3 gPool((M_ROWS * D + 255) / 256);

  k_wprep<<<dim3(D / 32, D / 32, (NLAYERS - 1) * 4), 256, 0, stream>>>(Wq, Wk, Wv, Ws, Wt);

  // combined CSR (+ ea gather into CSR order)
  hipMemsetAsync(cnt, 0, M_ROWS * sizeof(int), stream);
  k_hist<<<gE, 256, 0, stream>>>(dstI, dstJ, cnt);
  k_scan<<<1, 1024, 0, stream>>>(cnt, start, cursor);
  k_scatter<<<gE, 256, 0, stream>>>(srcI, dstI, srcJ, dstJ, eaI, eaJ, cursor,
                                    srcS, eaS);

  // layer 0
  k_lin4<<<gLin4, 256, 0, stream>>>(xI, xJ, W0q, b0q, W0k, b0k, W0v, b0v, W0s,
                                    b0s, qbf, kvbf, sbf);
  k_edge_fused<<<gEdge, 256, 0, stream>>>(hbf, sbf, qbf, kvbf, eaS, W0e, srcS,
                                          start, 1);

  // layers 1..5
  for (int l = 0; l < NLAYERS - 1; ++l) {
    const unsigned short* WtL = Wt + (size_t)l * 4 * D * D;
    const float* Wel = We + (size_t)l * ED_IN * D;
    int last = (l == NLAYERS - 2);
    k_gemm_bf16<<<gGemm, 256, 0, stream>>>(
        hbf, WtL, bq + (size_t)l * D, bk + (size_t)l * D, bv + (size_t)l * D,
        bs + (size_t)l * D, qbf, kvbf, sbf);
    k_edge_fused<<<gEdge, 256, 0, stream>>>(hbf, sbf, qbf, kvbf, eaS, Wel, srcS,
                                            start, last ? 0 : 1);
  }

  hipMemsetAsync(pooled, 0, (size_t)2 * NB * D * sizeof(float), stream);
  k_pool<<<gPool, 256, 0, stream>>>(hbf, batI, batJ, pooled);
  k_head<<<2 * NB, 256, 0, stream>>>(pooled, ln_g, ln_b, Wemb, bemb, z);
  k_cosine<<<NB, 64, 0, stream>>>(z, z + (size_t)NB * D, (float*)d_out);
}

// Round 8
// 1780.727 us; speedup vs baseline: 6.7133x; 1.0856x over previous
//
#include <hip/hip_runtime.h>

#define N_NODES 10000
#define N_EDGES 160000
#define NB 64
#define D 640
#define ND_IN 4
#define ED_IN 8
#define NLAYERS 6
#define M_ROWS (2 * N_NODES)  // both graphs batched

#define SCORE_SCALE 0.039528470752104741f  // 1/sqrt(640)
#define NEGBIG -3.4e38f

typedef __attribute__((ext_vector_type(8))) short short8;
typedef __attribute__((ext_vector_type(4))) float floatx4;

__device__ __forceinline__ unsigned short f2bf(float f) {
  unsigned u = __float_as_uint(f);
  u += 0x7fffu + ((u >> 16) & 1);  // RNE
  return (unsigned short)(u >> 16);
}
__device__ __forceinline__ float bf2f(unsigned short s) {
  return __uint_as_float((unsigned)s << 16);
}
__device__ __forceinline__ void gload_lds16(const void* g, void* l) {
  __builtin_amdgcn_global_load_lds(
      (const __attribute__((address_space(1))) void*)g,
      (__attribute__((address_space(3))) void*)l, 16, 0, 0);
}
__device__ __forceinline__ float4 cvt4(ushort4 s) {
  return make_float4(bf2f(s.x), bf2f(s.y), bf2f(s.z), bf2f(s.w));
}

// ---- layer-0 projections: q,skip separate; k,v interleaved in kv ----
__global__ void k_lin4(const float* __restrict__ xI, const float* __restrict__ xJ,
                       const float* __restrict__ Wq, const float* __restrict__ bq,
                       const float* __restrict__ Wk, const float* __restrict__ bk,
                       const float* __restrict__ Wv, const float* __restrict__ bv,
                       const float* __restrict__ Ws, const float* __restrict__ bs,
                       unsigned short* __restrict__ oqb, unsigned short* __restrict__ okv,
                       unsigned short* __restrict__ osb) {
  int t = blockIdx.x * blockDim.x + threadIdx.x;
  if (t >= M_ROWS * D) return;
  int z = blockIdx.z;
  const float* W = (z == 0) ? Wq : (z == 1) ? Wk : (z == 2) ? Wv : Ws;
  const float* b = (z == 0) ? bq : (z == 1) ? bk : (z == 2) ? bv : bs;
  int n = t / D, d = t % D;
  const float* xr = (n < N_NODES) ? xI + (size_t)n * ND_IN
                                  : xJ + (size_t)(n - N_NODES) * ND_IN;
  float acc = b[d];
#pragma unroll
  for (int c = 0; c < ND_IN; ++c) acc += xr[c] * W[c * D + d];
  unsigned short r = f2bf(acc);
  if (z == 0) oqb[t] = r;
  else if (z == 1) okv[(size_t)(2 * n) * D + d] = r;
  else if (z == 2) okv[(size_t)(2 * n + 1) * D + d] = r;
  else osb[t] = r;
}

// one-time: Wt[l][mat][n][k] = bf16(W[l][mat][k][n])
__global__ __launch_bounds__(256) void k_wprep(const float* __restrict__ Wq,
                                               const float* __restrict__ Wk,
                                               const float* __restrict__ Wv,
                                               const float* __restrict__ Ws,
                                               unsigned short* __restrict__ Wt) {
  __shared__ float tile[32][33];
  int mt = blockIdx.z;
  int l = mt >> 2, mat = mt & 3;
  const float* W =
      (mat == 0 ? Wq : mat == 1 ? Wk : mat == 2 ? Wv : Ws) + (size_t)l * D * D;
  int tk = blockIdx.x * 32, tn = blockIdx.y * 32;
  int tx = threadIdx.x & 31, ty = threadIdx.x >> 5;
#pragma unroll
  for (int i = 0; i < 32; i += 8)
    tile[ty + i][tx] = W[(size_t)(tk + ty + i) * D + tn + tx];
  __syncthreads();
  unsigned short* dst = Wt + (size_t)mt * D * D;
#pragma unroll
  for (int i = 0; i < 32; i += 8)
    dst[(size_t)(tn + ty + i) * D + tk + tx] = f2bf(tile[tx][ty + i]);
}

// bf16 MFMA GEMM over 2N rows, XCD-swizzled flat grid, BK=64 (10 K-iters),
// swapped-operand MFMA so each lane holds 4 consecutive output cols
// (row = l15, col = l4*4 + reg) -> ushort4 packed stores.
#define BM 128
#define BN 128
#define BK 64
#define RBANDS ((M_ROWS + BM - 1) / BM)  // 157
__global__ __launch_bounds__(256) void k_gemm_bf16(
    const unsigned short* __restrict__ Abf, const unsigned short* __restrict__ Wt,
    const float* __restrict__ b0, const float* __restrict__ b1,
    const float* __restrict__ b2, const float* __restrict__ b3,
    unsigned short* __restrict__ oqb, unsigned short* __restrict__ okv,
    unsigned short* __restrict__ osb) {
  __shared__ __attribute__((aligned(16))) unsigned short lA[BM * BK];  // 16 KB
  __shared__ __attribute__((aligned(16))) unsigned short lB[BN * BK];  // 16 KB
  const int f = blockIdx.x;
  const int xcd = f & 7;
  const int slot = f >> 3;
  const int grp = slot / 20;
  const int tt = slot - grp * 20;  // 0..19
  const int r = xcd + (grp << 3);
  if (r >= RBANDS) return;
  const int z = tt / 5;
  const int by = tt - z * 5;
  const unsigned short* Wz = Wt + (size_t)z * D * D;
  const float* bias = (z == 0) ? b0 : (z == 1) ? b1 : (z == 2) ? b2 : b3;
  const int bm = r * BM, bn = by * BN;
  const int t = threadIdx.x;
  const int lane = t & 63, wv = t >> 6;
  const int wm = (wv & 1) * 64, wn = (wv >> 1) * 64;
  const int l15 = lane & 15, l4 = lane >> 4;
  const int srow = lane >> 3;  // staging: row within 8-row chunk
  const int scb = lane & 7;    // staging: physical colblk (8 x 8 ushorts = 128B row)

  floatx4 acc[4][4] = {};  // [ni][mi]

  for (int k0 = 0; k0 < D; k0 += BK) {
#pragma unroll
    for (int i = 0; i < 4; ++i) {
      int row = wv * 32 + i * 8 + srow;
      int lcb = scb ^ (row & 7);  // logical colblk stored at physical scb
      gload_lds16(Abf + (size_t)(bm + row) * D + k0 + lcb * 8,
                  lA + (size_t)(wv * 32 + i * 8) * BK);
      gload_lds16(Wz + (size_t)(bn + row) * D + k0 + lcb * 8,
                  lB + (size_t)(wv * 32 + i * 8) * BK);
    }
    __syncthreads();
#pragma unroll
    for (int kk = 0; kk < 2; ++kk) {
      short8 af[4], bfr[4];
#pragma unroll
      for (int i = 0; i < 4; ++i) {
        int rowA = wm + i * 16 + l15;
        int pcA = (kk * 4 + l4) ^ (rowA & 7);
        af[i] = *(const short8*)(lA + rowA * BK + pcA * 8);
        int rowB = wn + i * 16 + l15;
        int pcB = (kk * 4 + l4) ^ (rowB & 7);
        bfr[i] = *(const short8*)(lB + rowB * BK + pcB * 8);
      }
#pragma unroll
      for (int ni = 0; ni < 4; ++ni)
#pragma unroll
        for (int mi = 0; mi < 4; ++mi)
          acc[ni][mi] = __builtin_amdgcn_mfma_f32_16x16x32_bf16(
              bfr[ni], af[mi], acc[ni][mi], 0, 0, 0);
    }
    __syncthreads();
  }
  // epilogue: row = bm+wm+mi*16+l15 ; col = bn+wn+ni*16+l4*4+{0..3}
  float4 bia[4];
#pragma unroll
  for (int ni = 0; ni < 4; ++ni)
    bia[ni] = *(const float4*)(bias + bn + wn + ni * 16 + l4 * 4);
#pragma unroll
  for (int mi = 0; mi < 4; ++mi) {
    int row = bm + wm + mi * 16 + l15;
    if (row >= M_ROWS) continue;
    size_t rbase = (z == 1)   ? (size_t)(2 * row) * D
                   : (z == 2) ? (size_t)(2 * row + 1) * D
                              : (size_t)row * D;
    unsigned short* dst = (z == 0) ? oqb : (z == 3) ? osb : okv;
#pragma unroll
    for (int ni = 0; ni < 4; ++ni) {
      int col = bn + wn + ni * 16 + l4 * 4;
      ushort4 pk;
      pk.x = f2bf(acc[ni][mi][0] + bia[ni].x);
      pk.y = f2bf(acc[ni][mi][1] + bia[ni].y);
      pk.z = f2bf(acc[ni][mi][2] + bia[ni].z);
      pk.w = f2bf(acc[ni][mi][3] + bia[ni].w);
      *(ushort4*)(dst + rbase + col) = pk;
    }
  }
}

// ---- combined-graph CSR build ----
__global__ void k_hist(const int* __restrict__ dstI, const int* __restrict__ dstJ,
                       int* __restrict__ cnt) {
  int e = blockIdx.x * blockDim.x + threadIdx.x;
  if (e >= 2 * N_EDGES) return;
  int d = (e < N_EDGES) ? dstI[e] : (dstJ[e - N_EDGES] + N_NODES);
  atomicAdd(&cnt[d], 1);
}

__global__ __launch_bounds__(1024) void k_scan(const int* __restrict__ cnt,
                                               int* __restrict__ start,
                                               int* __restrict__ cursor) {
  __shared__ int sh[1024];
  __shared__ int carry_sh;
  int tid = threadIdx.x;
  if (tid == 0) {
    carry_sh = 0;
    start[0] = 0;
  }
  __syncthreads();
  for (int base = 0; base < M_ROWS; base += 1024) {
    int idx = base + tid;
    int v = (idx < M_ROWS) ? cnt[idx] : 0;
    sh[tid] = v;
    __syncthreads();
    for (int off = 1; off < 1024; off <<= 1) {
      int t = (tid >= off) ? sh[tid - off] : 0;
      __syncthreads();
      sh[tid] += t;
      __syncthreads();
    }
    int incl = sh[tid] + carry_sh;
    if (idx < M_ROWS) {
      start[idx + 1] = incl;
      cursor[idx] = incl - v;
    }
    __syncthreads();
    if (tid == 1023) carry_sh = incl;
    __syncthreads();
  }
}

// scatter + gather edge attrs into CSR order (eaS)
__global__ void k_scatter(const int* __restrict__ srcI, const int* __restrict__ dstI,
                          const int* __restrict__ srcJ, const int* __restrict__ dstJ,
                          const float* __restrict__ eaI, const float* __restrict__ eaJ,
                          int* __restrict__ cursor, int* __restrict__ srcS,
                          float* __restrict__ eaS) {
  int e = blockIdx.x * blockDim.x + threadIdx.x;
  if (e >= 2 * N_EDGES) return;
  int s, d;
  const float* eap;
  if (e < N_EDGES) {
    s = srcI[e];
    d = dstI[e];
    eap = eaI + (size_t)e * ED_IN;
  } else {
    s = srcJ[e - N_EDGES] + N_NODES;
    d = dstJ[e - N_EDGES] + N_NODES;
    eap = eaJ + (size_t)(e - N_EDGES) * ED_IN;
  }
  int pos = atomicAdd(&cursor[d], 1);
  srcS[pos] = s;
  float4 a0 = *(const float4*)eap;
  float4 a1 = *(const float4*)(eap + 4);
  *(float4*)(eaS + (size_t)pos * ED_IN) = a0;
  *(float4*)(eaS + (size_t)pos * ED_IN + 4) = a1;
}

// ---- fused edge phase: one wave per node; two 32-lane groups split the edge
// list (stride 2), each unrolled by 2, with next-iter srcS prefetch; online
// softmax; width-64 merge.
__global__ __launch_bounds__(256) void k_edge_fused(
    unsigned short* __restrict__ hbf, const unsigned short* __restrict__ sbf,
    const unsigned short* __restrict__ qb16, const unsigned short* __restrict__ kv16,
    const float* __restrict__ eaS, const float* __restrict__ We,
    const int* __restrict__ srcS, const int* __restrict__ start, int do_relu) {
  int w = blockIdx.x * 4 + (threadIdx.x >> 6);
  if (w >= M_ROWS) return;
  int l64 = threadIdx.x & 63;
  int g = l64 >> 5, lane = l64 & 31;
  const int s0 = start[w], s1 = start[w + 1];
  const int deg = s1 - s0;
  const int EMAX = 2 * N_EDGES - 1;

  float4 qr[5];
#pragma unroll
  for (int i = 0; i < 5; ++i)
    qr[i] = cvt4(*(const ushort4*)(qb16 + (size_t)w * D + i * 128 + 4 * lane));

  // Gc on lane c (c<8): q[w] . We[c,:]
  float Gc = 0.f;
#pragma unroll
  for (int c = 0; c < ED_IN; ++c) {
    const float* wr = We + c * D;
    float p = 0.f;
#pragma unroll
    for (int i = 0; i < 5; ++i) {
      float4 wv = *(const float4*)(wr + i * 128 + 4 * lane);
      p += qr[i].x * wv.x + qr[i].y * wv.y + qr[i].z * wv.z + qr[i].w * wv.w;
    }
#pragma unroll
    for (int m = 1; m < 32; m <<= 1) p += __shfl_xor(p, m, 32);
    if (lane == c) Gc = p;
  }

  float mx = NEGBIG, Sp = 0.f, Sea = 0.f;
  float4 acc[5];
#pragma unroll
  for (int i = 0; i < 5; ++i) acc[i] = make_float4(0.f, 0.f, 0.f, 0.f);

  int p0 = s0 + g, p1 = p0 + 2;
  int c0 = min(p0, EMAX), c1 = min(p1, EMAX);
  int sj0 = srcS[c0], sj1 = srcS[c1];
  const int U = (deg + 3) >> 2;
  for (int u = 0; u < U; ++u) {
    bool ok0 = p0 < s1, ok1 = p1 < s1;
    int cc0 = c0, cc1 = c1;
    int tj0 = sj0, tj1 = sj1;
    // prefetch next iteration's indices (loads overlap this iteration's math)
    p0 += 4;
    p1 += 4;
    c0 = min(p0, EMAX);
    c1 = min(p1, EMAX);
    sj0 = srcS[c0];
    sj1 = srcS[c1];

    const unsigned short* r0 = kv16 + (size_t)tj0 * 2 * D;
    const unsigned short* r1 = kv16 + (size_t)tj1 * 2 * D;
    float part0 = 0.f, part1 = 0.f;
    float4 vv0[5], vv1[5];
#pragma unroll
    for (int i = 0; i < 5; ++i) {
      int off = i * 128 + 4 * lane;
      float4 k0 = cvt4(*(const ushort4*)(r0 + off));
      float4 k1 = cvt4(*(const ushort4*)(r1 + off));
      vv0[i] = cvt4(*(const ushort4*)(r0 + D + off));
      vv1[i] = cvt4(*(const ushort4*)(r1 + D + off));
      part0 += qr[i].x * k0.x + qr[i].y * k0.y + qr[i].z * k0.z + qr[i].w * k0.w;
      part1 += qr[i].x * k1.x + qr[i].y * k1.y + qr[i].z * k1.z + qr[i].w * k1.w;
    }
    float ea0 = (lane < ED_IN) ? eaS[(size_t)cc0 * ED_IN + lane] : 0.f;
    float ea1 = (lane < ED_IN) ? eaS[(size_t)cc1 * ED_IN + lane] : 0.f;
    part0 += ea0 * Gc;
    part1 += ea1 * Gc;
#pragma unroll
    for (int m = 1; m < 32; m <<= 1) {
      part0 += __shfl_xor(part0, m, 32);
      part1 += __shfl_xor(part1, m, 32);
    }
    float sc0 = ok0 ? part0 * SCORE_SCALE : NEGBIG;
    float sc1 = ok1 ? part1 * SCORE_SCALE : NEGBIG;
    float m2 = fmaxf(sc0, sc1);
    if (m2 > mx) {
      float cs = __expf(mx - m2);
      float pA = __expf(sc0 - m2);
      float pB = __expf(sc1 - m2);
      mx = m2;
      Sp = Sp * cs + pA + pB;
      Sea = Sea * cs + pA * ea0 + pB * ea1;
#pragma unroll
      for (int i = 0; i < 5; ++i) {
        acc[i].x = acc[i].x * cs + pA * vv0[i].x + pB * vv1[i].x;
        acc[i].y = acc[i].y * cs + pA * vv0[i].y + pB * vv1[i].y;
        acc[i].z = acc[i].z * cs + pA * vv0[i].z + pB * vv1[i].z;
        acc[i].w = acc[i].w * cs + pA * vv0[i].w + pB * vv1[i].w;
      }
    } else {
      float pA = __expf(sc0 - mx);
      float pB = __expf(sc1 - mx);
      Sp += pA + pB;
      Sea += pA * ea0 + pB * ea1;
#pragma unroll
      for (int i = 0; i < 5; ++i) {
        acc[i].x += pA * vv0[i].x + pB * vv1[i].x;
        acc[i].y += pA * vv0[i].y + pB * vv1[i].y;
        acc[i].z += pA * vv0[i].z + pB * vv1[i].z;
        acc[i].w += pA * vv0[i].w + pB * vv1[i].w;
      }
    }
  }

  // merge the two groups' online-softmax states
  float mo = __shfl_xor(mx, 32);
  float mn = fmaxf(mx, mo);
  float a = __expf(mx - mn);
  float b = __expf(mo - mn);
  float Spo = __shfl_xor(Sp, 32);
  Sp = Sp * a + Spo * b;
  float Seao = __shfl_xor(Sea, 32);
  Sea = Sea * a + Seao * b;
#pragma unroll
  for (int i = 0; i < 5; ++i) {
    float ox = __shfl_xor(acc[i].x, 32);
    float oy = __shfl_xor(acc[i].y, 32);
    float oz = __shfl_xor(acc[i].z, 32);
    float ow = __shfl_xor(acc[i].w, 32);
    acc[i].x = acc[i].x * a + ox * b;
    acc[i].y = acc[i].y * a + oy * b;
    acc[i].z = acc[i].z * a + oz * b;
    acc[i].w = acc[i].w * a + ow * b;
  }
  float inv = 1.0f / (Sp + 1e-16f);
  float seac[ED_IN];
#pragma unroll
  for (int c = 0; c < ED_IN; ++c) seac[c] = __shfl(Sea, c, 32);

  for (int i = g; i < 5; i += 2) {
    int d = i * 128 + 4 * lane;
    float4 term = acc[i];
#pragma unroll
    for (int c = 0; c < ED_IN; ++c) {
      float4 wv = *(const float4*)(We + c * D + d);
      term.x += seac[c] * wv.x;
      term.y += seac[c] * wv.y;
      term.z += seac[c] * wv.z;
      term.w += seac[c] * wv.w;
    }
    ushort4 sv = *(const ushort4*)(sbf + (size_t)w * D + d);
    float vx = bf2f(sv.x) + term.x * inv;
    float vy = bf2f(sv.y) + term.y * inv;
    float vz = bf2f(sv.z) + term.z * inv;
    float vw = bf2f(sv.w) + term.w * inv;
    if (do_relu) {
      vx = fmaxf(vx, 0.f);
      vy = fmaxf(vy, 0.f);
      vz = fmaxf(vz, 0.f);
      vw = fmaxf(vw, 0.f);
    }
    ushort4 hb;
    hb.x = f2bf(vx);
    hb.y = f2bf(vy);
    hb.z = f2bf(vz);
    hb.w = f2bf(vw);
    *(ushort4*)(hbf + (size_t)w * D + d) = hb;
  }
}

// per-batch node ranges via binary search (batch arrays are sorted)
__global__ void k_ranges(const int* __restrict__ batI, const int* __restrict__ batJ,
                         int* __restrict__ rng) {
  int b = threadIdx.x;
  if (b > 2 * NB) return;
  if (b == 2 * NB) {
    rng[b] = M_ROWS;
    return;
  }
  const int* bat = (b < NB) ? batI : batJ;
  int tgt = (b < NB) ? b : b - NB;
  int lo = 0, hi = N_NODES;
  while (lo < hi) {
    int mid = (lo + hi) >> 1;
    if (bat[mid] < tgt) lo = mid + 1;
    else hi = mid;
  }
  rng[b] = lo + ((b < NB) ? 0 : N_NODES);
}

// segmented pool: block b sums rows [rng[b], rng[b+1]) — no atomics
__global__ __launch_bounds__(256) void k_pool_seg(const unsigned short* __restrict__ hbf,
                                                  const int* __restrict__ rng,
                                                  float* __restrict__ pooled) {
  int b = blockIdx.x;
  int lo = rng[b], hi = rng[b + 1];
  int ch = threadIdx.x;  // ushort4 chunk id, 0..159
  if (ch >= 160) return;
  float4 s = make_float4(0.f, 0.f, 0.f, 0.f);
  for (int n = lo; n < hi; ++n) {
    ushort4 v = *(const ushort4*)(hbf + (size_t)n * D + ch * 4);
    s.x += bf2f(v.x);
    s.y += bf2f(v.y);
    s.z += bf2f(v.z);
    s.w += bf2f(v.w);
  }
  *(float4*)(pooled + (size_t)b * D + ch * 4) = s;
}

// per graph row: LayerNorm -> @Wemb + bemb -> ReLU  (grid 2*NB)
__global__ __launch_bounds__(256) void k_head(const float* __restrict__ pooled,
                                              const float* __restrict__ gam,
                                              const float* __restrict__ bet,
                                              const float* __restrict__ Wemb,
                                              const float* __restrict__ bemb,
                                              float* __restrict__ z) {
  __shared__ float sh[D];
  __shared__ float red[4];
  int b = blockIdx.x, tid = threadIdx.x;
  float local = 0.f;
  for (int c = tid; c < D; c += 256) {
    float val = pooled[(size_t)b * D + c];
    sh[c] = val;
    local += val;
  }
#pragma unroll
  for (int off = 32; off > 0; off >>= 1) local += __shfl_down(local, off);
  if ((tid & 63) == 0) red[tid >> 6] = local;
  __syncthreads();
  float mu = (red[0] + red[1] + red[2] + red[3]) * (1.0f / D);
  __syncthreads();
  float lv = 0.f;
  for (int c = tid; c < D; c += 256) {
    float t2 = sh[c] - mu;
    lv += t2 * t2;
  }
#pragma unroll
  for (int off = 32; off > 0; off >>= 1) lv += __shfl_down(lv, off);
  if ((tid & 63) == 0) red[tid >> 6] = lv;
  __syncthreads();
  float var = (red[0] + red[1] + red[2] + red[3]) * (1.0f / D);
  float rstd = rsqrtf(var + 1e-5f);
  __syncthreads();
  for (int c = tid; c < D; c += 256) sh[c] = (sh[c] - mu) * rstd * gam[c] + bet[c];
  __syncthreads();
  for (int d = tid; d < D; d += 256) {
    float acc = bemb[d];
    for (int c = 0; c < D; ++c) acc += sh[c] * Wemb[c * D + d];
    z[(size_t)b * D + d] = fmaxf(acc, 0.f);
  }
}

__global__ void k_cosine(const float* __restrict__ zi, const float* __restrict__ zj,
                         float* __restrict__ out) {
  int b = blockIdx.x, lane = threadIdx.x;
  float dot = 0.f, ni = 0.f, nj = 0.f;
  for (int d = lane; d < D; d += 64) {
    float a = zi[(size_t)b * D + d], c = zj[(size_t)b * D + d];
    dot += a * c;
    ni += a * a;
    nj += c * c;
  }
#pragma unroll
  for (int off = 32; off > 0; off >>= 1) {
    dot += __shfl_down(dot, off);
    ni += __shfl_down(ni, off);
    nj += __shfl_down(nj, off);
  }
  if (lane == 0)
    out[b] = dot / (fmaxf(sqrtf(ni), 1e-8f) * fmaxf(sqrtf(nj), 1e-8f));
}

extern "C" void kernel_launch(void* const* d_in, const int* in_sizes, int n_in,
                              void* d_out, int out_size, void* d_ws, size_t ws_size,
                              hipStream_t stream) {
  (void)in_sizes; (void)n_in; (void)out_size; (void)ws_size;
  const float* xI = (const float*)d_in[0];
  const int* eiI = (const int*)d_in[1];
  const float* eaI = (const float*)d_in[2];
  const int* batI = (const int*)d_in[3];
  const float* xJ = (const float*)d_in[4];
  const int* eiJ = (const int*)d_in[5];
  const float* eaJ = (const float*)d_in[6];
  const int* batJ = (const int*)d_in[7];
  const float* W0q = (const float*)d_in[8];
  const float* b0q = (const float*)d_in[9];
  const float* W0k = (const float*)d_in[10];
  const float* b0k = (const float*)d_in[11];
  const float* W0v = (const float*)d_in[12];
  const float* b0v = (const float*)d_in[13];
  const float* W0e = (const float*)d_in[14];
  const float* W0s = (const float*)d_in[15];
  const float* b0s = (const float*)d_in[16];
  const float* Wq = (const float*)d_in[17];
  const float* bq = (const float*)d_in[18];
  const float* Wk = (const float*)d_in[19];
  const float* bk = (const float*)d_in[20];
  const float* Wv = (const float*)d_in[21];
  const float* bv = (const float*)d_in[22];
  const float* We = (const float*)d_in[23];
  const float* Ws = (const float*)d_in[24];
  const float* bs = (const float*)d_in[25];
  const float* ln_g = (const float*)d_in[26];
  const float* ln_b = (const float*)d_in[27];
  const float* Wemb = (const float*)d_in[28];
  const float* bemb = (const float*)d_in[29];

  const size_t ND2 = (size_t)M_ROWS * D;
  float* pooled = (float*)d_ws;                  // 2NB*D
  float* z = pooled + (size_t)2 * NB * D;        // 2NB*D
  float* eaS = z + (size_t)2 * NB * D;           // 2E*8
  unsigned short* qbf = (unsigned short*)(eaS + (size_t)2 * N_EDGES * ED_IN);
  unsigned short* kvbf = qbf + ND2;              // 2*ND2 (k/v interleaved)
  unsigned short* hbf = kvbf + 2 * ND2;          // ND2
  unsigned short* sbf = hbf + ND2;               // ND2 (also A-OOB pad)
  unsigned short* Wt = sbf + ND2;                // 20*D*D
  int* cnt = (int*)(Wt + (size_t)(NLAYERS - 1) * 4 * D * D);  // 2N
  int* start = cnt + M_ROWS;                     // 2N+1
  int* cursor = start + M_ROWS + 1;              // 2N
  int* srcS = cursor + M_ROWS;                   // 2E
  int* rng = srcS + 2 * N_EDGES;                 // 2NB+1

  const int* srcI = eiI;
  const int* dstI = eiI + N_EDGES;
  const int* srcJ = eiJ;
  const int* dstJ = eiJ + N_EDGES;

  dim3 gLin4((M_ROWS * D + 255) / 256, 1, 4);
  dim3 gGemm(8 * 20 * 20);
  dim3 gEdge((M_ROWS + 3) / 4);
  dim3 gE((2 * N_EDGES + 255) / 256);

  k_wprep<<<dim3(D / 32, D / 32, (NLAYERS - 1) * 4), 256, 0, stream>>>(Wq, Wk, Wv, Ws, Wt);

  // combined CSR (+ ea gather into CSR order) + batch ranges
  hipMemsetAsync(cnt, 0, M_ROWS * sizeof(int), stream);
  k_hist<<<gE, 256, 0, stream>>>(dstI, dstJ, cnt);
  k_scan<<<1, 1024, 0, stream>>>(cnt, start, cursor);
  k_scatter<<<gE, 256, 0, stream>>>(srcI, dstI, srcJ, dstJ, eaI, eaJ, cursor,
                                    srcS, eaS);
  k_ranges<<<1, 192, 0, stream>>>(batI, batJ, rng);

  // layer 0
  k_lin4<<<gLin4, 256, 0, stream>>>(xI, xJ, W0q, b0q, W0k, b0k, W0v, b0v, W0s,
                                    b0s, qbf, kvbf, sbf);
  k_edge_fused<<<gEdge, 256, 0, stream>>>(hbf, sbf, qbf, kvbf, eaS, W0e, srcS,
                                          start, 1);

  // layers 1..5
  for (int l = 0; l < NLAYERS - 1; ++l) {
    const unsigned short* WtL = Wt + (size_t)l * 4 * D * D;
    const float* Wel = We + (size_t)l * ED_IN * D;
    int last = (l == NLAYERS - 2);
    k_gemm_bf16<<<gGemm, 256, 0, stream>>>(
        hbf, WtL, bq + (size_t)l * D, bk + (size_t)l * D, bv + (size_t)l * D,
        bs + (size_t)l * D, qbf, kvbf, sbf);
    k_edge_fused<<<gEdge, 256, 0, stream>>>(hbf, sbf, qbf, kvbf, eaS, Wel, srcS,
                                            start, last ? 0 : 1);
  }

  k_pool_seg<<<2 * NB, 256, 0, stream>>>(hbf, rng, pooled);
  k_head<<<2 * NB, 256, 0, stream>>>(pooled, ln_g, ln_b, Wemb, bemb, z);
  k_cosine<<<NB, 64, 0, stream>>>(z, z + (size_t)NB * D, (float*)d_out);
}

// Round 9
// 1584.328 us; speedup vs baseline: 7.5455x; 1.1240x over previous
//
#include <hip/hip_runtime.h>

#define N_NODES 10000
#define N_EDGES 160000
#define NB 64
#define D 640
#define ND_IN 4
#define ED_IN 8
#define NLAYERS 6
#define M_ROWS (2 * N_NODES)  // both graphs batched

#define SCORE_SCALE 0.039528470752104741f  // 1/sqrt(640)
#define NEGBIG -3.4e38f

typedef __attribute__((ext_vector_type(8))) short short8;
typedef __attribute__((ext_vector_type(4))) float floatx4;
typedef __attribute__((ext_vector_type(2))) float floatx2;

__device__ __forceinline__ unsigned short f2bf(float f) {
  unsigned u = __float_as_uint(f);
  u += 0x7fffu + ((u >> 16) & 1);  // RNE
  return (unsigned short)(u >> 16);
}
__device__ __forceinline__ float bf2f(unsigned short s) {
  return __uint_as_float((unsigned)s << 16);
}
__device__ __forceinline__ void gload_lds16(const void* g, void* l) {
  __builtin_amdgcn_global_load_lds(
      (const __attribute__((address_space(1))) void*)g,
      (__attribute__((address_space(3))) void*)l, 16, 0, 0);
}
__device__ __forceinline__ float4 cvt4(ushort4 s) {
  return make_float4(bf2f(s.x), bf2f(s.y), bf2f(s.z), bf2f(s.w));
}
// 4 fp8 e4m3 (packed in uint) -> float4 via v_cvt_pk_f32_fp8
__device__ __forceinline__ float4 fp8x4_to_f4(unsigned u) {
  floatx2 lo = __builtin_amdgcn_cvt_pk_f32_fp8((int)u, false);
  floatx2 hi = __builtin_amdgcn_cvt_pk_f32_fp8((int)u, true);
  return make_float4(lo[0], lo[1], hi[0], hi[1]);
}
// 4 floats -> packed fp8 e4m3 uint via v_cvt_pk_fp8_f32
__device__ __forceinline__ unsigned f4_to_fp8x4(float a, float b, float c, float d) {
  int pk = __builtin_amdgcn_cvt_pk_fp8_f32(a, b, 0, false);
  pk = __builtin_amdgcn_cvt_pk_fp8_f32(c, d, pk, true);
  return (unsigned)pk;
}

// ---- layer-0 projections: q,skip bf16; k,v fp8 interleaved in kvf8 ----
__global__ void k_lin4(const float* __restrict__ xI, const float* __restrict__ xJ,
                       const float* __restrict__ Wq, const float* __restrict__ bq,
                       const float* __restrict__ Wk, const float* __restrict__ bk,
                       const float* __restrict__ Wv, const float* __restrict__ bv,
                       const float* __restrict__ Ws, const float* __restrict__ bs,
                       unsigned short* __restrict__ oqb, unsigned char* __restrict__ okv,
                       unsigned short* __restrict__ osb) {
  int t = blockIdx.x * blockDim.x + threadIdx.x;
  if (t >= M_ROWS * D) return;
  int z = blockIdx.z;
  const float* W = (z == 0) ? Wq : (z == 1) ? Wk : (z == 2) ? Wv : Ws;
  const float* b = (z == 0) ? bq : (z == 1) ? bk : (z == 2) ? bv : bs;
  int n = t / D, d = t % D;
  const float* xr = (n < N_NODES) ? xI + (size_t)n * ND_IN
                                  : xJ + (size_t)(n - N_NODES) * ND_IN;
  float acc = b[d];
#pragma unroll
  for (int c = 0; c < ND_IN; ++c) acc += xr[c] * W[c * D + d];
  if (z == 0) oqb[t] = f2bf(acc);
  else if (z == 3) osb[t] = f2bf(acc);
  else {
    unsigned char f8 =
        (unsigned char)(__builtin_amdgcn_cvt_pk_fp8_f32(acc, 0.f, 0, false) & 0xFF);
    okv[(size_t)(2 * n + (z - 1)) * D + d] = f8;
  }
}

// one-time: Wt[l][mat][n][k] = bf16(W[l][mat][k][n])
__global__ __launch_bounds__(256) void k_wprep(const float* __restrict__ Wq,
                                               const float* __restrict__ Wk,
                                               const float* __restrict__ Wv,
                                               const float* __restrict__ Ws,
                                               unsigned short* __restrict__ Wt) {
  __shared__ float tile[32][33];
  int mt = blockIdx.z;
  int l = mt >> 2, mat = mt & 3;
  const float* W =
      (mat == 0 ? Wq : mat == 1 ? Wk : mat == 2 ? Wv : Ws) + (size_t)l * D * D;
  int tk = blockIdx.x * 32, tn = blockIdx.y * 32;
  int tx = threadIdx.x & 31, ty = threadIdx.x >> 5;
#pragma unroll
  for (int i = 0; i < 32; i += 8)
    tile[ty + i][tx] = W[(size_t)(tk + ty + i) * D + tn + tx];
  __syncthreads();
  unsigned short* dst = Wt + (size_t)mt * D * D;
#pragma unroll
  for (int i = 0; i < 32; i += 8)
    dst[(size_t)(tn + ty + i) * D + tk + tx] = f2bf(tile[tx][ty + i]);
}

// bf16 MFMA GEMM over 2N rows, XCD-swizzled flat grid, BK=64, swapped-operand
// epilogue (row=l15, col=l4*4+reg). q,s written bf16; k,v written fp8 packed.
#define BM 128
#define BN 128
#define BK 64
#define RBANDS ((M_ROWS + BM - 1) / BM)  // 157
__global__ __launch_bounds__(256) void k_gemm_bf16(
    const unsigned short* __restrict__ Abf, const unsigned short* __restrict__ Wt,
    const float* __restrict__ b0, const float* __restrict__ b1,
    const float* __restrict__ b2, const float* __restrict__ b3,
    unsigned short* __restrict__ oqb, unsigned char* __restrict__ okv,
    unsigned short* __restrict__ osb) {
  __shared__ __attribute__((aligned(16))) unsigned short lA[BM * BK];  // 16 KB
  __shared__ __attribute__((aligned(16))) unsigned short lB[BN * BK];  // 16 KB
  const int f = blockIdx.x;
  const int xcd = f & 7;
  const int slot = f >> 3;
  const int grp = slot / 20;
  const int tt = slot - grp * 20;  // 0..19
  const int r = xcd + (grp << 3);
  if (r >= RBANDS) return;
  const int z = tt / 5;
  const int by = tt - z * 5;
  const unsigned short* Wz = Wt + (size_t)z * D * D;
  const float* bias = (z == 0) ? b0 : (z == 1) ? b1 : (z == 2) ? b2 : b3;
  const int bm = r * BM, bn = by * BN;
  const int t = threadIdx.x;
  const int lane = t & 63, wv = t >> 6;
  const int wm = (wv & 1) * 64, wn = (wv >> 1) * 64;
  const int l15 = lane & 15, l4 = lane >> 4;
  const int srow = lane >> 3;
  const int scb = lane & 7;

  floatx4 acc[4][4] = {};  // [ni][mi]

  for (int k0 = 0; k0 < D; k0 += BK) {
#pragma unroll
    for (int i = 0; i < 4; ++i) {
      int row = wv * 32 + i * 8 + srow;
      int lcb = scb ^ (row & 7);
      gload_lds16(Abf + (size_t)(bm + row) * D + k0 + lcb * 8,
                  lA + (size_t)(wv * 32 + i * 8) * BK);
      gload_lds16(Wz + (size_t)(bn + row) * D + k0 + lcb * 8,
                  lB + (size_t)(wv * 32 + i * 8) * BK);
    }
    __syncthreads();
#pragma unroll
    for (int kk = 0; kk < 2; ++kk) {
      short8 af[4], bfr[4];
#pragma unroll
      for (int i = 0; i < 4; ++i) {
        int rowA = wm + i * 16 + l15;
        int pcA = (kk * 4 + l4) ^ (rowA & 7);
        af[i] = *(const short8*)(lA + rowA * BK + pcA * 8);
        int rowB = wn + i * 16 + l15;
        int pcB = (kk * 4 + l4) ^ (rowB & 7);
        bfr[i] = *(const short8*)(lB + rowB * BK + pcB * 8);
      }
#pragma unroll
      for (int ni = 0; ni < 4; ++ni)
#pragma unroll
        for (int mi = 0; mi < 4; ++mi)
          acc[ni][mi] = __builtin_amdgcn_mfma_f32_16x16x32_bf16(
              bfr[ni], af[mi], acc[ni][mi], 0, 0, 0);
    }
    __syncthreads();
  }
  float4 bia[4];
#pragma unroll
  for (int ni = 0; ni < 4; ++ni)
    bia[ni] = *(const float4*)(bias + bn + wn + ni * 16 + l4 * 4);
#pragma unroll
  for (int mi = 0; mi < 4; ++mi) {
    int row = bm + wm + mi * 16 + l15;
    if (row >= M_ROWS) continue;
#pragma unroll
    for (int ni = 0; ni < 4; ++ni) {
      int col = bn + wn + ni * 16 + l4 * 4;
      float v0 = acc[ni][mi][0] + bia[ni].x;
      float v1 = acc[ni][mi][1] + bia[ni].y;
      float v2 = acc[ni][mi][2] + bia[ni].z;
      float v3 = acc[ni][mi][3] + bia[ni].w;
      if (z == 0 || z == 3) {
        ushort4 pk;
        pk.x = f2bf(v0);
        pk.y = f2bf(v1);
        pk.z = f2bf(v2);
        pk.w = f2bf(v3);
        unsigned short* dst = (z == 0) ? oqb : osb;
        *(ushort4*)(dst + (size_t)row * D + col) = pk;
      } else {
        unsigned pk8 = f4_to_fp8x4(v0, v1, v2, v3);
        *(unsigned*)(okv + (size_t)(2 * row + (z - 1)) * D + col) = pk8;
      }
    }
  }
}

// ---- combined-graph CSR build ----
__global__ void k_hist(const int* __restrict__ dstI, const int* __restrict__ dstJ,
                       int* __restrict__ cnt) {
  int e = blockIdx.x * blockDim.x + threadIdx.x;
  if (e >= 2 * N_EDGES) return;
  int d = (e < N_EDGES) ? dstI[e] : (dstJ[e - N_EDGES] + N_NODES);
  atomicAdd(&cnt[d], 1);
}

__global__ __launch_bounds__(1024) void k_scan(const int* __restrict__ cnt,
                                               int* __restrict__ start,
                                               int* __restrict__ cursor) {
  __shared__ int sh[1024];
  __shared__ int carry_sh;
  int tid = threadIdx.x;
  if (tid == 0) {
    carry_sh = 0;
    start[0] = 0;
  }
  __syncthreads();
  for (int base = 0; base < M_ROWS; base += 1024) {
    int idx = base + tid;
    int v = (idx < M_ROWS) ? cnt[idx] : 0;
    sh[tid] = v;
    __syncthreads();
    for (int off = 1; off < 1024; off <<= 1) {
      int t = (tid >= off) ? sh[tid - off] : 0;
      __syncthreads();
      sh[tid] += t;
      __syncthreads();
    }
    int incl = sh[tid] + carry_sh;
    if (idx < M_ROWS) {
      start[idx + 1] = incl;
      cursor[idx] = incl - v;
    }
    __syncthreads();
    if (tid == 1023) carry_sh = incl;
    __syncthreads();
  }
}

// scatter + gather edge attrs into CSR order (eaS)
__global__ void k_scatter(const int* __restrict__ srcI, const int* __restrict__ dstI,
                          const int* __restrict__ srcJ, const int* __restrict__ dstJ,
                          const float* __restrict__ eaI, const float* __restrict__ eaJ,
                          int* __restrict__ cursor, int* __restrict__ srcS,
                          float* __restrict__ eaS) {
  int e = blockIdx.x * blockDim.x + threadIdx.x;
  if (e >= 2 * N_EDGES) return;
  int s, d;
  const float* eap;
  if (e < N_EDGES) {
    s = srcI[e];
    d = dstI[e];
    eap = eaI + (size_t)e * ED_IN;
  } else {
    s = srcJ[e - N_EDGES] + N_NODES;
    d = dstJ[e - N_EDGES] + N_NODES;
    eap = eaJ + (size_t)(e - N_EDGES) * ED_IN;
  }
  int pos = atomicAdd(&cursor[d], 1);
  srcS[pos] = s;
  float4 a0 = *(const float4*)eap;
  float4 a1 = *(const float4*)(eap + 4);
  *(float4*)(eaS + (size_t)pos * ED_IN) = a0;
  *(float4*)(eaS + (size_t)pos * ED_IN + 4) = a1;
}

// ---- fused edge phase: one wave per node; two 32-lane groups split the edge
// list (stride 2), each unrolled by 2, srcS prefetch; fp8 k/v gathers;
// online softmax; width-64 merge.
__global__ __launch_bounds__(256) void k_edge_fused(
    unsigned short* __restrict__ hbf, const unsigned short* __restrict__ sbf,
    const unsigned short* __restrict__ qb16, const unsigned char* __restrict__ kvf8,
    const float* __restrict__ eaS, const float* __restrict__ We,
    const int* __restrict__ srcS, const int* __restrict__ start, int do_relu) {
  int w = blockIdx.x * 4 + (threadIdx.x >> 6);
  if (w >= M_ROWS) return;
  int l64 = threadIdx.x & 63;
  int g = l64 >> 5, lane = l64 & 31;
  const int s0 = start[w], s1 = start[w + 1];
  const int deg = s1 - s0;
  const int EMAX = 2 * N_EDGES - 1;

  float4 qr[5];
#pragma unroll
  for (int i = 0; i < 5; ++i)
    qr[i] = cvt4(*(const ushort4*)(qb16 + (size_t)w * D + i * 128 + 4 * lane));

  // Gc on lane c (c<8): q[w] . We[c,:]
  float Gc = 0.f;
#pragma unroll
  for (int c = 0; c < ED_IN; ++c) {
    const float* wr = We + c * D;
    float p = 0.f;
#pragma unroll
    for (int i = 0; i < 5; ++i) {
      float4 wv = *(const float4*)(wr + i * 128 + 4 * lane);
      p += qr[i].x * wv.x + qr[i].y * wv.y + qr[i].z * wv.z + qr[i].w * wv.w;
    }
#pragma unroll
    for (int m = 1; m < 32; m <<= 1) p += __shfl_xor(p, m, 32);
    if (lane == c) Gc = p;
  }

  float mx = NEGBIG, Sp = 0.f, Sea = 0.f;
  float4 acc[5];
#pragma unroll
  for (int i = 0; i < 5; ++i) acc[i] = make_float4(0.f, 0.f, 0.f, 0.f);

  int p0 = s0 + g, p1 = p0 + 2;
  int c0 = min(p0, EMAX), c1 = min(p1, EMAX);
  int sj0 = srcS[c0], sj1 = srcS[c1];
  const int U = (deg + 3) >> 2;
  for (int u = 0; u < U; ++u) {
    bool ok0 = p0 < s1, ok1 = p1 < s1;
    int cc0 = c0, cc1 = c1;
    int tj0 = sj0, tj1 = sj1;
    p0 += 4;
    p1 += 4;
    c0 = min(p0, EMAX);
    c1 = min(p1, EMAX);
    sj0 = srcS[c0];
    sj1 = srcS[c1];

    const unsigned char* r0 = kvf8 + (size_t)tj0 * 2 * D;
    const unsigned char* r1 = kvf8 + (size_t)tj1 * 2 * D;
    float part0 = 0.f, part1 = 0.f;
    float4 vv0[5], vv1[5];
#pragma unroll
    for (int i = 0; i < 5; ++i) {
      int off = i * 128 + 4 * lane;
      float4 k0 = fp8x4_to_f4(*(const unsigned*)(r0 + off));
      float4 k1 = fp8x4_to_f4(*(const unsigned*)(r1 + off));
      vv0[i] = fp8x4_to_f4(*(const unsigned*)(r0 + D + off));
      vv1[i] = fp8x4_to_f4(*(const unsigned*)(r1 + D + off));
      part0 += qr[i].x * k0.x + qr[i].y * k0.y + qr[i].z * k0.z + qr[i].w * k0.w;
      part1 += qr[i].x * k1.x + qr[i].y * k1.y + qr[i].z * k1.z + qr[i].w * k1.w;
    }
    float ea0 = (lane < ED_IN) ? eaS[(size_t)cc0 * ED_IN + lane] : 0.f;
    float ea1 = (lane < ED_IN) ? eaS[(size_t)cc1 * ED_IN + lane] : 0.f;
    part0 += ea0 * Gc;
    part1 += ea1 * Gc;
#pragma unroll
    for (int m = 1; m < 32; m <<= 1) {
      part0 += __shfl_xor(part0, m, 32);
      part1 += __shfl_xor(part1, m, 32);
    }
    float sc0 = ok0 ? part0 * SCORE_SCALE : NEGBIG;
    float sc1 = ok1 ? part1 * SCORE_SCALE : NEGBIG;
    float m2 = fmaxf(sc0, sc1);
    if (m2 > mx) {
      float cs = __expf(mx - m2);
      float pA = __expf(sc0 - m2);
      float pB = __expf(sc1 - m2);
      mx = m2;
      Sp = Sp * cs + pA + pB;
      Sea = Sea * cs + pA * ea0 + pB * ea1;
#pragma unroll
      for (int i = 0; i < 5; ++i) {
        acc[i].x = acc[i].x * cs + pA * vv0[i].x + pB * vv1[i].x;
        acc[i].y = acc[i].y * cs + pA * vv0[i].y + pB * vv1[i].y;
        acc[i].z = acc[i].z * cs + pA * vv0[i].z + pB * vv1[i].z;
        acc[i].w = acc[i].w * cs + pA * vv0[i].w + pB * vv1[i].w;
      }
    } else {
      float pA = __expf(sc0 - mx);
      float pB = __expf(sc1 - mx);
      Sp += pA + pB;
      Sea += pA * ea0 + pB * ea1;
#pragma unroll
      for (int i = 0; i < 5; ++i) {
        acc[i].x += pA * vv0[i].x + pB * vv1[i].x;
        acc[i].y += pA * vv0[i].y + pB * vv1[i].y;
        acc[i].z += pA * vv0[i].z + pB * vv1[i].z;
        acc[i].w += pA * vv0[i].w + pB * vv1[i].w;
      }
    }
  }

  // merge the two groups' online-softmax states
  float mo = __shfl_xor(mx, 32);
  float mn = fmaxf(mx, mo);
  float a = __expf(mx - mn);
  float b = __expf(mo - mn);
  float Spo = __shfl_xor(Sp, 32);
  Sp = Sp * a + Spo * b;
  float Seao = __shfl_xor(Sea, 32);
  Sea = Sea * a + Seao * b;
#pragma unroll
  for (int i = 0; i < 5; ++i) {
    float ox = __shfl_xor(acc[i].x, 32);
    float oy = __shfl_xor(acc[i].y, 32);
    float oz = __shfl_xor(acc[i].z, 32);
    float ow = __shfl_xor(acc[i].w, 32);
    acc[i].x = acc[i].x * a + ox * b;
    acc[i].y = acc[i].y * a + oy * b;
    acc[i].z = acc[i].z * a + oz * b;
    acc[i].w = acc[i].w * a + ow * b;
  }
  float inv = 1.0f / (Sp + 1e-16f);
  float seac[ED_IN];
#pragma unroll
  for (int c = 0; c < ED_IN; ++c) seac[c] = __shfl(Sea, c, 32);

  for (int i = g; i < 5; i += 2) {
    int d = i * 128 + 4 * lane;
    float4 term = acc[i];
#pragma unroll
    for (int c = 0; c < ED_IN; ++c) {
      float4 wv = *(const float4*)(We + c * D + d);
      term.x += seac[c] * wv.x;
      term.y += seac[c] * wv.y;
      term.z += seac[c] * wv.z;
      term.w += seac[c] * wv.w;
    }
    ushort4 sv = *(const ushort4*)(sbf + (size_t)w * D + d);
    float vx = bf2f(sv.x) + term.x * inv;
    float vy = bf2f(sv.y) + term.y * inv;
    float vz = bf2f(sv.z) + term.z * inv;
    float vw = bf2f(sv.w) + term.w * inv;
    if (do_relu) {
      vx = fmaxf(vx, 0.f);
      vy = fmaxf(vy, 0.f);
      vz = fmaxf(vz, 0.f);
      vw = fmaxf(vw, 0.f);
    }
    ushort4 hb;
    hb.x = f2bf(vx);
    hb.y = f2bf(vy);
    hb.z = f2bf(vz);
    hb.w = f2bf(vw);
    *(ushort4*)(hbf + (size_t)w * D + d) = hb;
  }
}

// per-batch node ranges via binary search (batch arrays are sorted)
__global__ void k_ranges(const int* __restrict__ batI, const int* __restrict__ batJ,
                         int* __restrict__ rng) {
  int b = threadIdx.x;
  if (b > 2 * NB) return;
  if (b == 2 * NB) {
    rng[b] = M_ROWS;
    return;
  }
  const int* bat = (b < NB) ? batI : batJ;
  int tgt = (b < NB) ? b : b - NB;
  int lo = 0, hi = N_NODES;
  while (lo < hi) {
    int mid = (lo + hi) >> 1;
    if (bat[mid] < tgt) lo = mid + 1;
    else hi = mid;
  }
  rng[b] = lo + ((b < NB) ? 0 : N_NODES);
}

// segmented pool: block b sums rows [rng[b], rng[b+1]) — no atomics
__global__ __launch_bounds__(256) void k_pool_seg(const unsigned short* __restrict__ hbf,
                                                  const int* __restrict__ rng,
                                                  float* __restrict__ pooled) {
  int b = blockIdx.x;
  int lo = rng[b], hi = rng[b + 1];
  int ch = threadIdx.x;  // ushort4 chunk id, 0..159
  if (ch >= 160) return;
  float4 s = make_float4(0.f, 0.f, 0.f, 0.f);
  for (int n = lo; n < hi; ++n) {
    ushort4 v = *(const ushort4*)(hbf + (size_t)n * D + ch * 4);
    s.x += bf2f(v.x);
    s.y += bf2f(v.y);
    s.z += bf2f(v.z);
    s.w += bf2f(v.w);
  }
  *(float4*)(pooled + (size_t)b * D + ch * 4) = s;
}

// per graph row: LayerNorm -> @Wemb + bemb -> ReLU  (grid 2*NB)
__global__ __launch_bounds__(256) void k_head(const float* __restrict__ pooled,
                                              const float* __restrict__ gam,
                                              const float* __restrict__ bet,
                                              const float* __restrict__ Wemb,
                                              const float* __restrict__ bemb,
                                              float* __restrict__ z) {
  __shared__ float sh[D];
  __shared__ float red[4];
  int b = blockIdx.x, tid = threadIdx.x;
  float local = 0.f;
  for (int c = tid; c < D; c += 256) {
    float val = pooled[(size_t)b * D + c];
    sh[c] = val;
    local += val;
  }
#pragma unroll
  for (int off = 32; off > 0; off >>= 1) local += __shfl_down(local, off);
  if ((tid & 63) == 0) red[tid >> 6] = local;
  __syncthreads();
  float mu = (red[0] + red[1] + red[2] + red[3]) * (1.0f / D);
  __syncthreads();
  float lv = 0.f;
  for (int c = tid; c < D; c += 256) {
    float t2 = sh[c] - mu;
    lv += t2 * t2;
  }
#pragma unroll
  for (int off = 32; off > 0; off >>= 1) lv += __shfl_down(lv, off);
  if ((tid & 63) == 0) red[tid >> 6] = lv;
  __syncthreads();
  float var = (red[0] + red[1] + red[2] + red[3]) * (1.0f / D);
  float rstd = rsqrtf(var + 1e-5f);
  __syncthreads();
  for (int c = tid; c < D; c += 256) sh[c] = (sh[c] - mu) * rstd * gam[c] + bet[c];
  __syncthreads();
  for (int d = tid; d < D; d += 256) {
    float acc = bemb[d];
    for (int c = 0; c < D; ++c) acc += sh[c] * Wemb[c * D + d];
    z[(size_t)b * D + d] = fmaxf(acc, 0.f);
  }
}

__global__ void k_cosine(const float* __restrict__ zi, const float* __restrict__ zj,
                         float* __restrict__ out) {
  int b = blockIdx.x, lane = threadIdx.x;
  float dot = 0.f, ni = 0.f, nj = 0.f;
  for (int d = lane; d < D; d += 64) {
    float a = zi[(size_t)b * D + d], c = zj[(size_t)b * D + d];
    dot += a * c;
    ni += a * a;
    nj += c * c;
  }
#pragma unroll
  for (int off = 32; off > 0; off >>= 1) {
    dot += __shfl_down(dot, off);
    ni += __shfl_down(ni, off);
    nj += __shfl_down(nj, off);
  }
  if (lane == 0)
    out[b] = dot / (fmaxf(sqrtf(ni), 1e-8f) * fmaxf(sqrtf(nj), 1e-8f));
}

extern "C" void kernel_launch(void* const* d_in, const int* in_sizes, int n_in,
                              void* d_out, int out_size, void* d_ws, size_t ws_size,
                              hipStream_t stream) {
  (void)in_sizes; (void)n_in; (void)out_size; (void)ws_size;
  const float* xI = (const float*)d_in[0];
  const int* eiI = (const int*)d_in[1];
  const float* eaI = (const float*)d_in[2];
  const int* batI = (const int*)d_in[3];
  const float* xJ = (const float*)d_in[4];
  const int* eiJ = (const int*)d_in[5];
  const float* eaJ = (const float*)d_in[6];
  const int* batJ = (const int*)d_in[7];
  const float* W0q = (const float*)d_in[8];
  const float* b0q = (const float*)d_in[9];
  const float* W0k = (const float*)d_in[10];
  const float* b0k = (const float*)d_in[11];
  const float* W0v = (const float*)d_in[12];
  const float* b0v = (const float*)d_in[13];
  const float* W0e = (const float*)d_in[14];
  const float* W0s = (const float*)d_in[15];
  const float* b0s = (const float*)d_in[16];
  const float* Wq = (const float*)d_in[17];
  const float* bq = (const float*)d_in[18];
  const float* Wk = (const float*)d_in[19];
  const float* bk = (const float*)d_in[20];
  const float* Wv = (const float*)d_in[21];
  const float* bv = (const float*)d_in[22];
  const float* We = (const float*)d_in[23];
  const float* Ws = (const float*)d_in[24];
  const float* bs = (const float*)d_in[25];
  const float* ln_g = (const float*)d_in[26];
  const float* ln_b = (const float*)d_in[27];
  const float* Wemb = (const float*)d_in[28];
  const float* bemb = (const float*)d_in[29];

  const size_t ND2 = (size_t)M_ROWS * D;
  float* pooled = (float*)d_ws;                  // 2NB*D
  float* z = pooled + (size_t)2 * NB * D;        // 2NB*D
  float* eaS = z + (size_t)2 * NB * D;           // 2E*8
  unsigned short* qbf = (unsigned short*)(eaS + (size_t)2 * N_EDGES * ED_IN);
  unsigned char* kvf8 = (unsigned char*)(qbf + ND2);  // 2*ND2 bytes (k/v fp8)
  unsigned short* hbf = (unsigned short*)(kvf8 + 2 * ND2);  // ND2
  unsigned short* sbf = hbf + ND2;               // ND2 (also A-OOB pad)
  unsigned short* Wt = sbf + ND2;                // 20*D*D
  int* cnt = (int*)(Wt + (size_t)(NLAYERS - 1) * 4 * D * D);  // 2N
  int* start = cnt + M_ROWS;                     // 2N+1
  int* cursor = start + M_ROWS + 1;              // 2N
  int* srcS = cursor + M_ROWS;                   // 2E
  int* rng = srcS + 2 * N_EDGES;                 // 2NB+1

  const int* srcI = eiI;
  const int* dstI = eiI + N_EDGES;
  const int* srcJ = eiJ;
  const int* dstJ = eiJ + N_EDGES;

  dim3 gLin4((M_ROWS * D + 255) / 256, 1, 4);
  dim3 gGemm(8 * 20 * 20);
  dim3 gEdge((M_ROWS + 3) / 4);
  dim3 gE((2 * N_EDGES + 255) / 256);

  k_wprep<<<dim3(D / 32, D / 32, (NLAYERS - 1) * 4), 256, 0, stream>>>(Wq, Wk, Wv, Ws, Wt);

  // combined CSR (+ ea gather into CSR order) + batch ranges
  hipMemsetAsync(cnt, 0, M_ROWS * sizeof(int), stream);
  k_hist<<<gE, 256, 0, stream>>>(dstI, dstJ, cnt);
  k_scan<<<1, 1024, 0, stream>>>(cnt, start, cursor);
  k_scatter<<<gE, 256, 0, stream>>>(srcI, dstI, srcJ, dstJ, eaI, eaJ, cursor,
                                    srcS, eaS);
  k_ranges<<<1, 192, 0, stream>>>(batI, batJ, rng);

  // layer 0
  k_lin4<<<gLin4, 256, 0, stream>>>(xI, xJ, W0q, b0q, W0k, b0k, W0v, b0v, W0s,
                                    b0s, qbf, kvf8, sbf);
  k_edge_fused<<<gEdge, 256, 0, stream>>>(hbf, sbf, qbf, kvf8, eaS, W0e, srcS,
                                          start, 1);

  // layers 1..5
  for (int l = 0; l < NLAYERS - 1; ++l) {
    const unsigned short* WtL = Wt + (size_t)l * 4 * D * D;
    const float* Wel = We + (size_t)l * ED_IN * D;
    int last = (l == NLAYERS - 2);
    k_gemm_bf16<<<gGemm, 256, 0, stream>>>(
        hbf, WtL, bq + (size_t)l * D, bk + (size_t)l * D, bv + (size_t)l * D,
        bs + (size_t)l * D, qbf, kvf8, sbf);
    k_edge_fused<<<gEdge, 256, 0, stream>>>(hbf, sbf, qbf, kvf8, eaS, Wel, srcS,
                                            start, last ? 0 : 1);
  }

  k_pool_seg<<<2 * NB, 256, 0, stream>>>(hbf, rng, pooled);
  k_head<<<2 * NB, 256, 0, stream>>>(pooled, ln_g, ln_b, Wemb, bemb, z);
  k_cosine<<<NB, 64, 0, stream>>>(z, z + (size_t)NB * D, (float*)d_out);
}

// Round 10
// 1343.306 us; speedup vs baseline: 8.8993x; 1.1794x over previous
//
#include <hip/hip_runtime.h>

#define N_NODES 10000
#define N_EDGES 160000
#define NB 64
#define D 640
#define ND_IN 4
#define ED_IN 8
#define NLAYERS 6
#define M_ROWS (2 * N_NODES)  // both graphs batched

#define SCORE_SCALE 0.039528470752104741f  // 1/sqrt(640)
#define NEGBIG -3.4e38f

typedef __attribute__((ext_vector_type(4))) float floatx4;
typedef __attribute__((ext_vector_type(2))) float floatx2;

__device__ __forceinline__ unsigned short f2bf(float f) {
  unsigned u = __float_as_uint(f);
  u += 0x7fffu + ((u >> 16) & 1);  // RNE
  return (unsigned short)(u >> 16);
}
__device__ __forceinline__ float bf2f(unsigned short s) {
  return __uint_as_float((unsigned)s << 16);
}
__device__ __forceinline__ void gload_lds16(const void* g, void* l) {
  __builtin_amdgcn_global_load_lds(
      (const __attribute__((address_space(1))) void*)g,
      (__attribute__((address_space(3))) void*)l, 16, 0, 0);
}
__device__ __forceinline__ float4 cvt4(ushort4 s) {
  return make_float4(bf2f(s.x), bf2f(s.y), bf2f(s.z), bf2f(s.w));
}
// 4 fp8 e4m3 (packed in uint) -> float4 via v_cvt_pk_f32_fp8
__device__ __forceinline__ float4 fp8x4_to_f4(unsigned u) {
  floatx2 lo = __builtin_amdgcn_cvt_pk_f32_fp8((int)u, false);
  floatx2 hi = __builtin_amdgcn_cvt_pk_f32_fp8((int)u, true);
  return make_float4(lo[0], lo[1], hi[0], hi[1]);
}
// 4 floats -> packed fp8 e4m3 uint via v_cvt_pk_fp8_f32
__device__ __forceinline__ unsigned f4_to_fp8x4(float a, float b, float c, float d) {
  int pk = __builtin_amdgcn_cvt_pk_fp8_f32(a, b, 0, false);
  pk = __builtin_amdgcn_cvt_pk_fp8_f32(c, d, pk, true);
  return (unsigned)pk;
}
__device__ __forceinline__ unsigned char f2fp8(float a) {
  return (unsigned char)(__builtin_amdgcn_cvt_pk_fp8_f32(a, 0.f, 0, false) & 0xFF);
}

// ---- layer-0 projections: q,skip bf16; k,v fp8 interleaved in kvf8 ----
__global__ void k_lin4(const float* __restrict__ xI, const float* __restrict__ xJ,
                       const float* __restrict__ Wq, const float* __restrict__ bq,
                       const float* __restrict__ Wk, const float* __restrict__ bk,
                       const float* __restrict__ Wv, const float* __restrict__ bv,
                       const float* __restrict__ Ws, const float* __restrict__ bs,
                       unsigned short* __restrict__ oqb, unsigned char* __restrict__ okv,
                       unsigned short* __restrict__ osb) {
  int t = blockIdx.x * blockDim.x + threadIdx.x;
  if (t >= M_ROWS * D) return;
  int z = blockIdx.z;
  const float* W = (z == 0) ? Wq : (z == 1) ? Wk : (z == 2) ? Wv : Ws;
  const float* b = (z == 0) ? bq : (z == 1) ? bk : (z == 2) ? bv : bs;
  int n = t / D, d = t % D;
  const float* xr = (n < N_NODES) ? xI + (size_t)n * ND_IN
                                  : xJ + (size_t)(n - N_NODES) * ND_IN;
  float acc = b[d];
#pragma unroll
  for (int c = 0; c < ND_IN; ++c) acc += xr[c] * W[c * D + d];
  if (z == 0) oqb[t] = f2bf(acc);
  else if (z == 3) osb[t] = f2bf(acc);
  else okv[(size_t)(2 * n + (z - 1)) * D + d] = f2fp8(acc);
}

// one-time: Wt8[l][mat][n][k] = fp8(W[l][mat][k][n])
__global__ __launch_bounds__(256) void k_wprep(const float* __restrict__ Wq,
                                               const float* __restrict__ Wk,
                                               const float* __restrict__ Wv,
                                               const float* __restrict__ Ws,
                                               unsigned char* __restrict__ Wt8) {
  __shared__ float tile[32][33];
  int mt = blockIdx.z;
  int l = mt >> 2, mat = mt & 3;
  const float* W =
      (mat == 0 ? Wq : mat == 1 ? Wk : mat == 2 ? Wv : Ws) + (size_t)l * D * D;
  int tk = blockIdx.x * 32, tn = blockIdx.y * 32;
  int tx = threadIdx.x & 31, ty = threadIdx.x >> 5;
#pragma unroll
  for (int i = 0; i < 32; i += 8)
    tile[ty + i][tx] = W[(size_t)(tk + ty + i) * D + tn + tx];
  __syncthreads();
  unsigned char* dst = Wt8 + (size_t)mt * D * D;
#pragma unroll
  for (int i = 0; i < 32; i += 8)
    dst[(size_t)(tn + ty + i) * D + tk + tx] = f2fp8(tile[tx][ty + i]);
}

// fp8 MFMA GEMM over 2N rows, XCD-swizzled flat grid, BK=128 bytes (5 K-iters,
// 64 MFMA per barrier), swapped-operand epilogue (row=l15, col=l4*4+reg).
// q,s written bf16; k,v written fp8 packed.
#define BM 128
#define BN 128
#define BKF 128
#define RBANDS ((M_ROWS + BM - 1) / BM)  // 157
__global__ __launch_bounds__(256) void k_gemm_fp8(
    const unsigned char* __restrict__ Af8, const unsigned char* __restrict__ Wt8,
    const float* __restrict__ b0, const float* __restrict__ b1,
    const float* __restrict__ b2, const float* __restrict__ b3,
    unsigned short* __restrict__ oqb, unsigned char* __restrict__ okv,
    unsigned short* __restrict__ osb) {
  __shared__ __attribute__((aligned(16))) unsigned char lA[BM * BKF];  // 16 KB
  __shared__ __attribute__((aligned(16))) unsigned char lB[BN * BKF];  // 16 KB
  const int f = blockIdx.x;
  const int xcd = f & 7;
  const int slot = f >> 3;
  const int grp = slot / 20;
  const int tt = slot - grp * 20;  // 0..19
  const int r = xcd + (grp << 3);
  if (r >= RBANDS) return;
  const int z = tt / 5;
  const int by = tt - z * 5;
  const unsigned char* Wz = Wt8 + (size_t)z * D * D;
  const float* bias = (z == 0) ? b0 : (z == 1) ? b1 : (z == 2) ? b2 : b3;
  const int bm = r * BM, bn = by * BN;
  const int t = threadIdx.x;
  const int lane = t & 63, wv = t >> 6;
  const int wm = (wv & 1) * 64, wn = (wv >> 1) * 64;
  const int l15 = lane & 15, l4 = lane >> 4;
  const int srow = lane >> 3;  // staging: row within 8-row chunk
  const int scb = lane & 7;    // staging: physical 16B block (8 per 128B row)

  floatx4 acc[4][4] = {};  // [ni][mi]

  for (int k0 = 0; k0 < D; k0 += BKF) {  // 5 iterations
#pragma unroll
    for (int i = 0; i < 4; ++i) {
      int row = wv * 32 + i * 8 + srow;
      int lcb = scb ^ (row & 7);  // logical 16B block stored at physical scb
      gload_lds16(Af8 + (size_t)(bm + row) * D + k0 + lcb * 16,
                  lA + (size_t)(wv * 32 + i * 8) * BKF);
      gload_lds16(Wz + (size_t)(bn + row) * D + k0 + lcb * 16,
                  lB + (size_t)(wv * 32 + i * 8) * BKF);
    }
    __syncthreads();
#pragma unroll
    for (int kk = 0; kk < 4; ++kk) {
      long af[4], bfr[4];
      int c8 = kk * 4 + l4;          // logical 8B chunk (0..15)
      int blk = c8 >> 1, sub = (c8 & 1) * 8;
#pragma unroll
      for (int i = 0; i < 4; ++i) {
        int rowA = wm + i * 16 + l15;
        af[i] = *(const long*)(lA + (size_t)rowA * BKF +
                               (blk ^ (rowA & 7)) * 16 + sub);
        int rowB = wn + i * 16 + l15;
        bfr[i] = *(const long*)(lB + (size_t)rowB * BKF +
                                (blk ^ (rowB & 7)) * 16 + sub);
      }
#pragma unroll
      for (int ni = 0; ni < 4; ++ni)
#pragma unroll
        for (int mi = 0; mi < 4; ++mi)
          acc[ni][mi] = __builtin_amdgcn_mfma_f32_16x16x32_fp8_fp8(
              bfr[ni], af[mi], acc[ni][mi], 0, 0, 0);
    }
    __syncthreads();
  }
  float4 bia[4];
#pragma unroll
  for (int ni = 0; ni < 4; ++ni)
    bia[ni] = *(const float4*)(bias + bn + wn + ni * 16 + l4 * 4);
#pragma unroll
  for (int mi = 0; mi < 4; ++mi) {
    int row = bm + wm + mi * 16 + l15;
    if (row >= M_ROWS) continue;
#pragma unroll
    for (int ni = 0; ni < 4; ++ni) {
      int col = bn + wn + ni * 16 + l4 * 4;
      float v0 = acc[ni][mi][0] + bia[ni].x;
      float v1 = acc[ni][mi][1] + bia[ni].y;
      float v2 = acc[ni][mi][2] + bia[ni].z;
      float v3 = acc[ni][mi][3] + bia[ni].w;
      if (z == 0 || z == 3) {
        ushort4 pk;
        pk.x = f2bf(v0);
        pk.y = f2bf(v1);
        pk.z = f2bf(v2);
        pk.w = f2bf(v3);
        unsigned short* dst = (z == 0) ? oqb : osb;
        *(ushort4*)(dst + (size_t)row * D + col) = pk;
      } else {
        unsigned pk8 = f4_to_fp8x4(v0, v1, v2, v3);
        *(unsigned*)(okv + (size_t)(2 * row + (z - 1)) * D + col) = pk8;
      }
    }
  }
}

// ---- combined-graph CSR build ----
__global__ void k_hist(const int* __restrict__ dstI, const int* __restrict__ dstJ,
                       int* __restrict__ cnt) {
  int e = blockIdx.x * blockDim.x + threadIdx.x;
  if (e >= 2 * N_EDGES) return;
  int d = (e < N_EDGES) ? dstI[e] : (dstJ[e - N_EDGES] + N_NODES);
  atomicAdd(&cnt[d], 1);
}

__global__ __launch_bounds__(1024) void k_scan(const int* __restrict__ cnt,
                                               int* __restrict__ start,
                                               int* __restrict__ cursor) {
  __shared__ int sh[1024];
  __shared__ int carry_sh;
  int tid = threadIdx.x;
  if (tid == 0) {
    carry_sh = 0;
    start[0] = 0;
  }
  __syncthreads();
  for (int base = 0; base < M_ROWS; base += 1024) {
    int idx = base + tid;
    int v = (idx < M_ROWS) ? cnt[idx] : 0;
    sh[tid] = v;
    __syncthreads();
    for (int off = 1; off < 1024; off <<= 1) {
      int t = (tid >= off) ? sh[tid - off] : 0;
      __syncthreads();
      sh[tid] += t;
      __syncthreads();
    }
    int incl = sh[tid] + carry_sh;
    if (idx < M_ROWS) {
      start[idx + 1] = incl;
      cursor[idx] = incl - v;
    }
    __syncthreads();
    if (tid == 1023) carry_sh = incl;
    __syncthreads();
  }
}

// scatter + gather edge attrs into CSR order (eaS)
__global__ void k_scatter(const int* __restrict__ srcI, const int* __restrict__ dstI,
                          const int* __restrict__ srcJ, const int* __restrict__ dstJ,
                          const float* __restrict__ eaI, const float* __restrict__ eaJ,
                          int* __restrict__ cursor, int* __restrict__ srcS,
                          float* __restrict__ eaS) {
  int e = blockIdx.x * blockDim.x + threadIdx.x;
  if (e >= 2 * N_EDGES) return;
  int s, d;
  const float* eap;
  if (e < N_EDGES) {
    s = srcI[e];
    d = dstI[e];
    eap = eaI + (size_t)e * ED_IN;
  } else {
    s = srcJ[e - N_EDGES] + N_NODES;
    d = dstJ[e - N_EDGES] + N_NODES;
    eap = eaJ + (size_t)(e - N_EDGES) * ED_IN;
  }
  int pos = atomicAdd(&cursor[d], 1);
  srcS[pos] = s;
  float4 a0 = *(const float4*)eap;
  float4 a1 = *(const float4*)(eap + 4);
  *(float4*)(eaS + (size_t)pos * ED_IN) = a0;
  *(float4*)(eaS + (size_t)pos * ED_IN + 4) = a1;
}

// ---- fused edge phase: one wave per node; two 32-lane groups split the edge
// list (stride 2), each unrolled by 2, srcS prefetch; fp8 k/v gathers; online
// softmax; width-64 merge. Output: fp8 h (layers 0..4) or bf16 h (last).
__global__ __launch_bounds__(256) void k_edge_fused(
    unsigned char* __restrict__ hf8, unsigned short* __restrict__ hbf,
    const unsigned short* __restrict__ sbf, const unsigned short* __restrict__ qb16,
    const unsigned char* __restrict__ kvf8, const float* __restrict__ eaS,
    const float* __restrict__ We, const int* __restrict__ srcS,
    const int* __restrict__ start, int do_relu, int write_bf) {
  int w = blockIdx.x * 4 + (threadIdx.x >> 6);
  if (w >= M_ROWS) return;
  int l64 = threadIdx.x & 63;
  int g = l64 >> 5, lane = l64 & 31;
  const int s0 = start[w], s1 = start[w + 1];
  const int deg = s1 - s0;
  const int EMAX = 2 * N_EDGES - 1;

  float4 qr[5];
#pragma unroll
  for (int i = 0; i < 5; ++i)
    qr[i] = cvt4(*(const ushort4*)(qb16 + (size_t)w * D + i * 128 + 4 * lane));

  // Gc on lane c (c<8): q[w] . We[c,:]
  float Gc = 0.f;
#pragma unroll
  for (int c = 0; c < ED_IN; ++c) {
    const float* wr = We + c * D;
    float p = 0.f;
#pragma unroll
    for (int i = 0; i < 5; ++i) {
      float4 wv = *(const float4*)(wr + i * 128 + 4 * lane);
      p += qr[i].x * wv.x + qr[i].y * wv.y + qr[i].z * wv.z + qr[i].w * wv.w;
    }
#pragma unroll
    for (int m = 1; m < 32; m <<= 1) p += __shfl_xor(p, m, 32);
    if (lane == c) Gc = p;
  }

  float mx = NEGBIG, Sp = 0.f, Sea = 0.f;
  float4 acc[5];
#pragma unroll
  for (int i = 0; i < 5; ++i) acc[i] = make_float4(0.f, 0.f, 0.f, 0.f);

  int p0 = s0 + g, p1 = p0 + 2;
  int c0 = min(p0, EMAX), c1 = min(p1, EMAX);
  int sj0 = srcS[c0], sj1 = srcS[c1];
  const int U = (deg + 3) >> 2;
  for (int u = 0; u < U; ++u) {
    bool ok0 = p0 < s1, ok1 = p1 < s1;
    int cc0 = c0, cc1 = c1;
    int tj0 = sj0, tj1 = sj1;
    p0 += 4;
    p1 += 4;
    c0 = min(p0, EMAX);
    c1 = min(p1, EMAX);
    sj0 = srcS[c0];
    sj1 = srcS[c1];

    const unsigned char* r0 = kvf8 + (size_t)tj0 * 2 * D;
    const unsigned char* r1 = kvf8 + (size_t)tj1 * 2 * D;
    float part0 = 0.f, part1 = 0.f;
    float4 vv0[5], vv1[5];
#pragma unroll
    for (int i = 0; i < 5; ++i) {
      int off = i * 128 + 4 * lane;
      float4 k0 = fp8x4_to_f4(*(const unsigned*)(r0 + off));
      float4 k1 = fp8x4_to_f4(*(const unsigned*)(r1 + off));
      vv0[i] = fp8x4_to_f4(*(const unsigned*)(r0 + D + off));
      vv1[i] = fp8x4_to_f4(*(const unsigned*)(r1 + D + off));
      part0 += qr[i].x * k0.x + qr[i].y * k0.y + qr[i].z * k0.z + qr[i].w * k0.w;
      part1 += qr[i].x * k1.x + qr[i].y * k1.y + qr[i].z * k1.z + qr[i].w * k1.w;
    }
    float ea0 = (lane < ED_IN) ? eaS[(size_t)cc0 * ED_IN + lane] : 0.f;
    float ea1 = (lane < ED_IN) ? eaS[(size_t)cc1 * ED_IN + lane] : 0.f;
    part0 += ea0 * Gc;
    part1 += ea1 * Gc;
#pragma unroll
    for (int m = 1; m < 32; m <<= 1) {
      part0 += __shfl_xor(part0, m, 32);
      part1 += __shfl_xor(part1, m, 32);
    }
    float sc0 = ok0 ? part0 * SCORE_SCALE : NEGBIG;
    float sc1 = ok1 ? part1 * SCORE_SCALE : NEGBIG;
    float m2 = fmaxf(sc0, sc1);
    if (m2 > mx) {
      float cs = __expf(mx - m2);
      float pA = __expf(sc0 - m2);
      float pB = __expf(sc1 - m2);
      mx = m2;
      Sp = Sp * cs + pA + pB;
      Sea = Sea * cs + pA * ea0 + pB * ea1;
#pragma unroll
      for (int i = 0; i < 5; ++i) {
        acc[i].x = acc[i].x * cs + pA * vv0[i].x + pB * vv1[i].x;
        acc[i].y = acc[i].y * cs + pA * vv0[i].y + pB * vv1[i].y;
        acc[i].z = acc[i].z * cs + pA * vv0[i].z + pB * vv1[i].z;
        acc[i].w = acc[i].w * cs + pA * vv0[i].w + pB * vv1[i].w;
      }
    } else {
      float pA = __expf(sc0 - mx);
      float pB = __expf(sc1 - mx);
      Sp += pA + pB;
      Sea += pA * ea0 + pB * ea1;
#pragma unroll
      for (int i = 0; i < 5; ++i) {
        acc[i].x += pA * vv0[i].x + pB * vv1[i].x;
        acc[i].y += pA * vv0[i].y + pB * vv1[i].y;
        acc[i].z += pA * vv0[i].z + pB * vv1[i].z;
        acc[i].w += pA * vv0[i].w + pB * vv1[i].w;
      }
    }
  }

  // merge the two groups' online-softmax states
  float mo = __shfl_xor(mx, 32);
  float mn = fmaxf(mx, mo);
  float a = __expf(mx - mn);
  float b = __expf(mo - mn);
  float Spo = __shfl_xor(Sp, 32);
  Sp = Sp * a + Spo * b;
  float Seao = __shfl_xor(Sea, 32);
  Sea = Sea * a + Seao * b;
#pragma unroll
  for (int i = 0; i < 5; ++i) {
    float ox = __shfl_xor(acc[i].x, 32);
    float oy = __shfl_xor(acc[i].y, 32);
    float oz = __shfl_xor(acc[i].z, 32);
    float ow = __shfl_xor(acc[i].w, 32);
    acc[i].x = acc[i].x * a + ox * b;
    acc[i].y = acc[i].y * a + oy * b;
    acc[i].z = acc[i].z * a + oz * b;
    acc[i].w = acc[i].w * a + ow * b;
  }
  float inv = 1.0f / (Sp + 1e-16f);
  float seac[ED_IN];
#pragma unroll
  for (int c = 0; c < ED_IN; ++c) seac[c] = __shfl(Sea, c, 32);

  for (int i = g; i < 5; i += 2) {
    int d = i * 128 + 4 * lane;
    float4 term = acc[i];
#pragma unroll
    for (int c = 0; c < ED_IN; ++c) {
      float4 wv = *(const float4*)(We + c * D + d);
      term.x += seac[c] * wv.x;
      term.y += seac[c] * wv.y;
      term.z += seac[c] * wv.z;
      term.w += seac[c] * wv.w;
    }
    ushort4 sv = *(const ushort4*)(sbf + (size_t)w * D + d);
    float vx = bf2f(sv.x) + term.x * inv;
    float vy = bf2f(sv.y) + term.y * inv;
    float vz = bf2f(sv.z) + term.z * inv;
    float vw = bf2f(sv.w) + term.w * inv;
    if (do_relu) {
      vx = fmaxf(vx, 0.f);
      vy = fmaxf(vy, 0.f);
      vz = fmaxf(vz, 0.f);
      vw = fmaxf(vw, 0.f);
    }
    if (write_bf) {
      ushort4 hb;
      hb.x = f2bf(vx);
      hb.y = f2bf(vy);
      hb.z = f2bf(vz);
      hb.w = f2bf(vw);
      *(ushort4*)(hbf + (size_t)w * D + d) = hb;
    } else {
      *(unsigned*)(hf8 + (size_t)w * D + d) = f4_to_fp8x4(vx, vy, vz, vw);
    }
  }
}

// per-batch node ranges via binary search (batch arrays are sorted)
__global__ void k_ranges(const int* __restrict__ batI, const int* __restrict__ batJ,
                         int* __restrict__ rng) {
  int b = threadIdx.x;
  if (b > 2 * NB) return;
  if (b == 2 * NB) {
    rng[b] = M_ROWS;
    return;
  }
  const int* bat = (b < NB) ? batI : batJ;
  int tgt = (b < NB) ? b : b - NB;
  int lo = 0, hi = N_NODES;
  while (lo < hi) {
    int mid = (lo + hi) >> 1;
    if (bat[mid] < tgt) lo = mid + 1;
    else hi = mid;
  }
  rng[b] = lo + ((b < NB) ? 0 : N_NODES);
}

// segmented pool: block b sums rows [rng[b], rng[b+1]) — no atomics
__global__ __launch_bounds__(256) void k_pool_seg(const unsigned short* __restrict__ hbf,
                                                  const int* __restrict__ rng,
                                                  float* __restrict__ pooled) {
  int b = blockIdx.x;
  int lo = rng[b], hi = rng[b + 1];
  int ch = threadIdx.x;  // ushort4 chunk id, 0..159
  if (ch >= 160) return;
  float4 s = make_float4(0.f, 0.f, 0.f, 0.f);
  for (int n = lo; n < hi; ++n) {
    ushort4 v = *(const ushort4*)(hbf + (size_t)n * D + ch * 4);
    s.x += bf2f(v.x);
    s.y += bf2f(v.y);
    s.z += bf2f(v.z);
    s.w += bf2f(v.w);
  }
  *(float4*)(pooled + (size_t)b * D + ch * 4) = s;
}

// per graph row: LayerNorm -> @Wemb + bemb -> ReLU  (grid 2*NB)
__global__ __launch_bounds__(256) void k_head(const float* __restrict__ pooled,
                                              const float* __restrict__ gam,
                                              const float* __restrict__ bet,
                                              const float* __restrict__ Wemb,
                                              const float* __restrict__ bemb,
                                              float* __restrict__ z) {
  __shared__ float sh[D];
  __shared__ float red[4];
  int b = blockIdx.x, tid = threadIdx.x;
  float local = 0.f;
  for (int c = tid; c < D; c += 256) {
    float val = pooled[(size_t)b * D + c];
    sh[c] = val;
    local += val;
  }
#pragma unroll
  for (int off = 32; off > 0; off >>= 1) local += __shfl_down(local, off);
  if ((tid & 63) == 0) red[tid >> 6] = local;
  __syncthreads();
  float mu = (red[0] + red[1] + red[2] + red[3]) * (1.0f / D);
  __syncthreads();
  float lv = 0.f;
  for (int c = tid; c < D; c += 256) {
    float t2 = sh[c] - mu;
    lv += t2 * t2;
  }
#pragma unroll
  for (int off = 32; off > 0; off >>= 1) lv += __shfl_down(lv, off);
  if ((tid & 63) == 0) red[tid >> 6] = lv;
  __syncthreads();
  float var = (red[0] + red[1] + red[2] + red[3]) * (1.0f / D);
  float rstd = rsqrtf(var + 1e-5f);
  __syncthreads();
  for (int c = tid; c < D; c += 256) sh[c] = (sh[c] - mu) * rstd * gam[c] + bet[c];
  __syncthreads();
  for (int d = tid; d < D; d += 256) {
    float acc = bemb[d];
    for (int c = 0; c < D; ++c) acc += sh[c] * Wemb[c * D + d];
    z[(size_t)b * D + d] = fmaxf(acc, 0.f);
  }
}

__global__ void k_cosine(const float* __restrict__ zi, const float* __restrict__ zj,
                         float* __restrict__ out) {
  int b = blockIdx.x, lane = threadIdx.x;
  float dot = 0.f, ni = 0.f, nj = 0.f;
  for (int d = lane; d < D; d += 64) {
    float a = zi[(size_t)b * D + d], c = zj[(size_t)b * D + d];
    dot += a * c;
    ni += a * a;
    nj += c * c;
  }
#pragma unroll
  for (int off = 32; off > 0; off >>= 1) {
    dot += __shfl_down(dot, off);
    ni += __shfl_down(ni, off);
    nj += __shfl_down(nj, off);
  }
  if (lane == 0)
    out[b] = dot / (fmaxf(sqrtf(ni), 1e-8f) * fmaxf(sqrtf(nj), 1e-8f));
}

extern "C" void kernel_launch(void* const* d_in, const int* in_sizes, int n_in,
                              void* d_out, int out_size, void* d_ws, size_t ws_size,
                              hipStream_t stream) {
  (void)in_sizes; (void)n_in; (void)out_size; (void)ws_size;
  const float* xI = (const float*)d_in[0];
  const int* eiI = (const int*)d_in[1];
  const float* eaI = (const float*)d_in[2];
  const int* batI = (const int*)d_in[3];
  const float* xJ = (const float*)d_in[4];
  const int* eiJ = (const int*)d_in[5];
  const float* eaJ = (const float*)d_in[6];
  const int* batJ = (const int*)d_in[7];
  const float* W0q = (const float*)d_in[8];
  const float* b0q = (const float*)d_in[9];
  const float* W0k = (const float*)d_in[10];
  const float* b0k = (const float*)d_in[11];
  const float* W0v = (const float*)d_in[12];
  const float* b0v = (const float*)d_in[13];
  const float* W0e = (const float*)d_in[14];
  const float* W0s = (const float*)d_in[15];
  const float* b0s = (const float*)d_in[16];
  const float* Wq = (const float*)d_in[17];
  const float* bq = (const float*)d_in[18];
  const float* Wk = (const float*)d_in[19];
  const float* bk = (const float*)d_in[20];
  const float* Wv = (const float*)d_in[21];
  const float* bv = (const float*)d_in[22];
  const float* We = (const float*)d_in[23];
  const float* Ws = (const float*)d_in[24];
  const float* bs = (const float*)d_in[25];
  const float* ln_g = (const float*)d_in[26];
  const float* ln_b = (const float*)d_in[27];
  const float* Wemb = (const float*)d_in[28];
  const float* bemb = (const float*)d_in[29];

  const size_t ND2 = (size_t)M_ROWS * D;
  float* pooled = (float*)d_ws;                  // 2NB*D
  float* z = pooled + (size_t)2 * NB * D;        // 2NB*D
  float* eaS = z + (size_t)2 * NB * D;           // 2E*8
  unsigned short* qbf = (unsigned short*)(eaS + (size_t)2 * N_EDGES * ED_IN);
  unsigned char* kvf8 = (unsigned char*)(qbf + ND2);   // 2*ND2 bytes (k/v fp8)
  unsigned char* hf8 = kvf8 + 2 * ND2;                 // ND2 bytes (h fp8)
  unsigned short* hbf = (unsigned short*)(hf8 + ND2);  // ND2 (also hf8 OOB pad)
  unsigned short* sbf = hbf + ND2;               // ND2
  unsigned char* Wt8 = (unsigned char*)(sbf + ND2);    // 20*D*D bytes
  int* cnt = (int*)(Wt8 + (size_t)(NLAYERS - 1) * 4 * D * D);  // 2N
  int* start = cnt + M_ROWS;                     // 2N+1
  int* cursor = start + M_ROWS + 1;              // 2N
  int* srcS = cursor + M_ROWS;                   // 2E
  int* rng = srcS + 2 * N_EDGES;                 // 2NB+1

  const int* srcI = eiI;
  const int* dstI = eiI + N_EDGES;
  const int* srcJ = eiJ;
  const int* dstJ = eiJ + N_EDGES;

  dim3 gLin4((M_ROWS * D + 255) / 256, 1, 4);
  dim3 gGemm(8 * 20 * 20);
  dim3 gEdge((M_ROWS + 3) / 4);
  dim3 gE((2 * N_EDGES + 255) / 256);

  k_wprep<<<dim3(D / 32, D / 32, (NLAYERS - 1) * 4), 256, 0, stream>>>(Wq, Wk, Wv, Ws, Wt8);

  // combined CSR (+ ea gather into CSR order) + batch ranges
  hipMemsetAsync(cnt, 0, M_ROWS * sizeof(int), stream);
  k_hist<<<gE, 256, 0, stream>>>(dstI, dstJ, cnt);
  k_scan<<<1, 1024, 0, stream>>>(cnt, start, cursor);
  k_scatter<<<gE, 256, 0, stream>>>(srcI, dstI, srcJ, dstJ, eaI, eaJ, cursor,
                                    srcS, eaS);
  k_ranges<<<1, 192, 0, stream>>>(batI, batJ, rng);

  // layer 0
  k_lin4<<<gLin4, 256, 0, stream>>>(xI, xJ, W0q, b0q, W0k, b0k, W0v, b0v, W0s,
                                    b0s, qbf, kvf8, sbf);
  k_edge_fused<<<gEdge, 256, 0, stream>>>(hf8, hbf, sbf, qbf, kvf8, eaS, W0e,
                                          srcS, start, 1, 0);

  // layers 1..5
  for (int l = 0; l < NLAYERS - 1; ++l) {
    const unsigned char* WtL = Wt8 + (size_t)l * 4 * D * D;
    const float* Wel = We + (size_t)l * ED_IN * D;
    int last = (l == NLAYERS - 2);
    k_gemm_fp8<<<gGemm, 256, 0, stream>>>(
        hf8, WtL, bq + (size_t)l * D, bk + (size_t)l * D, bv + (size_t)l * D,
        bs + (size_t)l * D, qbf, kvf8, sbf);
    k_edge_fused<<<gEdge, 256, 0, stream>>>(hf8, hbf, sbf, qbf, kvf8, eaS, Wel,
                                            srcS, start, last ? 0 : 1,
                                            last ? 1 : 0);
  }

  k_pool_seg<<<2 * NB, 256, 0, stream>>>(hbf, rng, pooled);
  k_head<<<2 * NB, 256, 0, stream>>>(pooled, ln_g, ln_b, Wemb, bemb, z);
  k_cosine<<<NB, 64, 0, stream>>>(z, z + (size_t)NB * D, (float*)d_out);
}